// Round 1
// baseline (2571.867 us; speedup 1.0000x reference)
//
#include <hip/hip_runtime.h>
#include <hip/hip_bf16.h>
#include <math.h>

// Problem constants (from reference setup_inputs)
#define NN   50000      // nodes
#define NE   400000     // edges (without self loops)
#define NET  450000     // edges + self loops
#define FH   8          // heads
#define FC   64         // channels per head
#define FHC  512        // H*C
#define FIN  128        // input features
#define NG   64         // graphs

// ---- order-preserving float<->uint for atomicMax on floats ----
static __device__ __forceinline__ unsigned ord_f32(float f) {
  unsigned u = __float_as_uint(f);
  return (u & 0x80000000u) ? ~u : (u | 0x80000000u);
}
static __device__ __forceinline__ float unord_f32(unsigned u) {
  return __uint_as_float((u & 0x80000000u) ? (u & 0x7fffffffu) : ~u);
}

// ---- f32 GEMM: C[M,N] = A[M,K] @ B[K,N]; 64x64 tile, 256 thr, 4x4/thread ----
__global__ __launch_bounds__(256) void gemm64(const float* __restrict__ A,
                                              const float* __restrict__ B,
                                              float* __restrict__ Cout,
                                              int M, int N, int K) {
  __shared__ float As[16][68];   // [kk][m], padded so float4 rows stay 16B aligned
  __shared__ float Bs[16][68];   // [kk][n]
  const int bm = blockIdx.y * 64;
  const int bn = blockIdx.x * 64;
  const int tid = threadIdx.x;
  const int lm  = tid >> 2;           // 0..63 (A row in tile)
  const int lk  = (tid & 3) << 2;     // 0,4,8,12 (A col in tile)
  const int lbk = tid >> 4;           // 0..15 (B row in tile)
  const int lbn = (tid & 15) << 2;    // 0..60 (B col in tile)
  const int tm  = (tid >> 4) << 2;    // 0..60
  const int tn  = (tid & 15) << 2;    // 0..60
  float acc[4][4] = {};
  for (int k0 = 0; k0 < K; k0 += 16) {
    float4 av = make_float4(0.f, 0.f, 0.f, 0.f);
    int ar = bm + lm;
    if (ar < M) av = *reinterpret_cast<const float4*>(A + (size_t)ar * K + k0 + lk);
    As[lk + 0][lm] = av.x; As[lk + 1][lm] = av.y;
    As[lk + 2][lm] = av.z; As[lk + 3][lm] = av.w;
    float4 bv = *reinterpret_cast<const float4*>(B + (size_t)(k0 + lbk) * N + bn + lbn);
    *reinterpret_cast<float4*>(&Bs[lbk][lbn]) = bv;
    __syncthreads();
#pragma unroll
    for (int kk = 0; kk < 16; ++kk) {
      float4 a = *reinterpret_cast<const float4*>(&As[kk][tm]);
      float4 b = *reinterpret_cast<const float4*>(&Bs[kk][tn]);
      acc[0][0] += a.x * b.x; acc[0][1] += a.x * b.y; acc[0][2] += a.x * b.z; acc[0][3] += a.x * b.w;
      acc[1][0] += a.y * b.x; acc[1][1] += a.y * b.y; acc[1][2] += a.y * b.z; acc[1][3] += a.y * b.w;
      acc[2][0] += a.z * b.x; acc[2][1] += a.z * b.y; acc[2][2] += a.z * b.z; acc[2][3] += a.z * b.w;
      acc[3][0] += a.w * b.x; acc[3][1] += a.w * b.y; acc[3][2] += a.w * b.z; acc[3][3] += a.w * b.w;
    }
    __syncthreads();
  }
#pragma unroll
  for (int i = 0; i < 4; ++i) {
    int r = bm + tm + i;
    if (r < M) {
      float4 v = make_float4(acc[i][0], acc[i][1], acc[i][2], acc[i][3]);
      *reinterpret_cast<float4*>(Cout + (size_t)r * N + bn + tn) = v;
    }
  }
}

// ---- per-node attention logits: asrc[n,h] = sum_c h[n,h,c]*a_src[h,c] ----
__global__ __launch_bounds__(512) void alphas_k(const float* __restrict__ h,
                                                const float* __restrict__ a_src,
                                                const float* __restrict__ a_dst,
                                                float* __restrict__ asrc,
                                                float* __restrict__ adst) {
  int n = blockIdx.x;
  int v = threadIdx.x;  // 0..511; wave w == head w
  float hv = h[(size_t)n * FHC + v];
  float ps = hv * a_src[v];
  float pd = hv * a_dst[v];
#pragma unroll
  for (int off = 32; off; off >>= 1) {
    ps += __shfl_down(ps, off);
    pd += __shfl_down(pd, off);
  }
  if ((v & 63) == 0) {
    int hh = v >> 6;
    asrc[n * FH + hh] = ps;
    adst[n * FH + hh] = pd;
  }
}

// ---- edge pass A: segment max of leaky_relu(e) into m (ordered-uint) ----
__global__ __launch_bounds__(256) void edge_max_k(const int* __restrict__ ei,
                                                  const float* __restrict__ asrc,
                                                  const float* __restrict__ adst,
                                                  unsigned* __restrict__ m) {
  int t = blockIdx.x * 256 + threadIdx.x;
  if (t >= NET * FH) return;
  int e = t >> 3, hh = t & 7;
  int s, d;
  if (e < NE) { s = ei[e]; d = ei[NE + e]; } else { s = d = e - NE; }
  float el = asrc[s * FH + hh] + adst[d * FH + hh];
  el = el > 0.f ? el : 0.2f * el;
  atomicMax(&m[d * FH + hh], ord_f32(el));
}

// ---- edge pass B: one wave per edge; accumulate ex*h[src] and denom ----
__global__ __launch_bounds__(256) void edge_aggr_k(const int* __restrict__ ei,
                                                   const float* __restrict__ asrc,
                                                   const float* __restrict__ adst,
                                                   const unsigned* __restrict__ m,
                                                   const float* __restrict__ h,
                                                   float* __restrict__ accum,
                                                   float* __restrict__ sden) {
  int e = blockIdx.x * 4 + (threadIdx.x >> 6);
  if (e >= NET) return;
  int lane = threadIdx.x & 63;
  int s, d;
  if (e < NE) { s = ei[e]; d = ei[NE + e]; } else { s = d = e - NE; }
  int hh = lane & 7;
  float el = asrc[s * FH + hh] + adst[d * FH + hh];
  el = el > 0.f ? el : 0.2f * el;
  float ex = expf(el - unord_f32(m[d * FH + hh]));
  if (lane < 8) atomicAdd(&sden[d * FH + lane], ex);
  const float* hs = h + (size_t)s * FHC;
  float* ad = accum + (size_t)d * FHC;
#pragma unroll
  for (int h2 = 0; h2 < FH; ++h2) {
    float exh = __shfl(ex, h2);
    atomicAdd(&ad[h2 * FC + lane], exh * hs[h2 * FC + lane]);
  }
}

// ---- node epilogue layer1: normalize, +b1, ELU ----
__global__ __launch_bounds__(256) void node_fin1_k(const float* __restrict__ accum,
                                                   const float* __restrict__ sden,
                                                   const float* __restrict__ b1,
                                                   float* __restrict__ outp) {
  size_t t = (size_t)blockIdx.x * 256 + threadIdx.x;
  if (t >= (size_t)NN * FHC) return;
  int v = (int)(t & (FHC - 1));
  int n = (int)(t >> 9);
  float val = accum[t] / (sden[n * FH + (v >> 6)] + 1e-16f) + b1[v];
  outp[t] = val > 0.f ? val : expm1f(val);
}

// ---- node epilogue layer2: normalize, head-mean, +b2, ELU, pool atomics ----
__global__ __launch_bounds__(256) void node_fin2_k(const float* __restrict__ accum,
                                                   const float* __restrict__ sden,
                                                   const float* __restrict__ b2,
                                                   const int* __restrict__ batch,
                                                   float* __restrict__ pool,
                                                   float* __restrict__ cnt) {
  int n = blockIdx.x * 4 + (threadIdx.x >> 6);
  if (n >= NN) return;
  int c = threadIdx.x & 63;
  float acc = 0.f;
#pragma unroll
  for (int hh = 0; hh < FH; ++hh)
    acc += accum[(size_t)n * FHC + hh * FC + c] / (sden[n * FH + hh] + 1e-16f);
  float val = acc * (1.f / FH) + b2[c];
  val = val > 0.f ? val : expm1f(val);
  int g = batch[n];
  atomicAdd(&pool[g * FC + c], val);
  if (c == 0) atomicAdd(&cnt[g], 1.f);
}

// ---- final: mean pool ----
__global__ __launch_bounds__(256) void final_k(const float* __restrict__ pool,
                                               const float* __restrict__ cnt,
                                               float* __restrict__ out) {
  int t = blockIdx.x * 256 + threadIdx.x;
  if (t >= NG * FC) return;
  int g = t >> 6;
  out[t] = pool[t] / fmaxf(cnt[g], 1.f);
}

extern "C" void kernel_launch(void* const* d_in, const int* in_sizes, int n_in,
                              void* d_out, int out_size, void* d_ws, size_t ws_size,
                              hipStream_t stream) {
  const float* x    = (const float*)d_in[0];
  const int*   ei   = (const int*)d_in[1];
  const int*   batch= (const int*)d_in[2];
  const float* W1   = (const float*)d_in[3];
  const float* as1  = (const float*)d_in[4];
  const float* ad1  = (const float*)d_in[5];
  const float* b1   = (const float*)d_in[6];
  const float* W2   = (const float*)d_in[7];
  const float* as2  = (const float*)d_in[8];
  const float* ad2  = (const float*)d_in[9];
  const float* b2   = (const float*)d_in[10];
  float* out = (float*)d_out;

  float* bufA = (float*)d_ws;                         // [NN, 512]
  float* bufB = bufA + (size_t)NN * FHC;              // [NN, 512]
  float* asrc = bufB + (size_t)NN * FHC;              // [NN, 8]
  float* adst = asrc + (size_t)NN * FH;               // [NN, 8]
  unsigned* m = (unsigned*)(adst + (size_t)NN * FH);  // [NN, 8]
  float* sden = (float*)(m + (size_t)NN * FH);        // [NN, 8]
  float* pool = sden + (size_t)NN * FH;               // [64, 64]
  float* cnt  = pool + NG * FC;                       // [64]

  const dim3 gemm_grid(FHC / 64, (NN + 63) / 64);
  const int emax_grid = (NET * FH + 255) / 256;
  const int eagg_grid = (NET + 3) / 4;
  const int nfin_grid = (int)(((size_t)NN * FHC + 255) / 256);

  // ---------- layer 1 ----------
  gemm64<<<gemm_grid, 256, 0, stream>>>(x, W1, bufA, NN, FHC, FIN);
  alphas_k<<<NN, 512, 0, stream>>>(bufA, as1, ad1, asrc, adst);
  hipMemsetAsync(m, 0, (size_t)NN * FH * 4, stream);
  hipMemsetAsync(sden, 0, (size_t)NN * FH * 4, stream);
  hipMemsetAsync(bufB, 0, (size_t)NN * FHC * 4, stream);
  edge_max_k<<<emax_grid, 256, 0, stream>>>(ei, asrc, adst, m);
  edge_aggr_k<<<eagg_grid, 256, 0, stream>>>(ei, asrc, adst, m, bufA, bufB, sden);
  node_fin1_k<<<nfin_grid, 256, 0, stream>>>(bufB, sden, b1, bufA);

  // ---------- layer 2 ----------
  gemm64<<<gemm_grid, 256, 0, stream>>>(bufA, W2, bufB, NN, FHC, FHC);
  alphas_k<<<NN, 512, 0, stream>>>(bufB, as2, ad2, asrc, adst);
  hipMemsetAsync(m, 0, (size_t)NN * FH * 4, stream);
  hipMemsetAsync(sden, 0, (size_t)NN * FH * 4, stream);
  hipMemsetAsync(bufA, 0, (size_t)NN * FHC * 4, stream);
  edge_max_k<<<emax_grid, 256, 0, stream>>>(ei, asrc, adst, m);
  edge_aggr_k<<<eagg_grid, 256, 0, stream>>>(ei, asrc, adst, m, bufB, bufA, sden);

  hipMemsetAsync(pool, 0, (size_t)(NG * FC + NG) * 4, stream);
  node_fin2_k<<<(NN + 3) / 4, 256, 0, stream>>>(bufA, sden, b2, batch, pool, cnt);
  final_k<<<(NG * FC + 255) / 256, 256, 0, stream>>>(pool, cnt, out);
}

// Round 2
// 1419.864 us; speedup vs baseline: 1.8113x; 1.8113x over previous
//
#include <hip/hip_runtime.h>
#include <hip/hip_bf16.h>
#include <math.h>

// Problem constants (from reference setup_inputs)
#define NN   50000      // nodes
#define NE   400000     // edges (without self loops)
#define NET  450000     // edges + self loops
#define FH   8          // heads
#define FC   64         // channels per head
#define FHC  512        // H*C
#define FIN  128        // input features
#define NG   64         // graphs

// ---- f32 GEMM: C[M,N] = A[M,K] @ B[K,N]; 64x64 tile, 256 thr, 4x4/thread ----
__global__ __launch_bounds__(256) void gemm64(const float* __restrict__ A,
                                              const float* __restrict__ B,
                                              float* __restrict__ Cout,
                                              int M, int N, int K) {
  __shared__ float As[16][68];
  __shared__ float Bs[16][68];
  const int bm = blockIdx.y * 64;
  const int bn = blockIdx.x * 64;
  const int tid = threadIdx.x;
  const int lm  = tid >> 2;
  const int lk  = (tid & 3) << 2;
  const int lbk = tid >> 4;
  const int lbn = (tid & 15) << 2;
  const int tm  = (tid >> 4) << 2;
  const int tn  = (tid & 15) << 2;
  float acc[4][4] = {};
  for (int k0 = 0; k0 < K; k0 += 16) {
    float4 av = make_float4(0.f, 0.f, 0.f, 0.f);
    int ar = bm + lm;
    if (ar < M) av = *reinterpret_cast<const float4*>(A + (size_t)ar * K + k0 + lk);
    As[lk + 0][lm] = av.x; As[lk + 1][lm] = av.y;
    As[lk + 2][lm] = av.z; As[lk + 3][lm] = av.w;
    float4 bv = *reinterpret_cast<const float4*>(B + (size_t)(k0 + lbk) * N + bn + lbn);
    *reinterpret_cast<float4*>(&Bs[lbk][lbn]) = bv;
    __syncthreads();
#pragma unroll
    for (int kk = 0; kk < 16; ++kk) {
      float4 a = *reinterpret_cast<const float4*>(&As[kk][tm]);
      float4 b = *reinterpret_cast<const float4*>(&Bs[kk][tn]);
      acc[0][0] += a.x * b.x; acc[0][1] += a.x * b.y; acc[0][2] += a.x * b.z; acc[0][3] += a.x * b.w;
      acc[1][0] += a.y * b.x; acc[1][1] += a.y * b.y; acc[1][2] += a.y * b.z; acc[1][3] += a.y * b.w;
      acc[2][0] += a.z * b.x; acc[2][1] += a.z * b.y; acc[2][2] += a.z * b.z; acc[2][3] += a.z * b.w;
      acc[3][0] += a.w * b.x; acc[3][1] += a.w * b.y; acc[3][2] += a.w * b.z; acc[3][3] += a.w * b.w;
    }
    __syncthreads();
  }
#pragma unroll
  for (int i = 0; i < 4; ++i) {
    int r = bm + tm + i;
    if (r < M) {
      float4 v = make_float4(acc[i][0], acc[i][1], acc[i][2], acc[i][3]);
      *reinterpret_cast<float4*>(Cout + (size_t)r * N + bn + tn) = v;
    }
  }
}

// ---- per-node attention logits ----
__global__ __launch_bounds__(512) void alphas_k(const float* __restrict__ h,
                                                const float* __restrict__ a_src,
                                                const float* __restrict__ a_dst,
                                                float* __restrict__ asrc,
                                                float* __restrict__ adst) {
  int n = blockIdx.x;
  int v = threadIdx.x;
  float hv = h[(size_t)n * FHC + v];
  float ps = hv * a_src[v];
  float pd = hv * a_dst[v];
#pragma unroll
  for (int off = 32; off; off >>= 1) {
    ps += __shfl_down(ps, off);
    pd += __shfl_down(pd, off);
  }
  if ((v & 63) == 0) {
    int hh = v >> 6;
    asrc[n * FH + hh] = ps;
    adst[n * FH + hh] = pd;
  }
}

// ---- CSR build: histogram of dst ----
__global__ __launch_bounds__(256) void hist_k(const int* __restrict__ ei,
                                              int* __restrict__ deg) {
  int e = blockIdx.x * 256 + threadIdx.x;
  if (e >= NET) return;
  int d = (e < NE) ? ei[NE + e] : e - NE;
  atomicAdd(&deg[d], 1);
}

// ---- CSR build: exclusive scan (single block) ----
__global__ __launch_bounds__(1024) void scan_k(const int* __restrict__ deg,
                                               int* __restrict__ row_ptr,
                                               int* __restrict__ cursor) {
  __shared__ int part[1024];
  int t = threadIdx.x;
  const int CH = (NN + 1023) / 1024;  // 49
  int base = t * CH;
  int s = 0;
  for (int i = 0; i < CH; ++i) {
    int idx = base + i;
    if (idx < NN) s += deg[idx];
  }
  part[t] = s;
  __syncthreads();
  for (int off = 1; off < 1024; off <<= 1) {
    int add = (t >= off) ? part[t - off] : 0;
    __syncthreads();
    part[t] += add;
    __syncthreads();
  }
  int run = part[t] - s;  // exclusive prefix for this chunk
  for (int i = 0; i < CH; ++i) {
    int idx = base + i;
    if (idx < NN) {
      row_ptr[idx] = run;
      cursor[idx] = run;
      run += deg[idx];
    }
  }
  if (t == 1023) row_ptr[NN] = part[1023];
}

// ---- CSR build: fill src ids per dst bucket ----
__global__ __launch_bounds__(256) void fill_k(const int* __restrict__ ei,
                                              int* __restrict__ cursor,
                                              int* __restrict__ col_src) {
  int e = blockIdx.x * 256 + threadIdx.x;
  if (e >= NET) return;
  int s, d;
  if (e < NE) { s = ei[e]; d = ei[NE + e]; } else { s = d = e - NE; }
  int pos = atomicAdd(&cursor[d], 1);
  col_src[pos] = s;
}

// ---- nodes-per-graph histogram ----
__global__ __launch_bounds__(256) void cnt_k(const int* __restrict__ batch,
                                             float* __restrict__ cnt) {
  int n = blockIdx.x * 256 + threadIdx.x;
  if (n >= NN) return;
  atomicAdd(&cnt[batch[n]], 1.f);
}

// ---- gather-aggregate: one wave per dst node; fused max/softmax/agg/epilogue ----
// LAYER==1: normalize + b1 + ELU -> outp[n*512+...]
// LAYER==2: normalize + head-mean + b2 + ELU -> atomic pool[batch[n]*64+c]
template <int LAYER>
__global__ __launch_bounds__(256) void gather_k(const int* __restrict__ row_ptr,
                                                const int* __restrict__ col_src,
                                                const float* __restrict__ asrc,
                                                const float* __restrict__ adst,
                                                const float* __restrict__ h,
                                                const float* __restrict__ bias,
                                                const int* __restrict__ batch,
                                                float* __restrict__ outp,
                                                float* __restrict__ pool) {
  int n = blockIdx.x * 4 + (threadIdx.x >> 6);
  if (n >= NN) return;
  int lane = threadIdx.x & 63;
  int hh = lane & 7;
  int start = row_ptr[n], end = row_ptr[n + 1];
  float adn = adst[n * FH + hh];
  // pass 1: per-head max over incoming edges (lanes 8..63 duplicate heads)
  float mx = -1e30f;
  for (int j = start; j < end; ++j) {
    int s = col_src[j];
    float el = asrc[s * FH + hh] + adn;
    el = el > 0.f ? el : 0.2f * el;
    mx = fmaxf(mx, el);
  }
  // pass 2: exp, denom, accumulate messages
  float den = 0.f;
  float acc[FH] = {};
  for (int j = start; j < end; ++j) {
    int s = col_src[j];
    float el = asrc[s * FH + hh] + adn;
    el = el > 0.f ? el : 0.2f * el;
    float ex = __expf(el - mx);
    den += ex;
    const float* hs = h + (size_t)s * FHC;
#pragma unroll
    for (int h2 = 0; h2 < FH; ++h2) {
      float exh = __shfl(ex, h2);
      acc[h2] += exh * hs[h2 * FC + lane];
    }
  }
  if (LAYER == 1) {
#pragma unroll
    for (int h2 = 0; h2 < FH; ++h2) {
      float dh = __shfl(den, h2);
      float val = acc[h2] / (dh + 1e-16f) + bias[h2 * FC + lane];
      outp[(size_t)n * FHC + h2 * FC + lane] = val > 0.f ? val : expm1f(val);
    }
  } else {
    float sm = 0.f;
#pragma unroll
    for (int h2 = 0; h2 < FH; ++h2) {
      float dh = __shfl(den, h2);
      sm += acc[h2] / (dh + 1e-16f);
    }
    float val = sm * (1.f / FH) + bias[lane];
    val = val > 0.f ? val : expm1f(val);
    atomicAdd(&pool[batch[n] * FC + lane], val);
  }
}

// ---- final: mean pool ----
__global__ __launch_bounds__(256) void final_k(const float* __restrict__ pool,
                                               const float* __restrict__ cnt,
                                               float* __restrict__ out) {
  int t = blockIdx.x * 256 + threadIdx.x;
  if (t >= NG * FC) return;
  int g = t >> 6;
  out[t] = pool[t] / fmaxf(cnt[g], 1.f);
}

extern "C" void kernel_launch(void* const* d_in, const int* in_sizes, int n_in,
                              void* d_out, int out_size, void* d_ws, size_t ws_size,
                              hipStream_t stream) {
  const float* x    = (const float*)d_in[0];
  const int*   ei   = (const int*)d_in[1];
  const int*   batch= (const int*)d_in[2];
  const float* W1   = (const float*)d_in[3];
  const float* as1  = (const float*)d_in[4];
  const float* ad1  = (const float*)d_in[5];
  const float* b1   = (const float*)d_in[6];
  const float* W2   = (const float*)d_in[7];
  const float* as2  = (const float*)d_in[8];
  const float* ad2  = (const float*)d_in[9];
  const float* b2   = (const float*)d_in[10];
  float* out = (float*)d_out;

  float* bufA = (float*)d_ws;                         // [NN, 512]
  float* bufB = bufA + (size_t)NN * FHC;              // [NN, 512]
  float* asrc = bufB + (size_t)NN * FHC;              // [NN, 8]
  float* adst = asrc + (size_t)NN * FH;               // [NN, 8]
  int* deg    = (int*)(adst + (size_t)NN * FH);       // [NN]
  int* rowp   = deg + NN;                             // [NN+1]
  int* cursor = rowp + NN + 1;                        // [NN]
  int* col    = cursor + NN;                          // [NET]
  float* pool = (float*)(col + NET);                  // [64, 64]
  float* cnt  = pool + NG * FC;                       // [64]

  const dim3 gemm_grid(FHC / 64, (NN + 63) / 64);
  const int egrid = (NET + 255) / 256;
  const int ngrid = (NN + 3) / 4;

  // ---- CSR build (shared by both layers) + counts ----
  hipMemsetAsync(deg, 0, (size_t)NN * 4, stream);
  hipMemsetAsync(pool, 0, (size_t)(NG * FC + NG) * 4, stream);
  hist_k<<<egrid, 256, 0, stream>>>(ei, deg);
  scan_k<<<1, 1024, 0, stream>>>(deg, rowp, cursor);
  fill_k<<<egrid, 256, 0, stream>>>(ei, cursor, col);
  cnt_k<<<(NN + 255) / 256, 256, 0, stream>>>(batch, cnt);

  // ---- layer 1 ----
  gemm64<<<gemm_grid, 256, 0, stream>>>(x, W1, bufA, NN, FHC, FIN);
  alphas_k<<<NN, 512, 0, stream>>>(bufA, as1, ad1, asrc, adst);
  gather_k<1><<<ngrid, 256, 0, stream>>>(rowp, col, asrc, adst, bufA, b1,
                                         nullptr, bufB, nullptr);

  // ---- layer 2 ----
  gemm64<<<gemm_grid, 256, 0, stream>>>(bufB, W2, bufA, NN, FHC, FHC);
  alphas_k<<<NN, 512, 0, stream>>>(bufA, as2, ad2, asrc, adst);
  gather_k<2><<<ngrid, 256, 0, stream>>>(rowp, col, asrc, adst, bufA, b2,
                                         batch, nullptr, pool);

  final_k<<<(NG * FC + 255) / 256, 256, 0, stream>>>(pool, cnt, out);
}

// Round 3
// 1132.469 us; speedup vs baseline: 2.2710x; 1.2538x over previous
//
#include <hip/hip_runtime.h>
#include <hip/hip_bf16.h>
#include <math.h>

// Problem constants (from reference setup_inputs)
#define NN   50000      // nodes
#define NE   400000     // edges (without self loops)
#define NET  450000     // edges + self loops
#define FH   8          // heads
#define FC   64         // channels per head
#define FHC  512        // H*C
#define FIN  128        // input features
#define NG   64         // graphs
#define MPAD 50048      // NN padded to tile multiple (391*128)

typedef unsigned short ushort_t;
typedef __bf16 bf16x8 __attribute__((ext_vector_type(8)));
typedef float f32x4 __attribute__((ext_vector_type(4)));

// ---- f32 -> bf16 (RNE) bit helpers ----
static __device__ __forceinline__ unsigned short f2bf(float f) {
  unsigned u = __float_as_uint(f);
  unsigned r = (u + 0x7fffu + ((u >> 16) & 1u)) >> 16;
  return (unsigned short)r;
}
static __device__ __forceinline__ float bf2f(unsigned short h) {
  return __uint_as_float(((unsigned)h) << 16);
}

// ---- split-convert: f32 -> (hi, lo) bf16 planes, 4 elems/thread ----
__global__ __launch_bounds__(256) void conv_split_k(const float* __restrict__ in,
                                                    unsigned short* __restrict__ hi,
                                                    unsigned short* __restrict__ lo,
                                                    int n4) {
  int t = blockIdx.x * 256 + threadIdx.x;
  if (t >= n4) return;
  float4 f = reinterpret_cast<const float4*>(in)[t];
  ushort4 h, l;
  h.x = f2bf(f.x); l.x = f2bf(f.x - bf2f(h.x));
  h.y = f2bf(f.y); l.y = f2bf(f.y - bf2f(h.y));
  h.z = f2bf(f.z); l.z = f2bf(f.z - bf2f(h.z));
  h.w = f2bf(f.w); l.w = f2bf(f.w - bf2f(h.w));
  reinterpret_cast<ushort4*>(hi)[t] = h;
  reinterpret_cast<ushort4*>(lo)[t] = l;
}

// ---- W [K,512] -> transposed hi/lo planes Wt [512,K] ----
__global__ __launch_bounds__(256) void conv_wt_k(const float* __restrict__ W,
                                                 unsigned short* __restrict__ hiT,
                                                 unsigned short* __restrict__ loT,
                                                 int K) {
  int t = blockIdx.x * 256 + threadIdx.x;
  if (t >= K * FHC) return;
  int k = t >> 9, n = t & 511;
  float f = W[t];
  unsigned short h = f2bf(f);
  hiT[n * K + k] = h;
  loT[n * K + k] = f2bf(f - bf2f(h));
}

// ---- split-bf16 MFMA GEMM: C[M,512] = (Ah+Al)[M,K] @ (Wh+Wl)^T ----
// A planes: [MPAD, K] bf16 row-major. B planes: [512, K] bf16 (W transposed).
// 128x128 tile, 4 waves, each 64x64 via 4x4 frags of mfma_f32_16x16x32_bf16.
__global__ __launch_bounds__(256) void gemm_mfma(const unsigned short* __restrict__ Ah,
                                                 const unsigned short* __restrict__ Al,
                                                 const unsigned short* __restrict__ Bh,
                                                 const unsigned short* __restrict__ Bl,
                                                 float* __restrict__ C,
                                                 int M, int K) {
  __shared__ unsigned short As[128 * 64];  // [m][k] 16 KB
  __shared__ unsigned short Bs[128 * 64];  // [n][k] 16 KB
  const int tid = threadIdx.x;
  const int bm = blockIdx.y * 128;
  const int bn = blockIdx.x * 128;
  const int wv = tid >> 6, l = tid & 63;
  const int wr = wv >> 1, wc = wv & 1;
  const int fr = l & 15, fq = l >> 4;

  f32x4 acc[4][4] = {};

  for (int pass = 0; pass < 3; ++pass) {
    const unsigned short* Ap = (pass == 2) ? Al : Ah;
    const unsigned short* Bp = (pass == 1) ? Bl : Bh;
    for (int k0 = 0; k0 < K; k0 += 64) {
      __syncthreads();  // previous compute done before restage
#pragma unroll
      for (int i = 0; i < 4; ++i) {  // A tile: 128 rows x 64 k
        int idx = i * 256 + tid;
        int row = idx >> 3, c8 = idx & 7;
        const unsigned short* g = Ap + (size_t)(bm + row) * K + k0 + c8 * 8;
        __builtin_amdgcn_global_load_lds(
            (const __attribute__((address_space(1))) void*)g,
            (__attribute__((address_space(3))) void*)(As + idx * 8), 16, 0, 0);
      }
#pragma unroll
      for (int i = 0; i < 4; ++i) {  // B tile: 128 n-rows x 64 k
        int idx = i * 256 + tid;
        int row = idx >> 3, c8 = idx & 7;
        const unsigned short* g = Bp + (size_t)(bn + row) * K + k0 + c8 * 8;
        __builtin_amdgcn_global_load_lds(
            (const __attribute__((address_space(1))) void*)g,
            (__attribute__((address_space(3))) void*)(Bs + idx * 8), 16, 0, 0);
      }
      __syncthreads();  // drains vmcnt, tiles visible
#pragma unroll
      for (int kk = 0; kk < 2; ++kk) {
        bf16x8 af[4], bfv[4];
#pragma unroll
        for (int mi = 0; mi < 4; ++mi)
          af[mi] = *reinterpret_cast<const bf16x8*>(
              As + (wr * 64 + mi * 16 + fr) * 64 + kk * 32 + fq * 8);
#pragma unroll
        for (int ni = 0; ni < 4; ++ni)
          bfv[ni] = *reinterpret_cast<const bf16x8*>(
              Bs + (wc * 64 + ni * 16 + fr) * 64 + kk * 32 + fq * 8);
#pragma unroll
        for (int mi = 0; mi < 4; ++mi)
#pragma unroll
          for (int ni = 0; ni < 4; ++ni)
            acc[mi][ni] = __builtin_amdgcn_mfma_f32_16x16x32_bf16(
                af[mi], bfv[ni], acc[mi][ni], 0, 0, 0);
      }
    }
  }
#pragma unroll
  for (int mi = 0; mi < 4; ++mi)
#pragma unroll
    for (int ni = 0; ni < 4; ++ni) {
      int r0 = bm + wr * 64 + mi * 16 + fq * 4;
      int c0 = bn + wc * 64 + ni * 16 + fr;
#pragma unroll
      for (int j = 0; j < 4; ++j)
        if (r0 + j < M) C[(size_t)(r0 + j) * FHC + c0] = acc[mi][ni][j];
    }
}

// ---- per-node attention logits ----
__global__ __launch_bounds__(512) void alphas_k(const float* __restrict__ h,
                                                const float* __restrict__ a_src,
                                                const float* __restrict__ a_dst,
                                                float* __restrict__ asrc,
                                                float* __restrict__ adst) {
  int n = blockIdx.x;
  int v = threadIdx.x;
  float hv = h[(size_t)n * FHC + v];
  float ps = hv * a_src[v];
  float pd = hv * a_dst[v];
#pragma unroll
  for (int off = 32; off; off >>= 1) {
    ps += __shfl_down(ps, off);
    pd += __shfl_down(pd, off);
  }
  if ((v & 63) == 0) {
    int hh = v >> 6;
    asrc[n * FH + hh] = ps;
    adst[n * FH + hh] = pd;
  }
}

// ---- CSR build: histogram of dst ----
__global__ __launch_bounds__(256) void hist_k(const int* __restrict__ ei,
                                              int* __restrict__ deg) {
  int e = blockIdx.x * 256 + threadIdx.x;
  if (e >= NET) return;
  int d = (e < NE) ? ei[NE + e] : e - NE;
  atomicAdd(&deg[d], 1);
}

// ---- CSR build: exclusive scan (single block) ----
__global__ __launch_bounds__(1024) void scan_k(const int* __restrict__ deg,
                                               int* __restrict__ row_ptr,
                                               int* __restrict__ cursor) {
  __shared__ int part[1024];
  int t = threadIdx.x;
  const int CH = (NN + 1023) / 1024;  // 49
  int base = t * CH;
  int s = 0;
  for (int i = 0; i < CH; ++i) {
    int idx = base + i;
    if (idx < NN) s += deg[idx];
  }
  part[t] = s;
  __syncthreads();
  for (int off = 1; off < 1024; off <<= 1) {
    int add = (t >= off) ? part[t - off] : 0;
    __syncthreads();
    part[t] += add;
    __syncthreads();
  }
  int run = part[t] - s;
  for (int i = 0; i < CH; ++i) {
    int idx = base + i;
    if (idx < NN) {
      row_ptr[idx] = run;
      cursor[idx] = run;
      run += deg[idx];
    }
  }
  if (t == 1023) row_ptr[NN] = part[1023];
}

// ---- CSR build: fill src ids per dst bucket ----
__global__ __launch_bounds__(256) void fill_k(const int* __restrict__ ei,
                                              int* __restrict__ cursor,
                                              int* __restrict__ col_src) {
  int e = blockIdx.x * 256 + threadIdx.x;
  if (e >= NET) return;
  int s, d;
  if (e < NE) { s = ei[e]; d = ei[NE + e]; } else { s = d = e - NE; }
  int pos = atomicAdd(&cursor[d], 1);
  col_src[pos] = s;
}

// ---- nodes-per-graph histogram ----
__global__ __launch_bounds__(256) void cnt_k(const int* __restrict__ batch,
                                             float* __restrict__ cnt) {
  int n = blockIdx.x * 256 + threadIdx.x;
  if (n >= NN) return;
  atomicAdd(&cnt[batch[n]], 1.f);
}

// ---- gather-aggregate: one wave per dst node; fused max/softmax/agg/epilogue
// LAYER==1: normalize + b1 + ELU -> split bf16 hi/lo planes (GEMM2 A input)
// LAYER==2: normalize + head-mean + b2 + ELU -> atomic pool[batch[n]*64+c]
template <int LAYER>
__global__ __launch_bounds__(256) void gather_k(const int* __restrict__ row_ptr,
                                                const int* __restrict__ col_src,
                                                const float* __restrict__ asrc,
                                                const float* __restrict__ adst,
                                                const float* __restrict__ h,
                                                const float* __restrict__ bias,
                                                const int* __restrict__ batch,
                                                unsigned short* __restrict__ outh,
                                                unsigned short* __restrict__ outl,
                                                float* __restrict__ pool) {
  int n = blockIdx.x * 4 + (threadIdx.x >> 6);
  if (n >= NN) return;
  int lane = threadIdx.x & 63;
  int hh = lane & 7;
  int start = row_ptr[n], end = row_ptr[n + 1];
  float adn = adst[n * FH + hh];
  float mx = -1e30f;
  for (int j = start; j < end; ++j) {
    int s = col_src[j];
    float el = asrc[s * FH + hh] + adn;
    el = el > 0.f ? el : 0.2f * el;
    mx = fmaxf(mx, el);
  }
  float den = 0.f;
  float acc[FH] = {};
  for (int j = start; j < end; ++j) {
    int s = col_src[j];
    float el = asrc[s * FH + hh] + adn;
    el = el > 0.f ? el : 0.2f * el;
    float ex = __expf(el - mx);
    den += ex;
    const float* hs = h + (size_t)s * FHC;
#pragma unroll
    for (int h2 = 0; h2 < FH; ++h2) {
      float exh = __shfl(ex, h2);
      acc[h2] += exh * hs[h2 * FC + lane];
    }
  }
  if (LAYER == 1) {
#pragma unroll
    for (int h2 = 0; h2 < FH; ++h2) {
      float dh = __shfl(den, h2);
      float val = acc[h2] / (dh + 1e-16f) + bias[h2 * FC + lane];
      val = val > 0.f ? val : expm1f(val);
      unsigned short hb = f2bf(val);
      size_t o = (size_t)n * FHC + h2 * FC + lane;
      outh[o] = hb;
      outl[o] = f2bf(val - bf2f(hb));
    }
  } else {
    float sm = 0.f;
#pragma unroll
    for (int h2 = 0; h2 < FH; ++h2) {
      float dh = __shfl(den, h2);
      sm += acc[h2] / (dh + 1e-16f);
    }
    float val = sm * (1.f / FH) + bias[lane];
    val = val > 0.f ? val : expm1f(val);
    atomicAdd(&pool[batch[n] * FC + lane], val);
  }
}

// ---- final: mean pool ----
__global__ __launch_bounds__(256) void final_k(const float* __restrict__ pool,
                                               const float* __restrict__ cnt,
                                               float* __restrict__ out) {
  int t = blockIdx.x * 256 + threadIdx.x;
  if (t >= NG * FC) return;
  int g = t >> 6;
  out[t] = pool[t] / fmaxf(cnt[g], 1.f);
}

extern "C" void kernel_launch(void* const* d_in, const int* in_sizes, int n_in,
                              void* d_out, int out_size, void* d_ws, size_t ws_size,
                              hipStream_t stream) {
  const float* x    = (const float*)d_in[0];
  const int*   ei   = (const int*)d_in[1];
  const int*   batch= (const int*)d_in[2];
  const float* W1   = (const float*)d_in[3];
  const float* as1  = (const float*)d_in[4];
  const float* ad1  = (const float*)d_in[5];
  const float* b1   = (const float*)d_in[6];
  const float* W2   = (const float*)d_in[7];
  const float* as2  = (const float*)d_in[8];
  const float* ad2  = (const float*)d_in[9];
  const float* b2   = (const float*)d_in[10];
  float* out = (float*)d_out;

  char* p = (char*)d_ws;
  float* bufC = (float*)p;            p += (size_t)NN * FHC * 4;     // 102.4 MB
  unsigned short* xh  = (unsigned short*)p; p += (size_t)MPAD * FIN * 2;
  unsigned short* xl  = (unsigned short*)p; p += (size_t)MPAD * FIN * 2;
  unsigned short* h1h = (unsigned short*)p; p += (size_t)MPAD * FHC * 2;
  unsigned short* h1l = (unsigned short*)p; p += (size_t)MPAD * FHC * 2;
  unsigned short* w1h = (unsigned short*)p; p += (size_t)FHC * FIN * 2;
  unsigned short* w1l = (unsigned short*)p; p += (size_t)FHC * FIN * 2;
  unsigned short* w2h = (unsigned short*)p; p += (size_t)FHC * FHC * 2;
  unsigned short* w2l = (unsigned short*)p; p += (size_t)FHC * FHC * 2;
  float* asrc = (float*)p;            p += (size_t)NN * FH * 4;
  float* adst = (float*)p;            p += (size_t)NN * FH * 4;
  int* deg    = (int*)p;              p += (size_t)NN * 4;
  int* rowp   = (int*)p;              p += (size_t)(NN + 1) * 4;
  int* cursor = (int*)p;              p += (size_t)NN * 4;
  int* col    = (int*)p;              p += (size_t)NET * 4;
  float* pool = (float*)p;            p += (size_t)NG * FC * 4;
  float* cnt  = (float*)p;            p += (size_t)NG * 4;

  const dim3 ggrid(FHC / 128, (MPAD) / 128);   // (4, 391)
  const int egrid = (NET + 255) / 256;
  const int ngrid = (NN + 3) / 4;

  // ---- zero-init: deg, pool+cnt, pad rows of A planes ----
  hipMemsetAsync(deg, 0, (size_t)NN * 4, stream);
  hipMemsetAsync(pool, 0, (size_t)(NG * FC + NG) * 4, stream);
  hipMemsetAsync(xh + (size_t)NN * FIN, 0, (size_t)(MPAD - NN) * FIN * 2, stream);
  hipMemsetAsync(xl + (size_t)NN * FIN, 0, (size_t)(MPAD - NN) * FIN * 2, stream);
  hipMemsetAsync(h1h + (size_t)NN * FHC, 0, (size_t)(MPAD - NN) * FHC * 2, stream);
  hipMemsetAsync(h1l + (size_t)NN * FHC, 0, (size_t)(MPAD - NN) * FHC * 2, stream);

  // ---- conversions ----
  conv_split_k<<<(NN * FIN / 4 + 255) / 256, 256, 0, stream>>>(x, xh, xl, NN * FIN / 4);
  conv_wt_k<<<(FIN * FHC + 255) / 256, 256, 0, stream>>>(W1, w1h, w1l, FIN);
  conv_wt_k<<<(FHC * FHC + 255) / 256, 256, 0, stream>>>(W2, w2h, w2l, FHC);

  // ---- CSR build + counts ----
  hist_k<<<egrid, 256, 0, stream>>>(ei, deg);
  scan_k<<<1, 1024, 0, stream>>>(deg, rowp, cursor);
  fill_k<<<egrid, 256, 0, stream>>>(ei, cursor, col);
  cnt_k<<<(NN + 255) / 256, 256, 0, stream>>>(batch, cnt);

  // ---- layer 1 ----
  gemm_mfma<<<ggrid, 256, 0, stream>>>(xh, xl, w1h, w1l, bufC, NN, FIN);
  alphas_k<<<NN, 512, 0, stream>>>(bufC, as1, ad1, asrc, adst);
  gather_k<1><<<ngrid, 256, 0, stream>>>(rowp, col, asrc, adst, bufC, b1,
                                         nullptr, h1h, h1l, nullptr);

  // ---- layer 2 ----
  gemm_mfma<<<ggrid, 256, 0, stream>>>(h1h, h1l, w2h, w2l, bufC, NN, FHC);
  alphas_k<<<NN, 512, 0, stream>>>(bufC, as2, ad2, asrc, adst);
  gather_k<2><<<ngrid, 256, 0, stream>>>(rowp, col, asrc, adst, bufC, b2,
                                         batch, nullptr, nullptr, pool);

  final_k<<<(NG * FC + 255) / 256, 256, 0, stream>>>(pool, cnt, out);
}

// Round 4
// 837.724 us; speedup vs baseline: 3.0701x; 1.3518x over previous
//
#include <hip/hip_runtime.h>
#include <hip/hip_bf16.h>
#include <math.h>

// Problem constants (from reference setup_inputs)
#define NN   50000      // nodes
#define NE   400000     // edges (without self loops)
#define NET  450000     // edges + self loops
#define FH   8          // heads
#define FC   64         // channels per head
#define FHC  512        // H*C
#define FIN  128        // input features
#define NG   64         // graphs
#define MPAD 50048      // NN padded to tile multiple (391*128)

typedef unsigned short ushort_t;
typedef __bf16 bf16x8 __attribute__((ext_vector_type(8)));
typedef float f32x4 __attribute__((ext_vector_type(4)));

// ---- f32 -> bf16 (RNE) bit helpers ----
static __device__ __forceinline__ unsigned short f2bf(float f) {
  unsigned u = __float_as_uint(f);
  unsigned r = (u + 0x7fffu + ((u >> 16) & 1u)) >> 16;
  return (unsigned short)r;
}
static __device__ __forceinline__ float bf2f(unsigned short h) {
  return __uint_as_float(((unsigned)h) << 16);
}

// ---- split-convert: f32 -> (hi, lo) bf16 planes, 4 elems/thread ----
__global__ __launch_bounds__(256) void conv_split_k(const float* __restrict__ in,
                                                    unsigned short* __restrict__ hi,
                                                    unsigned short* __restrict__ lo,
                                                    int n4) {
  int t = blockIdx.x * 256 + threadIdx.x;
  if (t >= n4) return;
  float4 f = reinterpret_cast<const float4*>(in)[t];
  ushort4 h, l;
  h.x = f2bf(f.x); l.x = f2bf(f.x - bf2f(h.x));
  h.y = f2bf(f.y); l.y = f2bf(f.y - bf2f(h.y));
  h.z = f2bf(f.z); l.z = f2bf(f.z - bf2f(h.z));
  h.w = f2bf(f.w); l.w = f2bf(f.w - bf2f(h.w));
  reinterpret_cast<ushort4*>(hi)[t] = h;
  reinterpret_cast<ushort4*>(lo)[t] = l;
}

// ---- W [K,512] -> transposed hi/lo planes Wt [512,K] ----
__global__ __launch_bounds__(256) void conv_wt_k(const float* __restrict__ W,
                                                 unsigned short* __restrict__ hiT,
                                                 unsigned short* __restrict__ loT,
                                                 int K) {
  int t = blockIdx.x * 256 + threadIdx.x;
  if (t >= K * FHC) return;
  int k = t >> 9, n = t & 511;
  float f = W[t];
  unsigned short h = f2bf(f);
  hiT[n * K + k] = h;
  loT[n * K + k] = f2bf(f - bf2f(h));
}

// ---- split-bf16 MFMA GEMM: C[M,512] = (Ah+Al)[M,K] @ (Wh+Wl)^T ----
__global__ __launch_bounds__(256) void gemm_mfma(const unsigned short* __restrict__ Ah,
                                                 const unsigned short* __restrict__ Al,
                                                 const unsigned short* __restrict__ Bh,
                                                 const unsigned short* __restrict__ Bl,
                                                 float* __restrict__ C,
                                                 int M, int K) {
  __shared__ unsigned short As[128 * 64];  // [m][k] 16 KB
  __shared__ unsigned short Bs[128 * 64];  // [n][k] 16 KB
  const int tid = threadIdx.x;
  const int bm = blockIdx.y * 128;
  const int bn = blockIdx.x * 128;
  const int wv = tid >> 6, l = tid & 63;
  const int wr = wv >> 1, wc = wv & 1;
  const int fr = l & 15, fq = l >> 4;

  f32x4 acc[4][4] = {};

  for (int pass = 0; pass < 3; ++pass) {
    const unsigned short* Ap = (pass == 2) ? Al : Ah;
    const unsigned short* Bp = (pass == 1) ? Bl : Bh;
    for (int k0 = 0; k0 < K; k0 += 64) {
      __syncthreads();
#pragma unroll
      for (int i = 0; i < 4; ++i) {  // A tile: 128 rows x 64 k
        int idx = i * 256 + tid;
        int row = idx >> 3, c8 = idx & 7;
        const unsigned short* g = Ap + (size_t)(bm + row) * K + k0 + c8 * 8;
        __builtin_amdgcn_global_load_lds(
            (const __attribute__((address_space(1))) void*)g,
            (__attribute__((address_space(3))) void*)(As + idx * 8), 16, 0, 0);
      }
#pragma unroll
      for (int i = 0; i < 4; ++i) {  // B tile: 128 n-rows x 64 k
        int idx = i * 256 + tid;
        int row = idx >> 3, c8 = idx & 7;
        const unsigned short* g = Bp + (size_t)(bn + row) * K + k0 + c8 * 8;
        __builtin_amdgcn_global_load_lds(
            (const __attribute__((address_space(1))) void*)g,
            (__attribute__((address_space(3))) void*)(Bs + idx * 8), 16, 0, 0);
      }
      __syncthreads();
#pragma unroll
      for (int kk = 0; kk < 2; ++kk) {
        bf16x8 af[4], bfv[4];
#pragma unroll
        for (int mi = 0; mi < 4; ++mi)
          af[mi] = *reinterpret_cast<const bf16x8*>(
              As + (wr * 64 + mi * 16 + fr) * 64 + kk * 32 + fq * 8);
#pragma unroll
        for (int ni = 0; ni < 4; ++ni)
          bfv[ni] = *reinterpret_cast<const bf16x8*>(
              Bs + (wc * 64 + ni * 16 + fr) * 64 + kk * 32 + fq * 8);
#pragma unroll
        for (int mi = 0; mi < 4; ++mi)
#pragma unroll
          for (int ni = 0; ni < 4; ++ni)
            acc[mi][ni] = __builtin_amdgcn_mfma_f32_16x16x32_bf16(
                af[mi], bfv[ni], acc[mi][ni], 0, 0, 0);
      }
    }
  }
#pragma unroll
  for (int mi = 0; mi < 4; ++mi)
#pragma unroll
    for (int ni = 0; ni < 4; ++ni) {
      int r0 = bm + wr * 64 + mi * 16 + fq * 4;
      int c0 = bn + wc * 64 + ni * 16 + fr;
#pragma unroll
      for (int j = 0; j < 4; ++j)
        if (r0 + j < M) C[(size_t)(r0 + j) * FHC + c0] = acc[mi][ni][j];
    }
}

// ---- per-node attention logits ----
__global__ __launch_bounds__(512) void alphas_k(const float* __restrict__ h,
                                                const float* __restrict__ a_src,
                                                const float* __restrict__ a_dst,
                                                float* __restrict__ asrc,
                                                float* __restrict__ adst) {
  int n = blockIdx.x;
  int v = threadIdx.x;
  float hv = h[(size_t)n * FHC + v];
  float ps = hv * a_src[v];
  float pd = hv * a_dst[v];
#pragma unroll
  for (int off = 32; off; off >>= 1) {
    ps += __shfl_down(ps, off);
    pd += __shfl_down(pd, off);
  }
  if ((v & 63) == 0) {
    int hh = v >> 6;
    asrc[n * FH + hh] = ps;
    adst[n * FH + hh] = pd;
  }
}

// ---- CSR build: histogram of dst ----
__global__ __launch_bounds__(256) void hist_k(const int* __restrict__ ei,
                                              int* __restrict__ deg) {
  int e = blockIdx.x * 256 + threadIdx.x;
  if (e >= NET) return;
  int d = (e < NE) ? ei[NE + e] : e - NE;
  atomicAdd(&deg[d], 1);
}

// ---- CSR build: exclusive scan (single block) ----
__global__ __launch_bounds__(1024) void scan_k(const int* __restrict__ deg,
                                               int* __restrict__ row_ptr,
                                               int* __restrict__ cursor) {
  __shared__ int part[1024];
  int t = threadIdx.x;
  const int CH = (NN + 1023) / 1024;  // 49
  int base = t * CH;
  int s = 0;
  for (int i = 0; i < CH; ++i) {
    int idx = base + i;
    if (idx < NN) s += deg[idx];
  }
  part[t] = s;
  __syncthreads();
  for (int off = 1; off < 1024; off <<= 1) {
    int add = (t >= off) ? part[t - off] : 0;
    __syncthreads();
    part[t] += add;
    __syncthreads();
  }
  int run = part[t] - s;
  for (int i = 0; i < CH; ++i) {
    int idx = base + i;
    if (idx < NN) {
      row_ptr[idx] = run;
      cursor[idx] = run;
      run += deg[idx];
    }
  }
  if (t == 1023) row_ptr[NN] = part[1023];
}

// ---- CSR build: fill src ids per dst bucket ----
__global__ __launch_bounds__(256) void fill_k(const int* __restrict__ ei,
                                              int* __restrict__ cursor,
                                              int* __restrict__ col_src) {
  int e = blockIdx.x * 256 + threadIdx.x;
  if (e >= NET) return;
  int s, d;
  if (e < NE) { s = ei[e]; d = ei[NE + e]; } else { s = d = e - NE; }
  int pos = atomicAdd(&cursor[d], 1);
  col_src[pos] = s;
}

// ---- graph boundary detection (batch is sorted) ----
__global__ __launch_bounds__(256) void bnd_k(const int* __restrict__ batch,
                                             int* __restrict__ gstart,
                                             int* __restrict__ gend) {
  int n = blockIdx.x * 256 + threadIdx.x;
  if (n >= NN) return;
  int b = batch[n];
  if (n == 0 || batch[n - 1] != b) gstart[b] = n;
  if (n == NN - 1 || batch[n + 1] != b) gend[b] = n + 1;
}

// ---- gather-aggregate: one wave per dst node; fused max/softmax/agg/epilogue
// LAYER==1: normalize + b1 + ELU -> split bf16 hi/lo planes (GEMM2 A input)
// LAYER==2: normalize + head-mean + b2 + ELU -> nodeval[n*64+c] (plain store)
template <int LAYER>
__global__ __launch_bounds__(256) void gather_k(const int* __restrict__ row_ptr,
                                                const int* __restrict__ col_src,
                                                const float* __restrict__ asrc,
                                                const float* __restrict__ adst,
                                                const float* __restrict__ h,
                                                const float* __restrict__ bias,
                                                unsigned short* __restrict__ outh,
                                                unsigned short* __restrict__ outl,
                                                float* __restrict__ nodeval) {
  int n = blockIdx.x * 4 + (threadIdx.x >> 6);
  if (n >= NN) return;
  int lane = threadIdx.x & 63;
  int hh = lane & 7;
  int start = row_ptr[n], end = row_ptr[n + 1];
  float adn = adst[n * FH + hh];
  float mx = -1e30f;
  for (int j = start; j < end; ++j) {
    int s = col_src[j];
    float el = asrc[s * FH + hh] + adn;
    el = el > 0.f ? el : 0.2f * el;
    mx = fmaxf(mx, el);
  }
  float den = 0.f;
  float acc[FH] = {};
  for (int j = start; j < end; ++j) {
    int s = col_src[j];
    float el = asrc[s * FH + hh] + adn;
    el = el > 0.f ? el : 0.2f * el;
    float ex = __expf(el - mx);
    den += ex;
    const float* hs = h + (size_t)s * FHC;
#pragma unroll
    for (int h2 = 0; h2 < FH; ++h2) {
      float exh = __shfl(ex, h2);
      acc[h2] += exh * hs[h2 * FC + lane];
    }
  }
  if (LAYER == 1) {
#pragma unroll
    for (int h2 = 0; h2 < FH; ++h2) {
      float dh = __shfl(den, h2);
      float val = acc[h2] / (dh + 1e-16f) + bias[h2 * FC + lane];
      val = val > 0.f ? val : expm1f(val);
      unsigned short hb = f2bf(val);
      size_t o = (size_t)n * FHC + h2 * FC + lane;
      outh[o] = hb;
      outl[o] = f2bf(val - bf2f(hb));
    }
  } else {
    float sm = 0.f;
#pragma unroll
    for (int h2 = 0; h2 < FH; ++h2) {
      float dh = __shfl(den, h2);
      sm += acc[h2] / (dh + 1e-16f);
    }
    float val = sm * (1.f / FH) + bias[lane];
    nodeval[(size_t)n * FC + lane] = val > 0.f ? val : expm1f(val);
  }
}

// ---- pool: one block per graph over its contiguous node range ----
__global__ __launch_bounds__(256) void pool_k(const float* __restrict__ nodeval,
                                              const int* __restrict__ gstart,
                                              const int* __restrict__ gend,
                                              float* __restrict__ out) {
  __shared__ float red[4][FC];
  int g = blockIdx.x;
  int c = threadIdx.x & 63, w = threadIdx.x >> 6;
  int s = gstart[g], e = gend[g];
  float acc = 0.f;
  for (int n = s + w; n < e; n += 4) acc += nodeval[(size_t)n * FC + c];
  red[w][c] = acc;
  __syncthreads();
  if (w == 0) {
    float v = red[0][c] + red[1][c] + red[2][c] + red[3][c];
    out[g * FC + c] = v / fmaxf((float)(e - s), 1.f);
  }
}

extern "C" void kernel_launch(void* const* d_in, const int* in_sizes, int n_in,
                              void* d_out, int out_size, void* d_ws, size_t ws_size,
                              hipStream_t stream) {
  const float* x    = (const float*)d_in[0];
  const int*   ei   = (const int*)d_in[1];
  const int*   batch= (const int*)d_in[2];
  const float* W1   = (const float*)d_in[3];
  const float* as1  = (const float*)d_in[4];
  const float* ad1  = (const float*)d_in[5];
  const float* b1   = (const float*)d_in[6];
  const float* W2   = (const float*)d_in[7];
  const float* as2  = (const float*)d_in[8];
  const float* ad2  = (const float*)d_in[9];
  const float* b2   = (const float*)d_in[10];
  float* out = (float*)d_out;

  char* p = (char*)d_ws;
  float* bufC = (float*)p;            p += (size_t)NN * FHC * 4;     // 102.4 MB
  unsigned short* xh  = (unsigned short*)p; p += (size_t)MPAD * FIN * 2;
  unsigned short* xl  = (unsigned short*)p; p += (size_t)MPAD * FIN * 2;
  unsigned short* h1h = (unsigned short*)p; p += (size_t)MPAD * FHC * 2;
  unsigned short* h1l = (unsigned short*)p; p += (size_t)MPAD * FHC * 2;
  unsigned short* w1h = (unsigned short*)p; p += (size_t)FHC * FIN * 2;
  unsigned short* w1l = (unsigned short*)p; p += (size_t)FHC * FIN * 2;
  unsigned short* w2h = (unsigned short*)p; p += (size_t)FHC * FHC * 2;
  unsigned short* w2l = (unsigned short*)p; p += (size_t)FHC * FHC * 2;
  float* asrc = (float*)p;            p += (size_t)NN * FH * 4;
  float* adst = (float*)p;            p += (size_t)NN * FH * 4;
  int* deg    = (int*)p;              p += (size_t)NN * 4;
  int* rowp   = (int*)p;              p += (size_t)(NN + 1) * 4;
  int* cursor = (int*)p;              p += (size_t)NN * 4;
  int* col    = (int*)p;              p += (size_t)NET * 4;
  int* gstart = (int*)p;              p += (size_t)NG * 4;
  int* gend   = (int*)p;              p += (size_t)NG * 4;
  // nodeval reuses xh's region (dead by the time gather_k<2> runs):
  // NN*64*4 = 12.80 MB <= MPAD*FIN*2 = 12.81 MB
  float* nodeval = (float*)xh;

  const dim3 ggrid(FHC / 128, (MPAD) / 128);   // (4, 391)
  const int egrid = (NET + 255) / 256;
  const int ngrid = (NN + 3) / 4;

  // ---- zero-init: deg, boundaries, pad rows of A planes ----
  hipMemsetAsync(deg, 0, (size_t)NN * 4, stream);
  hipMemsetAsync(gstart, 0, (size_t)NG * 2 * 4, stream);
  hipMemsetAsync(xh + (size_t)NN * FIN, 0, (size_t)(MPAD - NN) * FIN * 2, stream);
  hipMemsetAsync(xl + (size_t)NN * FIN, 0, (size_t)(MPAD - NN) * FIN * 2, stream);
  hipMemsetAsync(h1h + (size_t)NN * FHC, 0, (size_t)(MPAD - NN) * FHC * 2, stream);
  hipMemsetAsync(h1l + (size_t)NN * FHC, 0, (size_t)(MPAD - NN) * FHC * 2, stream);

  // ---- conversions ----
  conv_split_k<<<(NN * FIN / 4 + 255) / 256, 256, 0, stream>>>(x, xh, xl, NN * FIN / 4);
  conv_wt_k<<<(FIN * FHC + 255) / 256, 256, 0, stream>>>(W1, w1h, w1l, FIN);
  conv_wt_k<<<(FHC * FHC + 255) / 256, 256, 0, stream>>>(W2, w2h, w2l, FHC);

  // ---- CSR build + graph boundaries ----
  hist_k<<<egrid, 256, 0, stream>>>(ei, deg);
  scan_k<<<1, 1024, 0, stream>>>(deg, rowp, cursor);
  fill_k<<<egrid, 256, 0, stream>>>(ei, cursor, col);
  bnd_k<<<(NN + 255) / 256, 256, 0, stream>>>(batch, gstart, gend);

  // ---- layer 1 ----
  gemm_mfma<<<ggrid, 256, 0, stream>>>(xh, xl, w1h, w1l, bufC, NN, FIN);
  alphas_k<<<NN, 512, 0, stream>>>(bufC, as1, ad1, asrc, adst);
  gather_k<1><<<ngrid, 256, 0, stream>>>(rowp, col, asrc, adst, bufC, b1,
                                         h1h, h1l, nullptr);

  // ---- layer 2 ----
  gemm_mfma<<<ggrid, 256, 0, stream>>>(h1h, h1l, w2h, w2l, bufC, NN, FHC);
  alphas_k<<<NN, 512, 0, stream>>>(bufC, as2, ad2, asrc, adst);
  gather_k<2><<<ngrid, 256, 0, stream>>>(rowp, col, asrc, adst, bufC, b2,
                                         nullptr, nullptr, nodeval);

  pool_k<<<NG, 256, 0, stream>>>(nodeval, gstart, gend, out);
}

// Round 5
// 702.279 us; speedup vs baseline: 3.6622x; 1.1929x over previous
//
#include <hip/hip_runtime.h>
#include <hip/hip_bf16.h>
#include <math.h>

// Problem constants (from reference setup_inputs)
#define NN   50000      // nodes
#define NE   400000     // edges (without self loops)
#define NET  450000     // edges + self loops
#define FH   8          // heads
#define FC   64         // channels per head
#define FHC  512        // H*C
#define FIN  128        // input features
#define NG   64         // graphs
#define MPAD 50048      // NN padded to tile multiple (391*128)

typedef unsigned short u16;
typedef __bf16 bf16x8 __attribute__((ext_vector_type(8)));
typedef float f32x4 __attribute__((ext_vector_type(4)));
typedef unsigned short u16x8 __attribute__((ext_vector_type(8)));

// ---- f32 -> bf16 (RNE) bit helpers ----
static __device__ __forceinline__ u16 f2bf(float f) {
  unsigned u = __float_as_uint(f);
  unsigned r = (u + 0x7fffu + ((u >> 16) & 1u)) >> 16;
  return (u16)r;
}
static __device__ __forceinline__ float bf2f(u16 h) {
  return __uint_as_float(((unsigned)h) << 16);
}

// ---- split-convert: f32 -> (hi, lo) bf16 planes, 4 elems/thread ----
__global__ __launch_bounds__(256) void conv_split_k(const float* __restrict__ in,
                                                    u16* __restrict__ hi,
                                                    u16* __restrict__ lo,
                                                    int n4) {
  int t = blockIdx.x * 256 + threadIdx.x;
  if (t >= n4) return;
  float4 f = reinterpret_cast<const float4*>(in)[t];
  ushort4 h, l;
  h.x = f2bf(f.x); l.x = f2bf(f.x - bf2f(h.x));
  h.y = f2bf(f.y); l.y = f2bf(f.y - bf2f(h.y));
  h.z = f2bf(f.z); l.z = f2bf(f.z - bf2f(h.z));
  h.w = f2bf(f.w); l.w = f2bf(f.w - bf2f(h.w));
  reinterpret_cast<ushort4*>(hi)[t] = h;
  reinterpret_cast<ushort4*>(lo)[t] = l;
}

// ---- W [K,512] -> transposed hi/lo planes Wt [512,K] ----
__global__ __launch_bounds__(256) void conv_wt_k(const float* __restrict__ W,
                                                 u16* __restrict__ hiT,
                                                 u16* __restrict__ loT,
                                                 int K) {
  int t = blockIdx.x * 256 + threadIdx.x;
  if (t >= K * FHC) return;
  int k = t >> 9, n = t & 511;
  float f = W[t];
  u16 h = f2bf(f);
  hiT[n * K + k] = h;
  loT[n * K + k] = f2bf(f - bf2f(h));
}

// ---- split-bf16 MFMA GEMM, single pass: stage all 4 planes per k-step,
// 3 products (hi*hi + hi*lo + lo*hi) per fragment pair. 128x128 tile, 4 waves.
__global__ __launch_bounds__(256) void gemm_mfma(const u16* __restrict__ Ah,
                                                 const u16* __restrict__ Al,
                                                 const u16* __restrict__ Bh,
                                                 const u16* __restrict__ Bl,
                                                 float* __restrict__ C,
                                                 int M, int K) {
  __shared__ u16 AsH[128 * 64];  // 16 KB each, 64 KB total
  __shared__ u16 AsL[128 * 64];
  __shared__ u16 BsH[128 * 64];
  __shared__ u16 BsL[128 * 64];
  const int tid = threadIdx.x;
  const int bm = blockIdx.y * 128;
  const int bn = blockIdx.x * 128;
  const int wv = tid >> 6, l = tid & 63;
  const int wr = wv >> 1, wc = wv & 1;
  const int fr = l & 15, fq = l >> 4;

  f32x4 acc[4][4] = {};

  for (int k0 = 0; k0 < K; k0 += 64) {
    __syncthreads();
#pragma unroll
    for (int i = 0; i < 4; ++i) {
      int idx = i * 256 + tid;
      int row = idx >> 3, c8 = idx & 7;
      size_t goA = (size_t)(bm + row) * K + k0 + c8 * 8;
      size_t goB = (size_t)(bn + row) * K + k0 + c8 * 8;
      __builtin_amdgcn_global_load_lds(
          (const __attribute__((address_space(1))) void*)(Ah + goA),
          (__attribute__((address_space(3))) void*)(AsH + idx * 8), 16, 0, 0);
      __builtin_amdgcn_global_load_lds(
          (const __attribute__((address_space(1))) void*)(Al + goA),
          (__attribute__((address_space(3))) void*)(AsL + idx * 8), 16, 0, 0);
      __builtin_amdgcn_global_load_lds(
          (const __attribute__((address_space(1))) void*)(Bh + goB),
          (__attribute__((address_space(3))) void*)(BsH + idx * 8), 16, 0, 0);
      __builtin_amdgcn_global_load_lds(
          (const __attribute__((address_space(1))) void*)(Bl + goB),
          (__attribute__((address_space(3))) void*)(BsL + idx * 8), 16, 0, 0);
    }
    __syncthreads();
#pragma unroll
    for (int kk = 0; kk < 2; ++kk) {
      bf16x8 ah[4], al4[4], bh[4], bl4[4];
#pragma unroll
      for (int mi = 0; mi < 4; ++mi) {
        int off = (wr * 64 + mi * 16 + fr) * 64 + kk * 32 + fq * 8;
        ah[mi]  = *reinterpret_cast<const bf16x8*>(AsH + off);
        al4[mi] = *reinterpret_cast<const bf16x8*>(AsL + off);
      }
#pragma unroll
      for (int ni = 0; ni < 4; ++ni) {
        int off = (wc * 64 + ni * 16 + fr) * 64 + kk * 32 + fq * 8;
        bh[ni]  = *reinterpret_cast<const bf16x8*>(BsH + off);
        bl4[ni] = *reinterpret_cast<const bf16x8*>(BsL + off);
      }
#pragma unroll
      for (int mi = 0; mi < 4; ++mi)
#pragma unroll
        for (int ni = 0; ni < 4; ++ni) {
          acc[mi][ni] = __builtin_amdgcn_mfma_f32_16x16x32_bf16(
              ah[mi], bh[ni], acc[mi][ni], 0, 0, 0);
          acc[mi][ni] = __builtin_amdgcn_mfma_f32_16x16x32_bf16(
              ah[mi], bl4[ni], acc[mi][ni], 0, 0, 0);
          acc[mi][ni] = __builtin_amdgcn_mfma_f32_16x16x32_bf16(
              al4[mi], bh[ni], acc[mi][ni], 0, 0, 0);
        }
    }
  }
#pragma unroll
  for (int mi = 0; mi < 4; ++mi)
#pragma unroll
    for (int ni = 0; ni < 4; ++ni) {
      int r0 = bm + wr * 64 + mi * 16 + fq * 4;
      int c0 = bn + wc * 64 + ni * 16 + fr;
#pragma unroll
      for (int j = 0; j < 4; ++j)
        if (r0 + j < M) C[(size_t)(r0 + j) * FHC + c0] = acc[mi][ni][j];
    }
}

// ---- per-node attention logits: one wave per node, 8 floats/lane ----
__global__ __launch_bounds__(256) void alphas_k(const float* __restrict__ h,
                                                const float* __restrict__ a_src,
                                                const float* __restrict__ a_dst,
                                                float* __restrict__ asrc,
                                                float* __restrict__ adst) {
  int n = blockIdx.x * 4 + (threadIdx.x >> 6);
  if (n >= NN) return;
  int lane = threadIdx.x & 63;
  const float4* hp = reinterpret_cast<const float4*>(h + (size_t)n * FHC + lane * 8);
  float4 h0 = hp[0], h1 = hp[1];
  const float4* sp = reinterpret_cast<const float4*>(a_src + lane * 8);
  const float4* dp = reinterpret_cast<const float4*>(a_dst + lane * 8);
  float4 s0 = sp[0], s1 = sp[1], d0 = dp[0], d1 = dp[1];
  float ps = h0.x * s0.x + h0.y * s0.y + h0.z * s0.z + h0.w * s0.w +
             h1.x * s1.x + h1.y * s1.y + h1.z * s1.z + h1.w * s1.w;
  float pd = h0.x * d0.x + h0.y * d0.y + h0.z * d0.z + h0.w * d0.w +
             h1.x * d1.x + h1.y * d1.y + h1.z * d1.z + h1.w * d1.w;
#pragma unroll
  for (int off = 1; off < 8; off <<= 1) {
    ps += __shfl_xor(ps, off);
    pd += __shfl_xor(pd, off);
  }
  if ((lane & 7) == 0) {
    asrc[n * FH + (lane >> 3)] = ps;
    adst[n * FH + (lane >> 3)] = pd;
  }
}

// ---- CSR build: histogram of dst ----
__global__ __launch_bounds__(256) void hist_k(const int* __restrict__ ei,
                                              int* __restrict__ deg) {
  int e = blockIdx.x * 256 + threadIdx.x;
  if (e >= NET) return;
  int d = (e < NE) ? ei[NE + e] : e - NE;
  atomicAdd(&deg[d], 1);
}

// ---- CSR build: exclusive scan (single block) ----
__global__ __launch_bounds__(1024) void scan_k(const int* __restrict__ deg,
                                               int* __restrict__ row_ptr,
                                               int* __restrict__ cursor) {
  __shared__ int part[1024];
  int t = threadIdx.x;
  const int CH = (NN + 1023) / 1024;  // 49
  int base = t * CH;
  int s = 0;
  for (int i = 0; i < CH; ++i) {
    int idx = base + i;
    if (idx < NN) s += deg[idx];
  }
  part[t] = s;
  __syncthreads();
  for (int off = 1; off < 1024; off <<= 1) {
    int add = (t >= off) ? part[t - off] : 0;
    __syncthreads();
    part[t] += add;
    __syncthreads();
  }
  int run = part[t] - s;
  for (int i = 0; i < CH; ++i) {
    int idx = base + i;
    if (idx < NN) {
      row_ptr[idx] = run;
      cursor[idx] = run;
      run += deg[idx];
    }
  }
  if (t == 1023) row_ptr[NN] = part[1023];
}

// ---- CSR build: fill src ids per dst bucket ----
__global__ __launch_bounds__(256) void fill_k(const int* __restrict__ ei,
                                              int* __restrict__ cursor,
                                              int* __restrict__ col_src) {
  int e = blockIdx.x * 256 + threadIdx.x;
  if (e >= NET) return;
  int s, d;
  if (e < NE) { s = ei[e]; d = ei[NE + e]; } else { s = d = e - NE; }
  int pos = atomicAdd(&cursor[d], 1);
  col_src[pos] = s;
}

// ---- graph boundary detection (batch is sorted) ----
__global__ __launch_bounds__(256) void bnd_k(const int* __restrict__ batch,
                                             int* __restrict__ gstart,
                                             int* __restrict__ gend) {
  int n = blockIdx.x * 256 + threadIdx.x;
  if (n >= NN) return;
  int b = batch[n];
  if (n == 0 || batch[n - 1] != b) gstart[b] = n;
  if (n == NN - 1 || batch[n + 1] != b) gend[b] = n + 1;
}

// ---- gather-aggregate: one wave per dst node, 8 floats/lane.
// No max-subtraction: logits bounded (|e| < ~10), exp(e) safe in f32, and
// alpha = exp(e)/sum exp(e) is mathematically identical to the max-shifted form.
// Lane L holds row elements [L*8, L*8+8) = head L>>3, channels ((L&7)*8..+8).
// Lanes 0..7 compute ex/den for heads 0..7 (all lanes duplicate via &7).
// LAYER==1: normalize + b1 + ELU -> split bf16 hi/lo planes (GEMM2 A input)
// LAYER==2: normalize + head-mean + b2 + ELU -> nodeval[n*64+c]
template <int LAYER>
__global__ __launch_bounds__(256) void gather_k(const int* __restrict__ row_ptr,
                                                const int* __restrict__ col_src,
                                                const float* __restrict__ asrc,
                                                const float* __restrict__ adst,
                                                const float* __restrict__ h,
                                                const float* __restrict__ bias,
                                                u16* __restrict__ outh,
                                                u16* __restrict__ outl,
                                                float* __restrict__ nodeval) {
  int n = blockIdx.x * 4 + (threadIdx.x >> 6);
  if (n >= NN) return;
  int lane = threadIdx.x & 63;
  int hh = lane & 7;       // head this lane computes alpha for
  int hsel = lane >> 3;    // head this lane accumulates channels of
  int start = row_ptr[n], end = row_ptr[n + 1];
  float adn = adst[n * FH + hh];
  float den = 0.f;
  float4 a0 = make_float4(0.f, 0.f, 0.f, 0.f);
  float4 a1 = make_float4(0.f, 0.f, 0.f, 0.f);
  for (int j = start; j < end; ++j) {
    int s = col_src[j];
    float el = asrc[s * FH + hh] + adn;
    el = el > 0.f ? el : 0.2f * el;
    float ex = __expf(el);
    den += ex;
    float exv = __shfl(ex, hsel);
    const float4* hp = reinterpret_cast<const float4*>(h + (size_t)s * FHC + lane * 8);
    float4 v0 = hp[0], v1 = hp[1];
    a0.x += exv * v0.x; a0.y += exv * v0.y; a0.z += exv * v0.z; a0.w += exv * v0.w;
    a1.x += exv * v1.x; a1.y += exv * v1.y; a1.z += exv * v1.z; a1.w += exv * v1.w;
  }
  float dh = __shfl(den, hsel);
  float inv = 1.f / (dh + 1e-16f);
  float v[8] = {a0.x * inv, a0.y * inv, a0.z * inv, a0.w * inv,
                a1.x * inv, a1.y * inv, a1.z * inv, a1.w * inv};
  if (LAYER == 1) {
    const float4* bp = reinterpret_cast<const float4*>(bias + lane * 8);
    float4 b0 = bp[0], b1 = bp[1];
    float bb[8] = {b0.x, b0.y, b0.z, b0.w, b1.x, b1.y, b1.z, b1.w};
    u16x8 hv, lv;
#pragma unroll
    for (int j = 0; j < 8; ++j) {
      float val = v[j] + bb[j];
      val = val > 0.f ? val : expm1f(val);
      u16 hb = f2bf(val);
      hv[j] = hb;
      lv[j] = f2bf(val - bf2f(hb));
    }
    *reinterpret_cast<u16x8*>(outh + (size_t)n * FHC + lane * 8) = hv;
    *reinterpret_cast<u16x8*>(outl + (size_t)n * FHC + lane * 8) = lv;
  } else {
    // head-mean: sum across lanes with same (lane&7) -> xor bits 3,4,5
#pragma unroll
    for (int off = 8; off < 64; off <<= 1)
#pragma unroll
      for (int j = 0; j < 8; ++j) v[j] += __shfl_xor(v[j], off);
    if (lane < 8) {
      const float4* bp = reinterpret_cast<const float4*>(bias + lane * 8);
      float4 b0 = bp[0], b1 = bp[1];
      float bb[8] = {b0.x, b0.y, b0.z, b0.w, b1.x, b1.y, b1.z, b1.w};
      float o[8];
#pragma unroll
      for (int j = 0; j < 8; ++j) {
        float val = v[j] * (1.f / FH) + bb[j];
        o[j] = val > 0.f ? val : expm1f(val);
      }
      float4* np = reinterpret_cast<float4*>(nodeval + (size_t)n * FC + lane * 8);
      np[0] = make_float4(o[0], o[1], o[2], o[3]);
      np[1] = make_float4(o[4], o[5], o[6], o[7]);
    }
  }
}

// ---- pool: one block per graph over its contiguous node range ----
__global__ __launch_bounds__(256) void pool_k(const float* __restrict__ nodeval,
                                              const int* __restrict__ gstart,
                                              const int* __restrict__ gend,
                                              float* __restrict__ out) {
  __shared__ float red[4][FC];
  int g = blockIdx.x;
  int c = threadIdx.x & 63, w = threadIdx.x >> 6;
  int s = gstart[g], e = gend[g];
  float acc = 0.f;
  for (int n = s + w; n < e; n += 4) acc += nodeval[(size_t)n * FC + c];
  red[w][c] = acc;
  __syncthreads();
  if (w == 0) {
    float v = red[0][c] + red[1][c] + red[2][c] + red[3][c];
    out[g * FC + c] = v / fmaxf((float)(e - s), 1.f);
  }
}

extern "C" void kernel_launch(void* const* d_in, const int* in_sizes, int n_in,
                              void* d_out, int out_size, void* d_ws, size_t ws_size,
                              hipStream_t stream) {
  const float* x    = (const float*)d_in[0];
  const int*   ei   = (const int*)d_in[1];
  const int*   batch= (const int*)d_in[2];
  const float* W1   = (const float*)d_in[3];
  const float* as1  = (const float*)d_in[4];
  const float* ad1  = (const float*)d_in[5];
  const float* b1   = (const float*)d_in[6];
  const float* W2   = (const float*)d_in[7];
  const float* as2  = (const float*)d_in[8];
  const float* ad2  = (const float*)d_in[9];
  const float* b2   = (const float*)d_in[10];
  float* out = (float*)d_out;

  char* p = (char*)d_ws;
  float* bufC = (float*)p;            p += (size_t)NN * FHC * 4;     // 102.4 MB
  u16* xh  = (u16*)p; p += (size_t)MPAD * FIN * 2;
  u16* xl  = (u16*)p; p += (size_t)MPAD * FIN * 2;
  u16* h1h = (u16*)p; p += (size_t)MPAD * FHC * 2;
  u16* h1l = (u16*)p; p += (size_t)MPAD * FHC * 2;
  u16* w1h = (u16*)p; p += (size_t)FHC * FIN * 2;
  u16* w1l = (u16*)p; p += (size_t)FHC * FIN * 2;
  u16* w2h = (u16*)p; p += (size_t)FHC * FHC * 2;
  u16* w2l = (u16*)p; p += (size_t)FHC * FHC * 2;
  float* asrc = (float*)p;            p += (size_t)NN * FH * 4;
  float* adst = (float*)p;            p += (size_t)NN * FH * 4;
  int* deg    = (int*)p;              p += (size_t)NN * 4;
  int* rowp   = (int*)p;              p += (size_t)(NN + 1) * 4;
  int* cursor = (int*)p;              p += (size_t)NN * 4;
  int* col    = (int*)p;              p += (size_t)NET * 4;
  int* gstart = (int*)p;              p += (size_t)NG * 4;
  int* gend   = (int*)p;              p += (size_t)NG * 4;
  // nodeval reuses xh's region (dead by the time gather_k<2> runs):
  // NN*64*4 = 12.80 MB <= MPAD*FIN*2 = 12.81 MB
  float* nodeval = (float*)xh;

  const dim3 ggrid(FHC / 128, (MPAD) / 128);   // (4, 391)
  const int egrid = (NET + 255) / 256;
  const int ngrid = (NN + 3) / 4;

  // ---- zero-init: deg, boundaries, pad rows of A planes ----
  hipMemsetAsync(deg, 0, (size_t)NN * 4, stream);
  hipMemsetAsync(gstart, 0, (size_t)NG * 2 * 4, stream);
  hipMemsetAsync(xh + (size_t)NN * FIN, 0, (size_t)(MPAD - NN) * FIN * 2, stream);
  hipMemsetAsync(xl + (size_t)NN * FIN, 0, (size_t)(MPAD - NN) * FIN * 2, stream);
  hipMemsetAsync(h1h + (size_t)NN * FHC, 0, (size_t)(MPAD - NN) * FHC * 2, stream);
  hipMemsetAsync(h1l + (size_t)NN * FHC, 0, (size_t)(MPAD - NN) * FHC * 2, stream);

  // ---- conversions ----
  conv_split_k<<<(NN * FIN / 4 + 255) / 256, 256, 0, stream>>>(x, xh, xl, NN * FIN / 4);
  conv_wt_k<<<(FIN * FHC + 255) / 256, 256, 0, stream>>>(W1, w1h, w1l, FIN);
  conv_wt_k<<<(FHC * FHC + 255) / 256, 256, 0, stream>>>(W2, w2h, w2l, FHC);

  // ---- CSR build + graph boundaries ----
  hist_k<<<egrid, 256, 0, stream>>>(ei, deg);
  scan_k<<<1, 1024, 0, stream>>>(deg, rowp, cursor);
  fill_k<<<egrid, 256, 0, stream>>>(ei, cursor, col);
  bnd_k<<<(NN + 255) / 256, 256, 0, stream>>>(batch, gstart, gend);

  // ---- layer 1 ----
  gemm_mfma<<<ggrid, 256, 0, stream>>>(xh, xl, w1h, w1l, bufC, NN, FIN);
  alphas_k<<<ngrid, 256, 0, stream>>>(bufC, as1, ad1, asrc, adst);
  gather_k<1><<<ngrid, 256, 0, stream>>>(rowp, col, asrc, adst, bufC, b1,
                                         h1h, h1l, nullptr);

  // ---- layer 2 ----
  gemm_mfma<<<ggrid, 256, 0, stream>>>(h1h, h1l, w2h, w2l, bufC, NN, FHC);
  alphas_k<<<ngrid, 256, 0, stream>>>(bufC, as2, ad2, asrc, adst);
  gather_k<2><<<ngrid, 256, 0, stream>>>(rowp, col, asrc, adst, bufC, b2,
                                         nullptr, nullptr, nodeval);

  pool_k<<<NG, 256, 0, stream>>>(nodeval, gstart, gend, out);
}

// Round 6
// 697.278 us; speedup vs baseline: 3.6884x; 1.0072x over previous
//
#include <hip/hip_runtime.h>
#include <hip/hip_bf16.h>
#include <math.h>

// Problem constants (from reference setup_inputs)
#define NN   50000      // nodes
#define NE   400000     // edges (without self loops)
#define NET  450000     // edges + self loops
#define FH   8          // heads
#define FC   64         // channels per head
#define FHC  512        // H*C
#define FIN  128        // input features
#define NG   64         // graphs
#define MPAD 50048      // NN padded to tile multiple (391*128)

typedef unsigned short u16;
typedef __bf16 bf16x8 __attribute__((ext_vector_type(8)));
typedef float f32x4 __attribute__((ext_vector_type(4)));
typedef unsigned short u16x8 __attribute__((ext_vector_type(8)));

// ---- f32 -> bf16 (RNE) bit helpers ----
static __device__ __forceinline__ u16 f2bf(float f) {
  unsigned u = __float_as_uint(f);
  unsigned r = (u + 0x7fffu + ((u >> 16) & 1u)) >> 16;
  return (u16)r;
}
static __device__ __forceinline__ float bf2f(u16 h) {
  return __uint_as_float(((unsigned)h) << 16);
}

// ---- split-convert: f32 -> (hi, lo) bf16 planes, 4 elems/thread ----
__global__ __launch_bounds__(256) void conv_split_k(const float* __restrict__ in,
                                                    u16* __restrict__ hi,
                                                    u16* __restrict__ lo,
                                                    int n4) {
  int t = blockIdx.x * 256 + threadIdx.x;
  if (t >= n4) return;
  float4 f = reinterpret_cast<const float4*>(in)[t];
  ushort4 h, l;
  h.x = f2bf(f.x); l.x = f2bf(f.x - bf2f(h.x));
  h.y = f2bf(f.y); l.y = f2bf(f.y - bf2f(h.y));
  h.z = f2bf(f.z); l.z = f2bf(f.z - bf2f(h.z));
  h.w = f2bf(f.w); l.w = f2bf(f.w - bf2f(h.w));
  reinterpret_cast<ushort4*>(hi)[t] = h;
  reinterpret_cast<ushort4*>(lo)[t] = l;
}

// ---- W [K,512] -> transposed hi/lo planes Wt [512,K] ----
__global__ __launch_bounds__(256) void conv_wt_k(const float* __restrict__ W,
                                                 u16* __restrict__ hiT,
                                                 u16* __restrict__ loT,
                                                 int K) {
  int t = blockIdx.x * 256 + threadIdx.x;
  if (t >= K * FHC) return;
  int k = t >> 9, n = t & 511;
  float f = W[t];
  u16 h = f2bf(f);
  hiT[n * K + k] = h;
  loT[n * K + k] = f2bf(f - bf2f(h));
}

// ---- split-bf16 MFMA GEMM + fused attention-logit epilogue.
// C[M,512] = (Ah+Al)[M,K] @ (Wh+Wl)^T; also asrc/adst[n,head] = C-row . a_{src,dst}
// 128x128 tile, 4 waves; each wave's 64-col half = exactly one head.
__global__ __launch_bounds__(256) void gemm_mfma(const u16* __restrict__ Ah,
                                                 const u16* __restrict__ Al,
                                                 const u16* __restrict__ Bh,
                                                 const u16* __restrict__ Bl,
                                                 float* __restrict__ C,
                                                 const float* __restrict__ As_g,
                                                 const float* __restrict__ Ad_g,
                                                 float* __restrict__ asrc,
                                                 float* __restrict__ adst,
                                                 int M, int K) {
  __shared__ u16 AsH[128 * 64];  // 16 KB each, 64 KB total
  __shared__ u16 AsL[128 * 64];
  __shared__ u16 BsH[128 * 64];
  __shared__ u16 BsL[128 * 64];
  const int tid = threadIdx.x;
  const int bm = blockIdx.y * 128;
  const int bn = blockIdx.x * 128;
  const int wv = tid >> 6, l = tid & 63;
  const int wr = wv >> 1, wc = wv & 1;
  const int fr = l & 15, fq = l >> 4;

  f32x4 acc[4][4] = {};

  for (int k0 = 0; k0 < K; k0 += 64) {
    __syncthreads();
#pragma unroll
    for (int i = 0; i < 4; ++i) {
      int idx = i * 256 + tid;
      int row = idx >> 3, c8 = idx & 7;
      size_t goA = (size_t)(bm + row) * K + k0 + c8 * 8;
      size_t goB = (size_t)(bn + row) * K + k0 + c8 * 8;
      __builtin_amdgcn_global_load_lds(
          (const __attribute__((address_space(1))) void*)(Ah + goA),
          (__attribute__((address_space(3))) void*)(AsH + idx * 8), 16, 0, 0);
      __builtin_amdgcn_global_load_lds(
          (const __attribute__((address_space(1))) void*)(Al + goA),
          (__attribute__((address_space(3))) void*)(AsL + idx * 8), 16, 0, 0);
      __builtin_amdgcn_global_load_lds(
          (const __attribute__((address_space(1))) void*)(Bh + goB),
          (__attribute__((address_space(3))) void*)(BsH + idx * 8), 16, 0, 0);
      __builtin_amdgcn_global_load_lds(
          (const __attribute__((address_space(1))) void*)(Bl + goB),
          (__attribute__((address_space(3))) void*)(BsL + idx * 8), 16, 0, 0);
    }
    __syncthreads();
#pragma unroll
    for (int kk = 0; kk < 2; ++kk) {
      bf16x8 ah[4], al4[4], bh[4], bl4[4];
#pragma unroll
      for (int mi = 0; mi < 4; ++mi) {
        int off = (wr * 64 + mi * 16 + fr) * 64 + kk * 32 + fq * 8;
        ah[mi]  = *reinterpret_cast<const bf16x8*>(AsH + off);
        al4[mi] = *reinterpret_cast<const bf16x8*>(AsL + off);
      }
#pragma unroll
      for (int ni = 0; ni < 4; ++ni) {
        int off = (wc * 64 + ni * 16 + fr) * 64 + kk * 32 + fq * 8;
        bh[ni]  = *reinterpret_cast<const bf16x8*>(BsH + off);
        bl4[ni] = *reinterpret_cast<const bf16x8*>(BsL + off);
      }
#pragma unroll
      for (int mi = 0; mi < 4; ++mi)
#pragma unroll
        for (int ni = 0; ni < 4; ++ni) {
          acc[mi][ni] = __builtin_amdgcn_mfma_f32_16x16x32_bf16(
              ah[mi], bh[ni], acc[mi][ni], 0, 0, 0);
          acc[mi][ni] = __builtin_amdgcn_mfma_f32_16x16x32_bf16(
              ah[mi], bl4[ni], acc[mi][ni], 0, 0, 0);
          acc[mi][ni] = __builtin_amdgcn_mfma_f32_16x16x32_bf16(
              al4[mi], bh[ni], acc[mi][ni], 0, 0, 0);
        }
    }
  }
  // ---- C store ----
#pragma unroll
  for (int mi = 0; mi < 4; ++mi)
#pragma unroll
    for (int ni = 0; ni < 4; ++ni) {
      int r0 = bm + wr * 64 + mi * 16 + fq * 4;
      int c0 = bn + wc * 64 + ni * 16 + fr;
#pragma unroll
      for (int j = 0; j < 4; ++j)
        if (r0 + j < M) C[(size_t)(r0 + j) * FHC + c0] = acc[mi][ni][j];
    }
  // ---- fused attention logits: this wave's 64 cols == head hd ----
  {
    int hd = (bn >> 6) + wc;
    int cb = bn + wc * 64 + fr;  // global col for each ni*16 offset
    float as_v[4], ad_v[4];
#pragma unroll
    for (int ni = 0; ni < 4; ++ni) {
      as_v[ni] = As_g[cb + ni * 16];
      ad_v[ni] = Ad_g[cb + ni * 16];
    }
#pragma unroll
    for (int mi = 0; mi < 4; ++mi)
#pragma unroll
      for (int j = 0; j < 4; ++j) {
        float ps = 0.f, pd = 0.f;
#pragma unroll
        for (int ni = 0; ni < 4; ++ni) {
          float v = acc[mi][ni][j];
          ps += v * as_v[ni];
          pd += v * ad_v[ni];
        }
#pragma unroll
        for (int off = 1; off < 16; off <<= 1) {
          ps += __shfl_xor(ps, off);
          pd += __shfl_xor(pd, off);
        }
        int row = bm + wr * 64 + mi * 16 + fq * 4 + j;
        if (fr == 0 && row < M) {
          asrc[row * FH + hd] = ps;
          adst[row * FH + hd] = pd;
        }
      }
  }
}

// ---- CSR build: histogram of dst ----
__global__ __launch_bounds__(256) void hist_k(const int* __restrict__ ei,
                                              int* __restrict__ deg) {
  int e = blockIdx.x * 256 + threadIdx.x;
  if (e >= NET) return;
  int d = (e < NE) ? ei[NE + e] : e - NE;
  atomicAdd(&deg[d], 1);
}

// ---- CSR build: exclusive scan (single block) ----
__global__ __launch_bounds__(1024) void scan_k(const int* __restrict__ deg,
                                               int* __restrict__ row_ptr,
                                               int* __restrict__ cursor) {
  __shared__ int part[1024];
  int t = threadIdx.x;
  const int CH = (NN + 1023) / 1024;  // 49
  int base = t * CH;
  int s = 0;
  for (int i = 0; i < CH; ++i) {
    int idx = base + i;
    if (idx < NN) s += deg[idx];
  }
  part[t] = s;
  __syncthreads();
  for (int off = 1; off < 1024; off <<= 1) {
    int add = (t >= off) ? part[t - off] : 0;
    __syncthreads();
    part[t] += add;
    __syncthreads();
  }
  int run = part[t] - s;
  for (int i = 0; i < CH; ++i) {
    int idx = base + i;
    if (idx < NN) {
      row_ptr[idx] = run;
      cursor[idx] = run;
      run += deg[idx];
    }
  }
  if (t == 1023) row_ptr[NN] = part[1023];
}

// ---- CSR build: fill src ids per dst bucket ----
__global__ __launch_bounds__(256) void fill_k(const int* __restrict__ ei,
                                              int* __restrict__ cursor,
                                              int* __restrict__ col_src) {
  int e = blockIdx.x * 256 + threadIdx.x;
  if (e >= NET) return;
  int s, d;
  if (e < NE) { s = ei[e]; d = ei[NE + e]; } else { s = d = e - NE; }
  int pos = atomicAdd(&cursor[d], 1);
  col_src[pos] = s;
}

// ---- graph boundary detection (batch is sorted) ----
__global__ __launch_bounds__(256) void bnd_k(const int* __restrict__ batch,
                                             int* __restrict__ gstart,
                                             int* __restrict__ gend) {
  int n = blockIdx.x * 256 + threadIdx.x;
  if (n >= NN) return;
  int b = batch[n];
  if (n == 0 || batch[n - 1] != b) gstart[b] = n;
  if (n == NN - 1 || batch[n + 1] != b) gend[b] = n + 1;
}

// ---- gather-aggregate: one wave per dst node, 8 floats/lane, 4-edge chunks.
// No max-subtraction (logits bounded; softmax shift-invariant).
// Lane L: head L>>3, channels ((L&7)*8..+8); lane computes alpha for head L&7.
template <int LAYER>
__global__ __launch_bounds__(256) void gather_k(const int* __restrict__ row_ptr,
                                                const int* __restrict__ col_src,
                                                const float* __restrict__ asrc,
                                                const float* __restrict__ adst,
                                                const float* __restrict__ h,
                                                const float* __restrict__ bias,
                                                u16* __restrict__ outh,
                                                u16* __restrict__ outl,
                                                float* __restrict__ nodeval) {
  int n = blockIdx.x * 4 + (threadIdx.x >> 6);
  if (n >= NN) return;
  int lane = threadIdx.x & 63;
  int hh = lane & 7;
  int hsel = lane >> 3;
  int start = row_ptr[n], end = row_ptr[n + 1];
  float adn = adst[n * FH + hh];
  float den = 0.f;
  float4 a0 = make_float4(0.f, 0.f, 0.f, 0.f);
  float4 a1 = make_float4(0.f, 0.f, 0.f, 0.f);
  for (int j0 = start; j0 < end; j0 += 4) {
    int sidx[4];
#pragma unroll
    for (int u = 0; u < 4; ++u) {
      int jj = (j0 + u < end) ? j0 + u : end - 1;
      sidx[u] = col_src[jj];
    }
    float ex[4];
#pragma unroll
    for (int u = 0; u < 4; ++u) {
      float el = asrc[sidx[u] * FH + hh] + adn;
      el = el > 0.f ? el : 0.2f * el;
      ex[u] = (j0 + u < end) ? __expf(el) : 0.f;
      den += ex[u];
    }
    float4 v0[4], v1[4];
#pragma unroll
    for (int u = 0; u < 4; ++u) {
      const float4* hp =
          reinterpret_cast<const float4*>(h + (size_t)sidx[u] * FHC + lane * 8);
      v0[u] = hp[0];
      v1[u] = hp[1];
    }
#pragma unroll
    for (int u = 0; u < 4; ++u) {
      float exv = __shfl(ex[u], hsel);
      a0.x += exv * v0[u].x; a0.y += exv * v0[u].y;
      a0.z += exv * v0[u].z; a0.w += exv * v0[u].w;
      a1.x += exv * v1[u].x; a1.y += exv * v1[u].y;
      a1.z += exv * v1[u].z; a1.w += exv * v1[u].w;
    }
  }
  float dh = __shfl(den, hsel);
  float inv = 1.f / (dh + 1e-16f);
  float v[8] = {a0.x * inv, a0.y * inv, a0.z * inv, a0.w * inv,
                a1.x * inv, a1.y * inv, a1.z * inv, a1.w * inv};
  if (LAYER == 1) {
    const float4* bp = reinterpret_cast<const float4*>(bias + lane * 8);
    float4 b0 = bp[0], b1 = bp[1];
    float bb[8] = {b0.x, b0.y, b0.z, b0.w, b1.x, b1.y, b1.z, b1.w};
    u16x8 hv, lv;
#pragma unroll
    for (int j = 0; j < 8; ++j) {
      float val = v[j] + bb[j];
      val = val > 0.f ? val : expm1f(val);
      u16 hb = f2bf(val);
      hv[j] = hb;
      lv[j] = f2bf(val - bf2f(hb));
    }
    *reinterpret_cast<u16x8*>(outh + (size_t)n * FHC + lane * 8) = hv;
    *reinterpret_cast<u16x8*>(outl + (size_t)n * FHC + lane * 8) = lv;
  } else {
    // head-mean: sum across lanes with same (lane&7) -> xor bits 3,4,5
#pragma unroll
    for (int off = 8; off < 64; off <<= 1)
#pragma unroll
      for (int j = 0; j < 8; ++j) v[j] += __shfl_xor(v[j], off);
    if (lane < 8) {
      const float4* bp = reinterpret_cast<const float4*>(bias + lane * 8);
      float4 b0 = bp[0], b1 = bp[1];
      float bb[8] = {b0.x, b0.y, b0.z, b0.w, b1.x, b1.y, b1.z, b1.w};
      float o[8];
#pragma unroll
      for (int j = 0; j < 8; ++j) {
        float val = v[j] * (1.f / FH) + bb[j];
        o[j] = val > 0.f ? val : expm1f(val);
      }
      float4* np = reinterpret_cast<float4*>(nodeval + (size_t)n * FC + lane * 8);
      np[0] = make_float4(o[0], o[1], o[2], o[3]);
      np[1] = make_float4(o[4], o[5], o[6], o[7]);
    }
  }
}

// ---- pool: one block per graph over its contiguous node range ----
__global__ __launch_bounds__(256) void pool_k(const float* __restrict__ nodeval,
                                              const int* __restrict__ gstart,
                                              const int* __restrict__ gend,
                                              float* __restrict__ out) {
  __shared__ float red[4][FC];
  int g = blockIdx.x;
  int c = threadIdx.x & 63, w = threadIdx.x >> 6;
  int s = gstart[g], e = gend[g];
  float acc = 0.f;
  for (int n = s + w; n < e; n += 4) acc += nodeval[(size_t)n * FC + c];
  red[w][c] = acc;
  __syncthreads();
  if (w == 0) {
    float v = red[0][c] + red[1][c] + red[2][c] + red[3][c];
    out[g * FC + c] = v / fmaxf((float)(e - s), 1.f);
  }
}

extern "C" void kernel_launch(void* const* d_in, const int* in_sizes, int n_in,
                              void* d_out, int out_size, void* d_ws, size_t ws_size,
                              hipStream_t stream) {
  const float* x    = (const float*)d_in[0];
  const int*   ei   = (const int*)d_in[1];
  const int*   batch= (const int*)d_in[2];
  const float* W1   = (const float*)d_in[3];
  const float* as1  = (const float*)d_in[4];
  const float* ad1  = (const float*)d_in[5];
  const float* b1   = (const float*)d_in[6];
  const float* W2   = (const float*)d_in[7];
  const float* as2  = (const float*)d_in[8];
  const float* ad2  = (const float*)d_in[9];
  const float* b2   = (const float*)d_in[10];
  float* out = (float*)d_out;

  char* p = (char*)d_ws;
  float* bufC = (float*)p;            p += (size_t)NN * FHC * 4;     // 102.4 MB
  u16* xh  = (u16*)p; p += (size_t)MPAD * FIN * 2;
  u16* xl  = (u16*)p; p += (size_t)MPAD * FIN * 2;
  u16* h1h = (u16*)p; p += (size_t)MPAD * FHC * 2;
  u16* h1l = (u16*)p; p += (size_t)MPAD * FHC * 2;
  u16* w1h = (u16*)p; p += (size_t)FHC * FIN * 2;
  u16* w1l = (u16*)p; p += (size_t)FHC * FIN * 2;
  u16* w2h = (u16*)p; p += (size_t)FHC * FHC * 2;
  u16* w2l = (u16*)p; p += (size_t)FHC * FHC * 2;
  float* asrc = (float*)p;            p += (size_t)NN * FH * 4;
  float* adst = (float*)p;            p += (size_t)NN * FH * 4;
  int* deg    = (int*)p;              p += (size_t)NN * 4;
  int* rowp   = (int*)p;              p += (size_t)(NN + 1) * 4;
  int* cursor = (int*)p;              p += (size_t)NN * 4;
  int* col    = (int*)p;              p += (size_t)NET * 4;
  int* gstart = (int*)p;              p += (size_t)NG * 4;
  int* gend   = (int*)p;              p += (size_t)NG * 4;
  // nodeval reuses xh's region (dead by the time gather_k<2> runs)
  float* nodeval = (float*)xh;

  const dim3 ggrid(FHC / 128, (MPAD) / 128);   // (4, 391)
  const int egrid = (NET + 255) / 256;
  const int ngrid = (NN + 3) / 4;

  // ---- zero-init: deg, boundaries, pad rows of A planes ----
  hipMemsetAsync(deg, 0, (size_t)NN * 4, stream);
  hipMemsetAsync(gstart, 0, (size_t)NG * 2 * 4, stream);
  hipMemsetAsync(xh + (size_t)NN * FIN, 0, (size_t)(MPAD - NN) * FIN * 2, stream);
  hipMemsetAsync(xl + (size_t)NN * FIN, 0, (size_t)(MPAD - NN) * FIN * 2, stream);
  hipMemsetAsync(h1h + (size_t)NN * FHC, 0, (size_t)(MPAD - NN) * FHC * 2, stream);
  hipMemsetAsync(h1l + (size_t)NN * FHC, 0, (size_t)(MPAD - NN) * FHC * 2, stream);

  // ---- conversions ----
  conv_split_k<<<(NN * FIN / 4 + 255) / 256, 256, 0, stream>>>(x, xh, xl, NN * FIN / 4);
  conv_wt_k<<<(FIN * FHC + 255) / 256, 256, 0, stream>>>(W1, w1h, w1l, FIN);
  conv_wt_k<<<(FHC * FHC + 255) / 256, 256, 0, stream>>>(W2, w2h, w2l, FHC);

  // ---- CSR build + graph boundaries ----
  hist_k<<<egrid, 256, 0, stream>>>(ei, deg);
  scan_k<<<1, 1024, 0, stream>>>(deg, rowp, cursor);
  fill_k<<<egrid, 256, 0, stream>>>(ei, cursor, col);
  bnd_k<<<(NN + 255) / 256, 256, 0, stream>>>(batch, gstart, gend);

  // ---- layer 1 (alphas fused into GEMM epilogue) ----
  gemm_mfma<<<ggrid, 256, 0, stream>>>(xh, xl, w1h, w1l, bufC,
                                       as1, ad1, asrc, adst, NN, FIN);
  gather_k<1><<<ngrid, 256, 0, stream>>>(rowp, col, asrc, adst, bufC, b1,
                                         h1h, h1l, nullptr);

  // ---- layer 2 ----
  gemm_mfma<<<ggrid, 256, 0, stream>>>(h1h, h1l, w2h, w2l, bufC,
                                       as2, ad2, asrc, adst, NN, FHC);
  gather_k<2><<<ngrid, 256, 0, stream>>>(rowp, col, asrc, adst, bufC, b2,
                                         nullptr, nullptr, nodeval);

  pool_k<<<NG, 256, 0, stream>>>(nodeval, gstart, gend, out);
}

// Round 7
// 539.845 us; speedup vs baseline: 4.7641x; 1.2916x over previous
//
#include <hip/hip_runtime.h>
#include <hip/hip_bf16.h>
#include <math.h>

// Problem constants (from reference setup_inputs)
#define NN   50000      // nodes
#define NE   400000     // edges (without self loops)
#define NET  450000     // edges + self loops
#define FH   8          // heads
#define FC   64         // channels per head
#define FHC  512        // H*C
#define FIN  128        // input features
#define NG   64         // graphs
#define MPAD 50048      // NN padded to tile multiple (391*128)

typedef unsigned short u16;
typedef __bf16 bf16x8 __attribute__((ext_vector_type(8)));
typedef float f32x4 __attribute__((ext_vector_type(4)));
typedef unsigned short u16x8 __attribute__((ext_vector_type(8)));

// ---- f32 -> bf16 (RNE) bit helpers ----
static __device__ __forceinline__ u16 f2bf(float f) {
  unsigned u = __float_as_uint(f);
  unsigned r = (u + 0x7fffu + ((u >> 16) & 1u)) >> 16;
  return (u16)r;
}
static __device__ __forceinline__ float bf2f(u16 h) {
  return __uint_as_float(((unsigned)h) << 16);
}

// ---- split-convert: f32 -> (hi, lo) bf16 planes, 4 elems/thread ----
__global__ __launch_bounds__(256) void conv_split_k(const float* __restrict__ in,
                                                    u16* __restrict__ hi,
                                                    u16* __restrict__ lo,
                                                    int n4) {
  int t = blockIdx.x * 256 + threadIdx.x;
  if (t >= n4) return;
  float4 f = reinterpret_cast<const float4*>(in)[t];
  ushort4 h, l;
  h.x = f2bf(f.x); l.x = f2bf(f.x - bf2f(h.x));
  h.y = f2bf(f.y); l.y = f2bf(f.y - bf2f(h.y));
  h.z = f2bf(f.z); l.z = f2bf(f.z - bf2f(h.z));
  h.w = f2bf(f.w); l.w = f2bf(f.w - bf2f(h.w));
  reinterpret_cast<ushort4*>(hi)[t] = h;
  reinterpret_cast<ushort4*>(lo)[t] = l;
}

// ---- W [K,512] -> transposed hi/lo planes Wt [512,K] ----
__global__ __launch_bounds__(256) void conv_wt_k(const float* __restrict__ W,
                                                 u16* __restrict__ hiT,
                                                 u16* __restrict__ loT,
                                                 int K) {
  int t = blockIdx.x * 256 + threadIdx.x;
  if (t >= K * FHC) return;
  int k = t >> 9, n = t & 511;
  float f = W[t];
  u16 h = f2bf(f);
  hiT[n * K + k] = h;
  loT[n * K + k] = f2bf(f - bf2f(h));
}

// ---- split-bf16 MFMA GEMM + fused attention-logit epilogue.
// APL=2: A has hi+lo planes (3 products). APL=1: A single bf16 (2 products).
// C written as single bf16 plane (gather only needs ~0.4% rel accuracy);
// logits asrc/adst computed from f32 accumulators (full accuracy).
template <int APL>
__global__ __launch_bounds__(256) void gemm_mfma(const u16* __restrict__ Ah,
                                                 const u16* __restrict__ Al,
                                                 const u16* __restrict__ Bh,
                                                 const u16* __restrict__ Bl,
                                                 u16* __restrict__ Cb,
                                                 const float* __restrict__ As_g,
                                                 const float* __restrict__ Ad_g,
                                                 float* __restrict__ asrc,
                                                 float* __restrict__ adst,
                                                 int M, int K) {
  __shared__ u16 AsH[128 * 64];  // 16 KB each
  __shared__ u16 AsL[128 * 64];  // unused when APL==1 (still allocated)
  __shared__ u16 BsH[128 * 64];
  __shared__ u16 BsL[128 * 64];
  const int tid = threadIdx.x;
  const int bm = blockIdx.y * 128;
  const int bn = blockIdx.x * 128;
  const int wv = tid >> 6, l = tid & 63;
  const int wr = wv >> 1, wc = wv & 1;
  const int fr = l & 15, fq = l >> 4;

  f32x4 acc[4][4] = {};

  for (int k0 = 0; k0 < K; k0 += 64) {
    __syncthreads();
#pragma unroll
    for (int i = 0; i < 4; ++i) {
      int idx = i * 256 + tid;
      int row = idx >> 3, c8 = idx & 7;
      size_t goA = (size_t)(bm + row) * K + k0 + c8 * 8;
      size_t goB = (size_t)(bn + row) * K + k0 + c8 * 8;
      __builtin_amdgcn_global_load_lds(
          (const __attribute__((address_space(1))) void*)(Ah + goA),
          (__attribute__((address_space(3))) void*)(AsH + idx * 8), 16, 0, 0);
      if (APL == 2)
        __builtin_amdgcn_global_load_lds(
            (const __attribute__((address_space(1))) void*)(Al + goA),
            (__attribute__((address_space(3))) void*)(AsL + idx * 8), 16, 0, 0);
      __builtin_amdgcn_global_load_lds(
          (const __attribute__((address_space(1))) void*)(Bh + goB),
          (__attribute__((address_space(3))) void*)(BsH + idx * 8), 16, 0, 0);
      __builtin_amdgcn_global_load_lds(
          (const __attribute__((address_space(1))) void*)(Bl + goB),
          (__attribute__((address_space(3))) void*)(BsL + idx * 8), 16, 0, 0);
    }
    __syncthreads();
#pragma unroll
    for (int kk = 0; kk < 2; ++kk) {
      bf16x8 ah[4], al4[4], bh[4], bl4[4];
#pragma unroll
      for (int mi = 0; mi < 4; ++mi) {
        int off = (wr * 64 + mi * 16 + fr) * 64 + kk * 32 + fq * 8;
        ah[mi] = *reinterpret_cast<const bf16x8*>(AsH + off);
        if (APL == 2) al4[mi] = *reinterpret_cast<const bf16x8*>(AsL + off);
      }
#pragma unroll
      for (int ni = 0; ni < 4; ++ni) {
        int off = (wc * 64 + ni * 16 + fr) * 64 + kk * 32 + fq * 8;
        bh[ni]  = *reinterpret_cast<const bf16x8*>(BsH + off);
        bl4[ni] = *reinterpret_cast<const bf16x8*>(BsL + off);
      }
#pragma unroll
      for (int mi = 0; mi < 4; ++mi)
#pragma unroll
        for (int ni = 0; ni < 4; ++ni) {
          acc[mi][ni] = __builtin_amdgcn_mfma_f32_16x16x32_bf16(
              ah[mi], bh[ni], acc[mi][ni], 0, 0, 0);
          acc[mi][ni] = __builtin_amdgcn_mfma_f32_16x16x32_bf16(
              ah[mi], bl4[ni], acc[mi][ni], 0, 0, 0);
          if (APL == 2)
            acc[mi][ni] = __builtin_amdgcn_mfma_f32_16x16x32_bf16(
                al4[mi], bh[ni], acc[mi][ni], 0, 0, 0);
        }
    }
  }
  // ---- C store (bf16 plane) ----
#pragma unroll
  for (int mi = 0; mi < 4; ++mi)
#pragma unroll
    for (int ni = 0; ni < 4; ++ni) {
      int r0 = bm + wr * 64 + mi * 16 + fq * 4;
      int c0 = bn + wc * 64 + ni * 16 + fr;
#pragma unroll
      for (int j = 0; j < 4; ++j)
        if (r0 + j < M) Cb[(size_t)(r0 + j) * FHC + c0] = f2bf(acc[mi][ni][j]);
    }
  // ---- fused attention logits: this wave's 64 cols == head hd ----
  {
    int hd = (bn >> 6) + wc;
    int cb = bn + wc * 64 + fr;
    float as_v[4], ad_v[4];
#pragma unroll
    for (int ni = 0; ni < 4; ++ni) {
      as_v[ni] = As_g[cb + ni * 16];
      ad_v[ni] = Ad_g[cb + ni * 16];
    }
#pragma unroll
    for (int mi = 0; mi < 4; ++mi)
#pragma unroll
      for (int j = 0; j < 4; ++j) {
        float ps = 0.f, pd = 0.f;
#pragma unroll
        for (int ni = 0; ni < 4; ++ni) {
          float v = acc[mi][ni][j];
          ps += v * as_v[ni];
          pd += v * ad_v[ni];
        }
#pragma unroll
        for (int off = 1; off < 16; off <<= 1) {
          ps += __shfl_xor(ps, off);
          pd += __shfl_xor(pd, off);
        }
        int row = bm + wr * 64 + mi * 16 + fq * 4 + j;
        if (fr == 0 && row < M) {
          asrc[row * FH + hd] = ps;
          adst[row * FH + hd] = pd;
        }
      }
  }
}

// ---- CSR build: histogram of dst ----
__global__ __launch_bounds__(256) void hist_k(const int* __restrict__ ei,
                                              int* __restrict__ deg) {
  int e = blockIdx.x * 256 + threadIdx.x;
  if (e >= NET) return;
  int d = (e < NE) ? ei[NE + e] : e - NE;
  atomicAdd(&deg[d], 1);
}

// ---- CSR build: exclusive scan (single block) ----
__global__ __launch_bounds__(1024) void scan_k(const int* __restrict__ deg,
                                               int* __restrict__ row_ptr,
                                               int* __restrict__ cursor) {
  __shared__ int part[1024];
  int t = threadIdx.x;
  const int CH = (NN + 1023) / 1024;  // 49
  int base = t * CH;
  int s = 0;
  for (int i = 0; i < CH; ++i) {
    int idx = base + i;
    if (idx < NN) s += deg[idx];
  }
  part[t] = s;
  __syncthreads();
  for (int off = 1; off < 1024; off <<= 1) {
    int add = (t >= off) ? part[t - off] : 0;
    __syncthreads();
    part[t] += add;
    __syncthreads();
  }
  int run = part[t] - s;
  for (int i = 0; i < CH; ++i) {
    int idx = base + i;
    if (idx < NN) {
      row_ptr[idx] = run;
      cursor[idx] = run;
      run += deg[idx];
    }
  }
  if (t == 1023) row_ptr[NN] = part[1023];
}

// ---- CSR build: fill src ids per dst bucket ----
__global__ __launch_bounds__(256) void fill_k(const int* __restrict__ ei,
                                              int* __restrict__ cursor,
                                              int* __restrict__ col_src) {
  int e = blockIdx.x * 256 + threadIdx.x;
  if (e >= NET) return;
  int s, d;
  if (e < NE) { s = ei[e]; d = ei[NE + e]; } else { s = d = e - NE; }
  int pos = atomicAdd(&cursor[d], 1);
  col_src[pos] = s;
}

// ---- graph boundary detection (batch is sorted) ----
__global__ __launch_bounds__(256) void bnd_k(const int* __restrict__ batch,
                                             int* __restrict__ gstart,
                                             int* __restrict__ gend) {
  int n = blockIdx.x * 256 + threadIdx.x;
  if (n >= NN) return;
  int b = batch[n];
  if (n == 0 || batch[n - 1] != b) gstart[b] = n;
  if (n == NN - 1 || batch[n + 1] != b) gend[b] = n + 1;
}

// ---- gather-aggregate: one wave per dst node, 8 bf16/lane, 4-edge chunks.
// h rows are bf16 (halves gather traffic); alphas from f32 logits.
// Lane L: head L>>3, channels ((L&7)*8..+8); lane computes alpha for head L&7.
template <int LAYER>
__global__ __launch_bounds__(256) void gather_k(const int* __restrict__ row_ptr,
                                                const int* __restrict__ col_src,
                                                const float* __restrict__ asrc,
                                                const float* __restrict__ adst,
                                                const u16* __restrict__ hb,
                                                const float* __restrict__ bias,
                                                u16* __restrict__ outb,
                                                float* __restrict__ nodeval) {
  int n = blockIdx.x * 4 + (threadIdx.x >> 6);
  if (n >= NN) return;
  int lane = threadIdx.x & 63;
  int hh = lane & 7;
  int hsel = lane >> 3;
  int start = row_ptr[n], end = row_ptr[n + 1];
  float adn = adst[n * FH + hh];
  float den = 0.f;
  float v[8] = {};
  for (int j0 = start; j0 < end; j0 += 4) {
    int sidx[4];
#pragma unroll
    for (int u = 0; u < 4; ++u) {
      int jj = (j0 + u < end) ? j0 + u : end - 1;
      sidx[u] = col_src[jj];
    }
    float ex[4];
#pragma unroll
    for (int u = 0; u < 4; ++u) {
      float el = asrc[sidx[u] * FH + hh] + adn;
      el = el > 0.f ? el : 0.2f * el;
      ex[u] = (j0 + u < end) ? __expf(el) : 0.f;
      den += ex[u];
    }
    u16x8 hv[4];
#pragma unroll
    for (int u = 0; u < 4; ++u)
      hv[u] = *reinterpret_cast<const u16x8*>(hb + (size_t)sidx[u] * FHC + lane * 8);
#pragma unroll
    for (int u = 0; u < 4; ++u) {
      float exv = __shfl(ex[u], hsel);
#pragma unroll
      for (int j = 0; j < 8; ++j) v[j] += exv * bf2f(hv[u][j]);
    }
  }
  float dh = __shfl(den, hsel);
  float inv = 1.f / (dh + 1e-16f);
#pragma unroll
  for (int j = 0; j < 8; ++j) v[j] *= inv;
  if (LAYER == 1) {
    const float4* bp = reinterpret_cast<const float4*>(bias + lane * 8);
    float4 b0 = bp[0], b1 = bp[1];
    float bb[8] = {b0.x, b0.y, b0.z, b0.w, b1.x, b1.y, b1.z, b1.w};
    u16x8 ov;
#pragma unroll
    for (int j = 0; j < 8; ++j) {
      float val = v[j] + bb[j];
      val = val > 0.f ? val : expm1f(val);
      ov[j] = f2bf(val);
    }
    *reinterpret_cast<u16x8*>(outb + (size_t)n * FHC + lane * 8) = ov;
  } else {
    // head-mean: sum across lanes with same (lane&7) -> xor bits 3,4,5
#pragma unroll
    for (int off = 8; off < 64; off <<= 1)
#pragma unroll
      for (int j = 0; j < 8; ++j) v[j] += __shfl_xor(v[j], off);
    if (lane < 8) {
      const float4* bp = reinterpret_cast<const float4*>(bias + lane * 8);
      float4 b0 = bp[0], b1 = bp[1];
      float bb[8] = {b0.x, b0.y, b0.z, b0.w, b1.x, b1.y, b1.z, b1.w};
      float o[8];
#pragma unroll
      for (int j = 0; j < 8; ++j) {
        float val = v[j] * (1.f / FH) + bb[j];
        o[j] = val > 0.f ? val : expm1f(val);
      }
      float4* np = reinterpret_cast<float4*>(nodeval + (size_t)n * FC + lane * 8);
      np[0] = make_float4(o[0], o[1], o[2], o[3]);
      np[1] = make_float4(o[4], o[5], o[6], o[7]);
    }
  }
}

// ---- pool: one block per graph over its contiguous node range ----
__global__ __launch_bounds__(256) void pool_k(const float* __restrict__ nodeval,
                                              const int* __restrict__ gstart,
                                              const int* __restrict__ gend,
                                              float* __restrict__ out) {
  __shared__ float red[4][FC];
  int g = blockIdx.x;
  int c = threadIdx.x & 63, w = threadIdx.x >> 6;
  int s = gstart[g], e = gend[g];
  float acc = 0.f;
  for (int n = s + w; n < e; n += 4) acc += nodeval[(size_t)n * FC + c];
  red[w][c] = acc;
  __syncthreads();
  if (w == 0) {
    float v = red[0][c] + red[1][c] + red[2][c] + red[3][c];
    out[g * FC + c] = v / fmaxf((float)(e - s), 1.f);
  }
}

extern "C" void kernel_launch(void* const* d_in, const int* in_sizes, int n_in,
                              void* d_out, int out_size, void* d_ws, size_t ws_size,
                              hipStream_t stream) {
  const float* x    = (const float*)d_in[0];
  const int*   ei   = (const int*)d_in[1];
  const int*   batch= (const int*)d_in[2];
  const float* W1   = (const float*)d_in[3];
  const float* as1  = (const float*)d_in[4];
  const float* ad1  = (const float*)d_in[5];
  const float* b1   = (const float*)d_in[6];
  const float* W2   = (const float*)d_in[7];
  const float* as2  = (const float*)d_in[8];
  const float* ad2  = (const float*)d_in[9];
  const float* b2   = (const float*)d_in[10];
  float* out = (float*)d_out;

  char* p = (char*)d_ws;
  u16* Cb  = (u16*)p; p += (size_t)NN * FHC * 2;     // 51.2 MB (GEMM out, bf16)
  u16* xh  = (u16*)p; p += (size_t)MPAD * FIN * 2;
  u16* xl  = (u16*)p; p += (size_t)MPAD * FIN * 2;
  u16* h1b = (u16*)p; p += (size_t)MPAD * FHC * 2;   // layer-1 out / GEMM2 A
  u16* w1h = (u16*)p; p += (size_t)FHC * FIN * 2;
  u16* w1l = (u16*)p; p += (size_t)FHC * FIN * 2;
  u16* w2h = (u16*)p; p += (size_t)FHC * FHC * 2;
  u16* w2l = (u16*)p; p += (size_t)FHC * FHC * 2;
  float* asrc = (float*)p;            p += (size_t)NN * FH * 4;
  float* adst = (float*)p;            p += (size_t)NN * FH * 4;
  int* deg    = (int*)p;              p += (size_t)NN * 4;
  int* rowp   = (int*)p;              p += (size_t)(NN + 1) * 4;
  int* cursor = (int*)p;              p += (size_t)NN * 4;
  int* col    = (int*)p;              p += (size_t)NET * 4;
  int* gstart = (int*)p;              p += (size_t)NG * 4;
  int* gend   = (int*)p;              p += (size_t)NG * 4;
  // nodeval reuses xh's region (dead by the time gather_k<2> runs):
  // NN*64*4 = 12.80 MB <= MPAD*FIN*2 = 12.81 MB
  float* nodeval = (float*)xh;

  const dim3 ggrid(FHC / 128, (MPAD) / 128);   // (4, 391)
  const int egrid = (NET + 255) / 256;
  const int ngrid = (NN + 3) / 4;

  // ---- zero-init: deg, boundaries, pad rows of A planes ----
  hipMemsetAsync(deg, 0, (size_t)NN * 4, stream);
  hipMemsetAsync(gstart, 0, (size_t)NG * 2 * 4, stream);
  hipMemsetAsync(xh + (size_t)NN * FIN, 0, (size_t)(MPAD - NN) * FIN * 2, stream);
  hipMemsetAsync(xl + (size_t)NN * FIN, 0, (size_t)(MPAD - NN) * FIN * 2, stream);
  hipMemsetAsync(h1b + (size_t)NN * FHC, 0, (size_t)(MPAD - NN) * FHC * 2, stream);

  // ---- conversions ----
  conv_split_k<<<(NN * FIN / 4 + 255) / 256, 256, 0, stream>>>(x, xh, xl, NN * FIN / 4);
  conv_wt_k<<<(FIN * FHC + 255) / 256, 256, 0, stream>>>(W1, w1h, w1l, FIN);
  conv_wt_k<<<(FHC * FHC + 255) / 256, 256, 0, stream>>>(W2, w2h, w2l, FHC);

  // ---- CSR build + graph boundaries ----
  hist_k<<<egrid, 256, 0, stream>>>(ei, deg);
  scan_k<<<1, 1024, 0, stream>>>(deg, rowp, cursor);
  fill_k<<<egrid, 256, 0, stream>>>(ei, cursor, col);
  bnd_k<<<(NN + 255) / 256, 256, 0, stream>>>(batch, gstart, gend);

  // ---- layer 1 (alphas fused into GEMM epilogue) ----
  gemm_mfma<2><<<ggrid, 256, 0, stream>>>(xh, xl, w1h, w1l, Cb,
                                          as1, ad1, asrc, adst, NN, FIN);
  gather_k<1><<<ngrid, 256, 0, stream>>>(rowp, col, asrc, adst, Cb, b1,
                                         h1b, nullptr);

  // ---- layer 2 (A single bf16 plane, 2 MFMA products) ----
  gemm_mfma<1><<<ggrid, 256, 0, stream>>>(h1b, nullptr, w2h, w2l, Cb,
                                          as2, ad2, asrc, adst, NN, FHC);
  gather_k<2><<<ngrid, 256, 0, stream>>>(rowp, col, asrc, adst, Cb, b2,
                                         nullptr, nodeval);

  pool_k<<<NG, 256, 0, stream>>>(nodeval, gstart, gend, out);
}

// Round 8
// 422.889 us; speedup vs baseline: 6.0817x; 1.2766x over previous
//
#include <hip/hip_runtime.h>
#include <hip/hip_bf16.h>
#include <math.h>

// Problem constants (from reference setup_inputs)
#define NN   50000      // nodes
#define NE   400000     // edges (without self loops)
#define NET  450000     // edges + self loops
#define FH   8          // heads
#define FC   64         // channels per head
#define FHC  512        // H*C
#define FIN  128        // input features
#define NG   64         // graphs
#define MPAD 50048      // NN padded to tile multiple (391*128)
#define NB   196        // scan blocks = ceil(NN/256)

typedef unsigned short u16;
typedef __bf16 bf16x8 __attribute__((ext_vector_type(8)));
typedef float f32x4 __attribute__((ext_vector_type(4)));
typedef unsigned short u16x8 __attribute__((ext_vector_type(8)));

// ---- f32 -> bf16 (RNE) bit helpers ----
static __device__ __forceinline__ u16 f2bf(float f) {
  unsigned u = __float_as_uint(f);
  unsigned r = (u + 0x7fffu + ((u >> 16) & 1u)) >> 16;
  return (u16)r;
}
static __device__ __forceinline__ float bf2f(u16 h) {
  return __uint_as_float(((unsigned)h) << 16);
}

// ---- split-convert: f32 -> (hi, lo) bf16 planes, 4 elems/thread ----
__global__ __launch_bounds__(256) void conv_split_k(const float* __restrict__ in,
                                                    u16* __restrict__ hi,
                                                    u16* __restrict__ lo,
                                                    int n4) {
  int t = blockIdx.x * 256 + threadIdx.x;
  if (t >= n4) return;
  float4 f = reinterpret_cast<const float4*>(in)[t];
  ushort4 h, l;
  h.x = f2bf(f.x); l.x = f2bf(f.x - bf2f(h.x));
  h.y = f2bf(f.y); l.y = f2bf(f.y - bf2f(h.y));
  h.z = f2bf(f.z); l.z = f2bf(f.z - bf2f(h.z));
  h.w = f2bf(f.w); l.w = f2bf(f.w - bf2f(h.w));
  reinterpret_cast<ushort4*>(hi)[t] = h;
  reinterpret_cast<ushort4*>(lo)[t] = l;
}

// ---- W [K,512] -> transposed hi/lo planes Wt [512,K] ----
__global__ __launch_bounds__(256) void conv_wt_k(const float* __restrict__ W,
                                                 u16* __restrict__ hiT,
                                                 u16* __restrict__ loT,
                                                 int K) {
  int t = blockIdx.x * 256 + threadIdx.x;
  if (t >= K * FHC) return;
  int k = t >> 9, n = t & 511;
  float f = W[t];
  u16 h = f2bf(f);
  hiT[n * K + k] = h;
  loT[n * K + k] = f2bf(f - bf2f(h));
}

// ---- split-bf16 MFMA GEMM + fused attention-logit epilogue.
// APL=2: A has hi+lo planes (3 products). APL=1: A single bf16 (2 products).
// C written as single bf16 plane; logits from f32 accumulators.
template <int APL>
__global__ __launch_bounds__(256) void gemm_mfma(const u16* __restrict__ Ah,
                                                 const u16* __restrict__ Al,
                                                 const u16* __restrict__ Bh,
                                                 const u16* __restrict__ Bl,
                                                 u16* __restrict__ Cb,
                                                 const float* __restrict__ As_g,
                                                 const float* __restrict__ Ad_g,
                                                 float* __restrict__ asrc,
                                                 float* __restrict__ adst,
                                                 int M, int K) {
  __shared__ u16 AsH[128 * 64];
  __shared__ u16 AsL[128 * 64];
  __shared__ u16 BsH[128 * 64];
  __shared__ u16 BsL[128 * 64];
  const int tid = threadIdx.x;
  const int bm = blockIdx.y * 128;
  const int bn = blockIdx.x * 128;
  const int wv = tid >> 6, l = tid & 63;
  const int wr = wv >> 1, wc = wv & 1;
  const int fr = l & 15, fq = l >> 4;

  f32x4 acc[4][4] = {};

  for (int k0 = 0; k0 < K; k0 += 64) {
    __syncthreads();
#pragma unroll
    for (int i = 0; i < 4; ++i) {
      int idx = i * 256 + tid;
      int row = idx >> 3, c8 = idx & 7;
      size_t goA = (size_t)(bm + row) * K + k0 + c8 * 8;
      size_t goB = (size_t)(bn + row) * K + k0 + c8 * 8;
      __builtin_amdgcn_global_load_lds(
          (const __attribute__((address_space(1))) void*)(Ah + goA),
          (__attribute__((address_space(3))) void*)(AsH + idx * 8), 16, 0, 0);
      if (APL == 2)
        __builtin_amdgcn_global_load_lds(
            (const __attribute__((address_space(1))) void*)(Al + goA),
            (__attribute__((address_space(3))) void*)(AsL + idx * 8), 16, 0, 0);
      __builtin_amdgcn_global_load_lds(
          (const __attribute__((address_space(1))) void*)(Bh + goB),
          (__attribute__((address_space(3))) void*)(BsH + idx * 8), 16, 0, 0);
      __builtin_amdgcn_global_load_lds(
          (const __attribute__((address_space(1))) void*)(Bl + goB),
          (__attribute__((address_space(3))) void*)(BsL + idx * 8), 16, 0, 0);
    }
    __syncthreads();
#pragma unroll
    for (int kk = 0; kk < 2; ++kk) {
      bf16x8 ah[4], al4[4], bh[4], bl4[4];
#pragma unroll
      for (int mi = 0; mi < 4; ++mi) {
        int off = (wr * 64 + mi * 16 + fr) * 64 + kk * 32 + fq * 8;
        ah[mi] = *reinterpret_cast<const bf16x8*>(AsH + off);
        if (APL == 2) al4[mi] = *reinterpret_cast<const bf16x8*>(AsL + off);
      }
#pragma unroll
      for (int ni = 0; ni < 4; ++ni) {
        int off = (wc * 64 + ni * 16 + fr) * 64 + kk * 32 + fq * 8;
        bh[ni]  = *reinterpret_cast<const bf16x8*>(BsH + off);
        bl4[ni] = *reinterpret_cast<const bf16x8*>(BsL + off);
      }
#pragma unroll
      for (int mi = 0; mi < 4; ++mi)
#pragma unroll
        for (int ni = 0; ni < 4; ++ni) {
          acc[mi][ni] = __builtin_amdgcn_mfma_f32_16x16x32_bf16(
              ah[mi], bh[ni], acc[mi][ni], 0, 0, 0);
          acc[mi][ni] = __builtin_amdgcn_mfma_f32_16x16x32_bf16(
              ah[mi], bl4[ni], acc[mi][ni], 0, 0, 0);
          if (APL == 2)
            acc[mi][ni] = __builtin_amdgcn_mfma_f32_16x16x32_bf16(
                al4[mi], bh[ni], acc[mi][ni], 0, 0, 0);
        }
    }
  }
  // ---- C store (bf16 plane) ----
#pragma unroll
  for (int mi = 0; mi < 4; ++mi)
#pragma unroll
    for (int ni = 0; ni < 4; ++ni) {
      int r0 = bm + wr * 64 + mi * 16 + fq * 4;
      int c0 = bn + wc * 64 + ni * 16 + fr;
#pragma unroll
      for (int j = 0; j < 4; ++j)
        if (r0 + j < M) Cb[(size_t)(r0 + j) * FHC + c0] = f2bf(acc[mi][ni][j]);
    }
  // ---- fused attention logits: this wave's 64 cols == head hd ----
  {
    int hd = (bn >> 6) + wc;
    int cb = bn + wc * 64 + fr;
    float as_v[4], ad_v[4];
#pragma unroll
    for (int ni = 0; ni < 4; ++ni) {
      as_v[ni] = As_g[cb + ni * 16];
      ad_v[ni] = Ad_g[cb + ni * 16];
    }
#pragma unroll
    for (int mi = 0; mi < 4; ++mi)
#pragma unroll
      for (int j = 0; j < 4; ++j) {
        float ps = 0.f, pd = 0.f;
#pragma unroll
        for (int ni = 0; ni < 4; ++ni) {
          float v = acc[mi][ni][j];
          ps += v * as_v[ni];
          pd += v * ad_v[ni];
        }
#pragma unroll
        for (int off = 1; off < 16; off <<= 1) {
          ps += __shfl_xor(ps, off);
          pd += __shfl_xor(pd, off);
        }
        int row = bm + wr * 64 + mi * 16 + fq * 4 + j;
        if (fr == 0 && row < M) {
          asrc[row * FH + hd] = ps;
          adst[row * FH + hd] = pd;
        }
      }
  }
}

// ---- CSR build: histogram of dst ----
__global__ __launch_bounds__(256) void hist_k(const int* __restrict__ ei,
                                              int* __restrict__ deg) {
  int e = blockIdx.x * 256 + threadIdx.x;
  if (e >= NET) return;
  int d = (e < NE) ? ei[NE + e] : e - NE;
  atomicAdd(&deg[d], 1);
}

// ---- hierarchical scan pass 1: per-block exclusive prefix + block sums ----
__global__ __launch_bounds__(256) void scan1_k(const int* __restrict__ deg,
                                               int* __restrict__ row_ptr,
                                               int* __restrict__ bsum) {
  int tid = threadIdx.x;
  int i = blockIdx.x * 256 + tid;
  int lane = tid & 63, w = tid >> 6;
  int val = (i < NN) ? deg[i] : 0;
  int s = val;
#pragma unroll
  for (int off = 1; off < 64; off <<= 1) {
    int t = __shfl_up(s, off);
    if (lane >= off) s += t;
  }
  __shared__ int wt[4], wo[4];
  if (lane == 63) wt[w] = s;
  __syncthreads();
  if (tid == 0) {
    int r = 0;
#pragma unroll
    for (int k = 0; k < 4; ++k) { wo[k] = r; r += wt[k]; }
    bsum[blockIdx.x] = r;
  }
  __syncthreads();
  if (i < NN) row_ptr[i] = s - val + wo[w];
}

// ---- scan pass 2: scan the NB block sums (single tiny block) ----
__global__ __launch_bounds__(256) void scan2_k(int* __restrict__ bsum,
                                               int* __restrict__ row_ptr) {
  int tid = threadIdx.x;
  int lane = tid & 63, w = tid >> 6;
  int val = (tid < NB) ? bsum[tid] : 0;
  int s = val;
#pragma unroll
  for (int off = 1; off < 64; off <<= 1) {
    int t = __shfl_up(s, off);
    if (lane >= off) s += t;
  }
  __shared__ int wt[4], wo[4];
  if (lane == 63) wt[w] = s;
  __syncthreads();
  if (tid == 0) {
    int r = 0;
#pragma unroll
    for (int k = 0; k < 4; ++k) { wo[k] = r; r += wt[k]; }
  }
  __syncthreads();
  int excl = s - val + wo[w];
  if (tid < NB) bsum[tid] = excl;
  if (tid == 255) row_ptr[NN] = excl;  // val=0 here -> excl == grand total
}

// ---- scan pass 3: add block offsets, init cursor ----
__global__ __launch_bounds__(256) void scan3_k(int* __restrict__ row_ptr,
                                               const int* __restrict__ bsum,
                                               int* __restrict__ cursor) {
  int i = blockIdx.x * 256 + threadIdx.x;
  if (i >= NN) return;
  int v = row_ptr[i] + bsum[blockIdx.x];
  row_ptr[i] = v;
  cursor[i] = v;
}

// ---- CSR build: fill src ids per dst bucket ----
__global__ __launch_bounds__(256) void fill_k(const int* __restrict__ ei,
                                              int* __restrict__ cursor,
                                              int* __restrict__ col_src) {
  int e = blockIdx.x * 256 + threadIdx.x;
  if (e >= NET) return;
  int s, d;
  if (e < NE) { s = ei[e]; d = ei[NE + e]; } else { s = d = e - NE; }
  int pos = atomicAdd(&cursor[d], 1);
  col_src[pos] = s;
}

// ---- graph boundary detection (batch is sorted) ----
__global__ __launch_bounds__(256) void bnd_k(const int* __restrict__ batch,
                                             int* __restrict__ gstart,
                                             int* __restrict__ gend) {
  int n = blockIdx.x * 256 + threadIdx.x;
  if (n >= NN) return;
  int b = batch[n];
  if (n == 0 || batch[n - 1] != b) gstart[b] = n;
  if (n == NN - 1 || batch[n + 1] != b) gend[b] = n + 1;
}

// ---- gather-aggregate: one wave per dst node, 8 bf16/lane, 4-edge chunks ----
template <int LAYER>
__global__ __launch_bounds__(256) void gather_k(const int* __restrict__ row_ptr,
                                                const int* __restrict__ col_src,
                                                const float* __restrict__ asrc,
                                                const float* __restrict__ adst,
                                                const u16* __restrict__ hb,
                                                const float* __restrict__ bias,
                                                u16* __restrict__ outb,
                                                float* __restrict__ nodeval) {
  int n = blockIdx.x * 4 + (threadIdx.x >> 6);
  if (n >= NN) return;
  int lane = threadIdx.x & 63;
  int hh = lane & 7;
  int hsel = lane >> 3;
  int start = row_ptr[n], end = row_ptr[n + 1];
  float adn = adst[n * FH + hh];
  float den = 0.f;
  float v[8] = {};
  for (int j0 = start; j0 < end; j0 += 4) {
    int sidx[4];
#pragma unroll
    for (int u = 0; u < 4; ++u) {
      int jj = (j0 + u < end) ? j0 + u : end - 1;
      sidx[u] = col_src[jj];
    }
    float ex[4];
#pragma unroll
    for (int u = 0; u < 4; ++u) {
      float el = asrc[sidx[u] * FH + hh] + adn;
      el = el > 0.f ? el : 0.2f * el;
      ex[u] = (j0 + u < end) ? __expf(el) : 0.f;
      den += ex[u];
    }
    u16x8 hv[4];
#pragma unroll
    for (int u = 0; u < 4; ++u)
      hv[u] = *reinterpret_cast<const u16x8*>(hb + (size_t)sidx[u] * FHC + lane * 8);
#pragma unroll
    for (int u = 0; u < 4; ++u) {
      float exv = __shfl(ex[u], hsel);
#pragma unroll
      for (int j = 0; j < 8; ++j) v[j] += exv * bf2f(hv[u][j]);
    }
  }
  float dh = __shfl(den, hsel);
  float inv = 1.f / (dh + 1e-16f);
#pragma unroll
  for (int j = 0; j < 8; ++j) v[j] *= inv;
  if (LAYER == 1) {
    const float4* bp = reinterpret_cast<const float4*>(bias + lane * 8);
    float4 b0 = bp[0], b1 = bp[1];
    float bb[8] = {b0.x, b0.y, b0.z, b0.w, b1.x, b1.y, b1.z, b1.w};
    u16x8 ov;
#pragma unroll
    for (int j = 0; j < 8; ++j) {
      float val = v[j] + bb[j];
      val = val > 0.f ? val : expm1f(val);
      ov[j] = f2bf(val);
    }
    *reinterpret_cast<u16x8*>(outb + (size_t)n * FHC + lane * 8) = ov;
  } else {
#pragma unroll
    for (int off = 8; off < 64; off <<= 1)
#pragma unroll
      for (int j = 0; j < 8; ++j) v[j] += __shfl_xor(v[j], off);
    if (lane < 8) {
      const float4* bp = reinterpret_cast<const float4*>(bias + lane * 8);
      float4 b0 = bp[0], b1 = bp[1];
      float bb[8] = {b0.x, b0.y, b0.z, b0.w, b1.x, b1.y, b1.z, b1.w};
      float o[8];
#pragma unroll
      for (int j = 0; j < 8; ++j) {
        float val = v[j] * (1.f / FH) + bb[j];
        o[j] = val > 0.f ? val : expm1f(val);
      }
      float4* np = reinterpret_cast<float4*>(nodeval + (size_t)n * FC + lane * 8);
      np[0] = make_float4(o[0], o[1], o[2], o[3]);
      np[1] = make_float4(o[4], o[5], o[6], o[7]);
    }
  }
}

// ---- pool: one block per graph over its contiguous node range ----
__global__ __launch_bounds__(256) void pool_k(const float* __restrict__ nodeval,
                                              const int* __restrict__ gstart,
                                              const int* __restrict__ gend,
                                              float* __restrict__ out) {
  __shared__ float red[4][FC];
  int g = blockIdx.x;
  int c = threadIdx.x & 63, w = threadIdx.x >> 6;
  int s = gstart[g], e = gend[g];
  float acc = 0.f;
  for (int n = s + w; n < e; n += 4) acc += nodeval[(size_t)n * FC + c];
  red[w][c] = acc;
  __syncthreads();
  if (w == 0) {
    float v = red[0][c] + red[1][c] + red[2][c] + red[3][c];
    out[g * FC + c] = v / fmaxf((float)(e - s), 1.f);
  }
}

extern "C" void kernel_launch(void* const* d_in, const int* in_sizes, int n_in,
                              void* d_out, int out_size, void* d_ws, size_t ws_size,
                              hipStream_t stream) {
  const float* x    = (const float*)d_in[0];
  const int*   ei   = (const int*)d_in[1];
  const int*   batch= (const int*)d_in[2];
  const float* W1   = (const float*)d_in[3];
  const float* as1  = (const float*)d_in[4];
  const float* ad1  = (const float*)d_in[5];
  const float* b1   = (const float*)d_in[6];
  const float* W2   = (const float*)d_in[7];
  const float* as2  = (const float*)d_in[8];
  const float* ad2  = (const float*)d_in[9];
  const float* b2   = (const float*)d_in[10];
  float* out = (float*)d_out;

  char* p = (char*)d_ws;
  u16* Cb  = (u16*)p; p += (size_t)NN * FHC * 2;     // 51.2 MB (GEMM out, bf16)
  u16* xh  = (u16*)p; p += (size_t)MPAD * FIN * 2;
  u16* xl  = (u16*)p; p += (size_t)MPAD * FIN * 2;
  u16* h1b = (u16*)p; p += (size_t)MPAD * FHC * 2;   // layer-1 out / GEMM2 A
  u16* w1h = (u16*)p; p += (size_t)FHC * FIN * 2;
  u16* w1l = (u16*)p; p += (size_t)FHC * FIN * 2;
  u16* w2h = (u16*)p; p += (size_t)FHC * FHC * 2;
  u16* w2l = (u16*)p; p += (size_t)FHC * FHC * 2;
  float* asrc = (float*)p;            p += (size_t)NN * FH * 4;
  float* adst = (float*)p;            p += (size_t)NN * FH * 4;
  int* deg    = (int*)p;              p += (size_t)NN * 4;
  int* rowp   = (int*)p;              p += (size_t)(NN + 1) * 4;
  int* cursor = (int*)p;              p += (size_t)NN * 4;
  int* col    = (int*)p;              p += (size_t)NET * 4;
  int* gstart = (int*)p;              p += (size_t)NG * 4;
  int* gend   = (int*)p;              p += (size_t)NG * 4;
  int* bsum   = (int*)p;              p += (size_t)NB * 4;
  // nodeval reuses xh's region (dead by the time gather_k<2> runs)
  float* nodeval = (float*)xh;

  const dim3 ggrid(FHC / 128, (MPAD) / 128);   // (4, 391)
  const int egrid = (NET + 255) / 256;
  const int ngrid = (NN + 3) / 4;

  // ---- zero-init: deg, boundaries, pad rows of A planes ----
  hipMemsetAsync(deg, 0, (size_t)NN * 4, stream);
  hipMemsetAsync(gstart, 0, (size_t)NG * 2 * 4, stream);
  hipMemsetAsync(xh + (size_t)NN * FIN, 0, (size_t)(MPAD - NN) * FIN * 2, stream);
  hipMemsetAsync(xl + (size_t)NN * FIN, 0, (size_t)(MPAD - NN) * FIN * 2, stream);
  hipMemsetAsync(h1b + (size_t)NN * FHC, 0, (size_t)(MPAD - NN) * FHC * 2, stream);

  // ---- conversions ----
  conv_split_k<<<(NN * FIN / 4 + 255) / 256, 256, 0, stream>>>(x, xh, xl, NN * FIN / 4);
  conv_wt_k<<<(FIN * FHC + 255) / 256, 256, 0, stream>>>(W1, w1h, w1l, FIN);
  conv_wt_k<<<(FHC * FHC + 255) / 256, 256, 0, stream>>>(W2, w2h, w2l, FHC);

  // ---- CSR build (3-pass parallel scan) + graph boundaries ----
  hist_k<<<egrid, 256, 0, stream>>>(ei, deg);
  scan1_k<<<NB, 256, 0, stream>>>(deg, rowp, bsum);
  scan2_k<<<1, 256, 0, stream>>>(bsum, rowp);
  scan3_k<<<NB, 256, 0, stream>>>(rowp, bsum, cursor);
  fill_k<<<egrid, 256, 0, stream>>>(ei, cursor, col);
  bnd_k<<<(NN + 255) / 256, 256, 0, stream>>>(batch, gstart, gend);

  // ---- layer 1 (alphas fused into GEMM epilogue) ----
  gemm_mfma<2><<<ggrid, 256, 0, stream>>>(xh, xl, w1h, w1l, Cb,
                                          as1, ad1, asrc, adst, NN, FIN);
  gather_k<1><<<ngrid, 256, 0, stream>>>(rowp, col, asrc, adst, Cb, b1,
                                         h1b, nullptr);

  // ---- layer 2 (A single bf16 plane, 2 MFMA products) ----
  gemm_mfma<1><<<ggrid, 256, 0, stream>>>(h1b, nullptr, w2h, w2l, Cb,
                                          as2, ad2, asrc, adst, NN, FHC);
  gather_k<2><<<ngrid, 256, 0, stream>>>(rowp, col, asrc, adst, Cb, b2,
                                         nullptr, nodeval);

  pool_k<<<NG, 256, 0, stream>>>(nodeval, gstart, gend, out);
}

// Round 9
// 415.155 us; speedup vs baseline: 6.1950x; 1.0186x over previous
//
#include <hip/hip_runtime.h>
#include <hip/hip_bf16.h>
#include <math.h>

// Problem constants (from reference setup_inputs)
#define NN   50000      // nodes
#define NE   400000     // edges (without self loops)
#define NET  450000     // edges + self loops
#define FH   8          // heads
#define FC   64         // channels per head
#define FHC  512        // H*C
#define FIN  128        // input features
#define NG   64         // graphs
#define MPAD 50048      // NN padded to tile multiple (391*128)
#define NB   196        // scan blocks = ceil(NN/256)

typedef unsigned short u16;
typedef __bf16 bf16x8 __attribute__((ext_vector_type(8)));
typedef float f32x4 __attribute__((ext_vector_type(4)));
typedef unsigned short u16x8 __attribute__((ext_vector_type(8)));

// ---- f32 -> bf16 (RNE) bit helpers ----
static __device__ __forceinline__ u16 f2bf(float f) {
  unsigned u = __float_as_uint(f);
  unsigned r = (u + 0x7fffu + ((u >> 16) & 1u)) >> 16;
  return (u16)r;
}
static __device__ __forceinline__ float bf2f(u16 h) {
  return __uint_as_float(((unsigned)h) << 16);
}

// ---- split-convert: f32 -> (hi, lo) bf16 planes, 4 elems/thread ----
__global__ __launch_bounds__(256) void conv_split_k(const float* __restrict__ in,
                                                    u16* __restrict__ hi,
                                                    u16* __restrict__ lo,
                                                    int n4) {
  int t = blockIdx.x * 256 + threadIdx.x;
  if (t >= n4) return;
  float4 f = reinterpret_cast<const float4*>(in)[t];
  ushort4 h, l;
  h.x = f2bf(f.x); l.x = f2bf(f.x - bf2f(h.x));
  h.y = f2bf(f.y); l.y = f2bf(f.y - bf2f(h.y));
  h.z = f2bf(f.z); l.z = f2bf(f.z - bf2f(h.z));
  h.w = f2bf(f.w); l.w = f2bf(f.w - bf2f(h.w));
  reinterpret_cast<ushort4*>(hi)[t] = h;
  reinterpret_cast<ushort4*>(lo)[t] = l;
}

// ---- W [K,512] -> transposed hi/lo planes Wt [512,K] ----
__global__ __launch_bounds__(256) void conv_wt_k(const float* __restrict__ W,
                                                 u16* __restrict__ hiT,
                                                 u16* __restrict__ loT,
                                                 int K) {
  int t = blockIdx.x * 256 + threadIdx.x;
  if (t >= K * FHC) return;
  int k = t >> 9, n = t & 511;
  float f = W[t];
  u16 h = f2bf(f);
  hiT[n * K + k] = h;
  loT[n * K + k] = f2bf(f - bf2f(h));
}

// ---- split-bf16 MFMA GEMM + fused attention-logit epilogue.
// APL=2: A hi+lo planes (3 products), BK=32 -> 32 KB LDS, 4 blocks/CU.
// APL=1: A single bf16    (2 products), BK=64 -> 48 KB LDS, 3 blocks/CU.
// 1D grid with bijective XCD-chunking: each XCD gets a contiguous run of
// workgroups; the 4 N-tiles of one M-tile are consecutive -> A-panel L2 reuse.
template <int APL>
__global__ __launch_bounds__(256) void gemm_mfma(const u16* __restrict__ Ah,
                                                 const u16* __restrict__ Al,
                                                 const u16* __restrict__ Bh,
                                                 const u16* __restrict__ Bl,
                                                 u16* __restrict__ Cb,
                                                 const float* __restrict__ As_g,
                                                 const float* __restrict__ Ad_g,
                                                 float* __restrict__ asrc,
                                                 float* __restrict__ adst,
                                                 int M, int K) {
  constexpr int BK = (APL == 2) ? 32 : 64;      // k-tile depth
  constexpr int GPR = BK / 8;                    // 8-u16 granules per row
  __shared__ u16 AsH[128 * BK];
  __shared__ u16 AsL[(APL == 2) ? 128 * BK : 8];
  __shared__ u16 BsH[128 * BK];
  __shared__ u16 BsL[128 * BK];
  const int tid = threadIdx.x;
  // ---- bijective XCD-chunked block id -> (mt, nt) ----
  constexpr int NWG = (MPAD / 128) * (FHC / 128);  // 1564
  constexpr int qq = NWG >> 3, rr = NWG & 7;
  int d = blockIdx.x;
  int xcd = d & 7, slot = d >> 3;
  int w = (xcd < rr) ? xcd * (qq + 1) + slot
                     : rr * (qq + 1) + (xcd - rr) * qq + slot;
  const int bm = (w >> 2) * 128;
  const int bn = (w & 3) * 128;
  const int wv = tid >> 6, l = tid & 63;
  const int wr = wv >> 1, wc = wv & 1;
  const int fr = l & 15, fq = l >> 4;

  f32x4 acc[4][4] = {};

  for (int k0 = 0; k0 < K; k0 += BK) {
    __syncthreads();
#pragma unroll
    for (int i = 0; i < BK / 16; ++i) {
      int idx = i * 256 + tid;
      int row = idx / GPR, c8 = idx % GPR;
      size_t goA = (size_t)(bm + row) * K + k0 + c8 * 8;
      size_t goB = (size_t)(bn + row) * K + k0 + c8 * 8;
      __builtin_amdgcn_global_load_lds(
          (const __attribute__((address_space(1))) void*)(Ah + goA),
          (__attribute__((address_space(3))) void*)(AsH + idx * 8), 16, 0, 0);
      if (APL == 2)
        __builtin_amdgcn_global_load_lds(
            (const __attribute__((address_space(1))) void*)(Al + goA),
            (__attribute__((address_space(3))) void*)(AsL + idx * 8), 16, 0, 0);
      __builtin_amdgcn_global_load_lds(
          (const __attribute__((address_space(1))) void*)(Bh + goB),
          (__attribute__((address_space(3))) void*)(BsH + idx * 8), 16, 0, 0);
      __builtin_amdgcn_global_load_lds(
          (const __attribute__((address_space(1))) void*)(Bl + goB),
          (__attribute__((address_space(3))) void*)(BsL + idx * 8), 16, 0, 0);
    }
    __syncthreads();
#pragma unroll
    for (int kk = 0; kk < BK / 32; ++kk) {
      bf16x8 ah[4], al4[4], bh[4], bl4[4];
#pragma unroll
      for (int mi = 0; mi < 4; ++mi) {
        int off = (wr * 64 + mi * 16 + fr) * BK + kk * 32 + fq * 8;
        ah[mi] = *reinterpret_cast<const bf16x8*>(AsH + off);
        if (APL == 2) al4[mi] = *reinterpret_cast<const bf16x8*>(AsL + off);
      }
#pragma unroll
      for (int ni = 0; ni < 4; ++ni) {
        int off = (wc * 64 + ni * 16 + fr) * BK + kk * 32 + fq * 8;
        bh[ni]  = *reinterpret_cast<const bf16x8*>(BsH + off);
        bl4[ni] = *reinterpret_cast<const bf16x8*>(BsL + off);
      }
#pragma unroll
      for (int mi = 0; mi < 4; ++mi)
#pragma unroll
        for (int ni = 0; ni < 4; ++ni) {
          acc[mi][ni] = __builtin_amdgcn_mfma_f32_16x16x32_bf16(
              ah[mi], bh[ni], acc[mi][ni], 0, 0, 0);
          acc[mi][ni] = __builtin_amdgcn_mfma_f32_16x16x32_bf16(
              ah[mi], bl4[ni], acc[mi][ni], 0, 0, 0);
          if (APL == 2)
            acc[mi][ni] = __builtin_amdgcn_mfma_f32_16x16x32_bf16(
                al4[mi], bh[ni], acc[mi][ni], 0, 0, 0);
        }
    }
  }
  // ---- C store (bf16 plane) ----
#pragma unroll
  for (int mi = 0; mi < 4; ++mi)
#pragma unroll
    for (int ni = 0; ni < 4; ++ni) {
      int r0 = bm + wr * 64 + mi * 16 + fq * 4;
      int c0 = bn + wc * 64 + ni * 16 + fr;
#pragma unroll
      for (int j = 0; j < 4; ++j)
        if (r0 + j < M) Cb[(size_t)(r0 + j) * FHC + c0] = f2bf(acc[mi][ni][j]);
    }
  // ---- fused attention logits: this wave's 64 cols == head hd ----
  {
    int hd = (bn >> 6) + wc;
    int cb = bn + wc * 64 + fr;
    float as_v[4], ad_v[4];
#pragma unroll
    for (int ni = 0; ni < 4; ++ni) {
      as_v[ni] = As_g[cb + ni * 16];
      ad_v[ni] = Ad_g[cb + ni * 16];
    }
#pragma unroll
    for (int mi = 0; mi < 4; ++mi)
#pragma unroll
      for (int j = 0; j < 4; ++j) {
        float ps = 0.f, pd = 0.f;
#pragma unroll
        for (int ni = 0; ni < 4; ++ni) {
          float v = acc[mi][ni][j];
          ps += v * as_v[ni];
          pd += v * ad_v[ni];
        }
#pragma unroll
        for (int off = 1; off < 16; off <<= 1) {
          ps += __shfl_xor(ps, off);
          pd += __shfl_xor(pd, off);
        }
        int row = bm + wr * 64 + mi * 16 + fq * 4 + j;
        if (fr == 0 && row < M) {
          asrc[row * FH + hd] = ps;
          adst[row * FH + hd] = pd;
        }
      }
  }
}

// ---- CSR build: histogram of dst ----
__global__ __launch_bounds__(256) void hist_k(const int* __restrict__ ei,
                                              int* __restrict__ deg) {
  int e = blockIdx.x * 256 + threadIdx.x;
  if (e >= NET) return;
  int d = (e < NE) ? ei[NE + e] : e - NE;
  atomicAdd(&deg[d], 1);
}

// ---- hierarchical scan pass 1: per-block exclusive prefix + block sums ----
__global__ __launch_bounds__(256) void scan1_k(const int* __restrict__ deg,
                                               int* __restrict__ row_ptr,
                                               int* __restrict__ bsum) {
  int tid = threadIdx.x;
  int i = blockIdx.x * 256 + tid;
  int lane = tid & 63, w = tid >> 6;
  int val = (i < NN) ? deg[i] : 0;
  int s = val;
#pragma unroll
  for (int off = 1; off < 64; off <<= 1) {
    int t = __shfl_up(s, off);
    if (lane >= off) s += t;
  }
  __shared__ int wt[4], wo[4];
  if (lane == 63) wt[w] = s;
  __syncthreads();
  if (tid == 0) {
    int r = 0;
#pragma unroll
    for (int k = 0; k < 4; ++k) { wo[k] = r; r += wt[k]; }
    bsum[blockIdx.x] = r;
  }
  __syncthreads();
  if (i < NN) row_ptr[i] = s - val + wo[w];
}

// ---- scan pass 2: scan the NB block sums (single tiny block) ----
__global__ __launch_bounds__(256) void scan2_k(int* __restrict__ bsum,
                                               int* __restrict__ row_ptr) {
  int tid = threadIdx.x;
  int lane = tid & 63, w = tid >> 6;
  int val = (tid < NB) ? bsum[tid] : 0;
  int s = val;
#pragma unroll
  for (int off = 1; off < 64; off <<= 1) {
    int t = __shfl_up(s, off);
    if (lane >= off) s += t;
  }
  __shared__ int wt[4], wo[4];
  if (lane == 63) wt[w] = s;
  __syncthreads();
  if (tid == 0) {
    int r = 0;
#pragma unroll
    for (int k = 0; k < 4; ++k) { wo[k] = r; r += wt[k]; }
  }
  __syncthreads();
  int excl = s - val + wo[w];
  if (tid < NB) bsum[tid] = excl;
  if (tid == 255) row_ptr[NN] = excl;  // val=0 here -> excl == grand total
}

// ---- scan pass 3: add block offsets, init cursor ----
__global__ __launch_bounds__(256) void scan3_k(int* __restrict__ row_ptr,
                                               const int* __restrict__ bsum,
                                               int* __restrict__ cursor) {
  int i = blockIdx.x * 256 + threadIdx.x;
  if (i >= NN) return;
  int v = row_ptr[i] + bsum[blockIdx.x];
  row_ptr[i] = v;
  cursor[i] = v;
}

// ---- CSR build: fill src ids per dst bucket ----
__global__ __launch_bounds__(256) void fill_k(const int* __restrict__ ei,
                                              int* __restrict__ cursor,
                                              int* __restrict__ col_src) {
  int e = blockIdx.x * 256 + threadIdx.x;
  if (e >= NET) return;
  int s, d;
  if (e < NE) { s = ei[e]; d = ei[NE + e]; } else { s = d = e - NE; }
  int pos = atomicAdd(&cursor[d], 1);
  col_src[pos] = s;
}

// ---- graph boundary detection (batch is sorted) ----
__global__ __launch_bounds__(256) void bnd_k(const int* __restrict__ batch,
                                             int* __restrict__ gstart,
                                             int* __restrict__ gend) {
  int n = blockIdx.x * 256 + threadIdx.x;
  if (n >= NN) return;
  int b = batch[n];
  if (n == 0 || batch[n - 1] != b) gstart[b] = n;
  if (n == NN - 1 || batch[n + 1] != b) gend[b] = n + 1;
}

// ---- gather-aggregate: one wave per dst node, 8 bf16/lane, 4-edge chunks ----
template <int LAYER>
__global__ __launch_bounds__(256) void gather_k(const int* __restrict__ row_ptr,
                                                const int* __restrict__ col_src,
                                                const float* __restrict__ asrc,
                                                const float* __restrict__ adst,
                                                const u16* __restrict__ hb,
                                                const float* __restrict__ bias,
                                                u16* __restrict__ outb,
                                                float* __restrict__ nodeval) {
  int n = blockIdx.x * 4 + (threadIdx.x >> 6);
  if (n >= NN) return;
  int lane = threadIdx.x & 63;
  int hh = lane & 7;
  int hsel = lane >> 3;
  int start = row_ptr[n], end = row_ptr[n + 1];
  float adn = adst[n * FH + hh];
  float den = 0.f;
  float v[8] = {};
  for (int j0 = start; j0 < end; j0 += 4) {
    int sidx[4];
#pragma unroll
    for (int u = 0; u < 4; ++u) {
      int jj = (j0 + u < end) ? j0 + u : end - 1;
      sidx[u] = col_src[jj];
    }
    float ex[4];
#pragma unroll
    for (int u = 0; u < 4; ++u) {
      float el = asrc[sidx[u] * FH + hh] + adn;
      el = el > 0.f ? el : 0.2f * el;
      ex[u] = (j0 + u < end) ? __expf(el) : 0.f;
      den += ex[u];
    }
    u16x8 hv[4];
#pragma unroll
    for (int u = 0; u < 4; ++u)
      hv[u] = *reinterpret_cast<const u16x8*>(hb + (size_t)sidx[u] * FHC + lane * 8);
#pragma unroll
    for (int u = 0; u < 4; ++u) {
      float exv = __shfl(ex[u], hsel);
#pragma unroll
      for (int j = 0; j < 8; ++j) v[j] += exv * bf2f(hv[u][j]);
    }
  }
  float dh = __shfl(den, hsel);
  float inv = 1.f / (dh + 1e-16f);
#pragma unroll
  for (int j = 0; j < 8; ++j) v[j] *= inv;
  if (LAYER == 1) {
    const float4* bp = reinterpret_cast<const float4*>(bias + lane * 8);
    float4 b0 = bp[0], b1 = bp[1];
    float bb[8] = {b0.x, b0.y, b0.z, b0.w, b1.x, b1.y, b1.z, b1.w};
    u16x8 ov;
#pragma unroll
    for (int j = 0; j < 8; ++j) {
      float val = v[j] + bb[j];
      val = val > 0.f ? val : expm1f(val);
      ov[j] = f2bf(val);
    }
    *reinterpret_cast<u16x8*>(outb + (size_t)n * FHC + lane * 8) = ov;
  } else {
#pragma unroll
    for (int off = 8; off < 64; off <<= 1)
#pragma unroll
      for (int j = 0; j < 8; ++j) v[j] += __shfl_xor(v[j], off);
    if (lane < 8) {
      const float4* bp = reinterpret_cast<const float4*>(bias + lane * 8);
      float4 b0 = bp[0], b1 = bp[1];
      float bb[8] = {b0.x, b0.y, b0.z, b0.w, b1.x, b1.y, b1.z, b1.w};
      float o[8];
#pragma unroll
      for (int j = 0; j < 8; ++j) {
        float val = v[j] * (1.f / FH) + bb[j];
        o[j] = val > 0.f ? val : expm1f(val);
      }
      float4* np = reinterpret_cast<float4*>(nodeval + (size_t)n * FC + lane * 8);
      np[0] = make_float4(o[0], o[1], o[2], o[3]);
      np[1] = make_float4(o[4], o[5], o[6], o[7]);
    }
  }
}

// ---- pool: one block per graph over its contiguous node range ----
__global__ __launch_bounds__(256) void pool_k(const float* __restrict__ nodeval,
                                              const int* __restrict__ gstart,
                                              const int* __restrict__ gend,
                                              float* __restrict__ out) {
  __shared__ float red[4][FC];
  int g = blockIdx.x;
  int c = threadIdx.x & 63, w = threadIdx.x >> 6;
  int s = gstart[g], e = gend[g];
  float acc = 0.f;
  for (int n = s + w; n < e; n += 4) acc += nodeval[(size_t)n * FC + c];
  red[w][c] = acc;
  __syncthreads();
  if (w == 0) {
    float v = red[0][c] + red[1][c] + red[2][c] + red[3][c];
    out[g * FC + c] = v / fmaxf((float)(e - s), 1.f);
  }
}

extern "C" void kernel_launch(void* const* d_in, const int* in_sizes, int n_in,
                              void* d_out, int out_size, void* d_ws, size_t ws_size,
                              hipStream_t stream) {
  const float* x    = (const float*)d_in[0];
  const int*   ei   = (const int*)d_in[1];
  const int*   batch= (const int*)d_in[2];
  const float* W1   = (const float*)d_in[3];
  const float* as1  = (const float*)d_in[4];
  const float* ad1  = (const float*)d_in[5];
  const float* b1   = (const float*)d_in[6];
  const float* W2   = (const float*)d_in[7];
  const float* as2  = (const float*)d_in[8];
  const float* ad2  = (const float*)d_in[9];
  const float* b2   = (const float*)d_in[10];
  float* out = (float*)d_out;

  char* p = (char*)d_ws;
  u16* Cb  = (u16*)p; p += (size_t)NN * FHC * 2;     // 51.2 MB (GEMM out, bf16)
  u16* xh  = (u16*)p; p += (size_t)MPAD * FIN * 2;
  u16* xl  = (u16*)p; p += (size_t)MPAD * FIN * 2;
  u16* h1b = (u16*)p; p += (size_t)MPAD * FHC * 2;   // layer-1 out / GEMM2 A
  u16* w1h = (u16*)p; p += (size_t)FHC * FIN * 2;
  u16* w1l = (u16*)p; p += (size_t)FHC * FIN * 2;
  u16* w2h = (u16*)p; p += (size_t)FHC * FHC * 2;
  u16* w2l = (u16*)p; p += (size_t)FHC * FHC * 2;
  float* asrc = (float*)p;            p += (size_t)NN * FH * 4;
  float* adst = (float*)p;            p += (size_t)NN * FH * 4;
  int* deg    = (int*)p;              p += (size_t)NN * 4;
  int* rowp   = (int*)p;              p += (size_t)(NN + 1) * 4;
  int* cursor = (int*)p;              p += (size_t)NN * 4;
  int* col    = (int*)p;              p += (size_t)NET * 4;
  int* gstart = (int*)p;              p += (size_t)NG * 4;
  int* gend   = (int*)p;              p += (size_t)NG * 4;
  int* bsum   = (int*)p;              p += (size_t)NB * 4;
  // nodeval reuses xh's region (dead by the time gather_k<2> runs)
  float* nodeval = (float*)xh;

  const int NWG = (MPAD / 128) * (FHC / 128);   // 1564, 1D XCD-chunked grid
  const int egrid = (NET + 255) / 256;
  const int ngrid = (NN + 3) / 4;

  // ---- zero-init: deg, boundaries, pad rows of A planes ----
  hipMemsetAsync(deg, 0, (size_t)NN * 4, stream);
  hipMemsetAsync(gstart, 0, (size_t)NG * 2 * 4, stream);
  hipMemsetAsync(xh + (size_t)NN * FIN, 0, (size_t)(MPAD - NN) * FIN * 2, stream);
  hipMemsetAsync(xl + (size_t)NN * FIN, 0, (size_t)(MPAD - NN) * FIN * 2, stream);
  hipMemsetAsync(h1b + (size_t)NN * FHC, 0, (size_t)(MPAD - NN) * FHC * 2, stream);

  // ---- conversions ----
  conv_split_k<<<(NN * FIN / 4 + 255) / 256, 256, 0, stream>>>(x, xh, xl, NN * FIN / 4);
  conv_wt_k<<<(FIN * FHC + 255) / 256, 256, 0, stream>>>(W1, w1h, w1l, FIN);
  conv_wt_k<<<(FHC * FHC + 255) / 256, 256, 0, stream>>>(W2, w2h, w2l, FHC);

  // ---- CSR build (3-pass parallel scan) + graph boundaries ----
  hist_k<<<egrid, 256, 0, stream>>>(ei, deg);
  scan1_k<<<NB, 256, 0, stream>>>(deg, rowp, bsum);
  scan2_k<<<1, 256, 0, stream>>>(bsum, rowp);
  scan3_k<<<NB, 256, 0, stream>>>(rowp, bsum, cursor);
  fill_k<<<egrid, 256, 0, stream>>>(ei, cursor, col);
  bnd_k<<<(NN + 255) / 256, 256, 0, stream>>>(batch, gstart, gend);

  // ---- layer 1 (alphas fused into GEMM epilogue) ----
  gemm_mfma<2><<<NWG, 256, 0, stream>>>(xh, xl, w1h, w1l, Cb,
                                        as1, ad1, asrc, adst, NN, FIN);
  gather_k<1><<<ngrid, 256, 0, stream>>>(rowp, col, asrc, adst, Cb, b1,
                                         h1b, nullptr);

  // ---- layer 2 (A single bf16 plane, 2 MFMA products) ----
  gemm_mfma<1><<<NWG, 256, 0, stream>>>(h1b, nullptr, w2h, w2l, Cb,
                                        as2, ad2, asrc, adst, NN, FHC);
  gather_k<2><<<ngrid, 256, 0, stream>>>(rowp, col, asrc, adst, Cb, b2,
                                         nullptr, nodeval);

  pool_k<<<NG, 256, 0, stream>>>(nodeval, gstart, gend, out);
}

// Round 10
// 412.577 us; speedup vs baseline: 6.2337x; 1.0062x over previous
//
#include <hip/hip_runtime.h>
#include <hip/hip_bf16.h>
#include <math.h>

// Problem constants (from reference setup_inputs)
#define NN   50000      // nodes
#define NE   400000     // edges (without self loops)
#define NET  450000     // edges + self loops
#define FH   8          // heads
#define FC   64         // channels per head
#define FHC  512        // H*C
#define FIN  128        // input features
#define NG   64         // graphs
#define MPAD 50048      // NN padded to tile multiple (391*128)
#define NB   196        // scan blocks = ceil(NN/256)

typedef unsigned short u16;
typedef __bf16 bf16x8 __attribute__((ext_vector_type(8)));
typedef float f32x4 __attribute__((ext_vector_type(4)));
typedef unsigned short u16x8 __attribute__((ext_vector_type(8)));

// ---- f32 -> bf16 (RNE) bit helpers ----
static __device__ __forceinline__ u16 f2bf(float f) {
  unsigned u = __float_as_uint(f);
  unsigned r = (u + 0x7fffu + ((u >> 16) & 1u)) >> 16;
  return (u16)r;
}
static __device__ __forceinline__ float bf2f(u16 h) {
  return __uint_as_float(((unsigned)h) << 16);
}

// ---- split-convert: f32 -> (hi, lo) bf16 planes, 4 elems/thread ----
__global__ __launch_bounds__(256) void conv_split_k(const float* __restrict__ in,
                                                    u16* __restrict__ hi,
                                                    u16* __restrict__ lo,
                                                    int n4) {
  int t = blockIdx.x * 256 + threadIdx.x;
  if (t >= n4) return;
  float4 f = reinterpret_cast<const float4*>(in)[t];
  ushort4 h, l;
  h.x = f2bf(f.x); l.x = f2bf(f.x - bf2f(h.x));
  h.y = f2bf(f.y); l.y = f2bf(f.y - bf2f(h.y));
  h.z = f2bf(f.z); l.z = f2bf(f.z - bf2f(h.z));
  h.w = f2bf(f.w); l.w = f2bf(f.w - bf2f(h.w));
  reinterpret_cast<ushort4*>(hi)[t] = h;
  reinterpret_cast<ushort4*>(lo)[t] = l;
}

// ---- W [K,512] -> transposed hi/lo planes Wt [512,K] ----
__global__ __launch_bounds__(256) void conv_wt_k(const float* __restrict__ W,
                                                 u16* __restrict__ hiT,
                                                 u16* __restrict__ loT,
                                                 int K) {
  int t = blockIdx.x * 256 + threadIdx.x;
  if (t >= K * FHC) return;
  int k = t >> 9, n = t & 511;
  float f = W[t];
  u16 h = f2bf(f);
  hiT[n * K + k] = h;
  loT[n * K + k] = f2bf(f - bf2f(h));
}

// ---- split-bf16 MFMA GEMM + fused attention-logit epilogue.
// APL=2: A hi+lo planes (3 products), 32 KB LDS. APL=1: A single bf16
// (2 products), 24 KB LDS -> 5 blocks/CU (VGPR-capped), BK=32.
// 1D grid with bijective XCD-chunking for A-panel L2 reuse.
template <int APL>
__global__ __launch_bounds__(256) void gemm_mfma(const u16* __restrict__ Ah,
                                                 const u16* __restrict__ Al,
                                                 const u16* __restrict__ Bh,
                                                 const u16* __restrict__ Bl,
                                                 u16* __restrict__ Cb,
                                                 const float* __restrict__ As_g,
                                                 const float* __restrict__ Ad_g,
                                                 float* __restrict__ asrc,
                                                 float* __restrict__ adst,
                                                 int M, int K) {
  constexpr int BK = 32;                         // k-tile depth
  constexpr int GPR = BK / 8;                    // 8-u16 granules per row
  __shared__ u16 AsH[128 * BK];
  __shared__ u16 AsL[(APL == 2) ? 128 * BK : 8];
  __shared__ u16 BsH[128 * BK];
  __shared__ u16 BsL[128 * BK];
  const int tid = threadIdx.x;
  // ---- bijective XCD-chunked block id -> (mt, nt) ----
  constexpr int NWG = (MPAD / 128) * (FHC / 128);  // 1564
  constexpr int qq = NWG >> 3, rr = NWG & 7;
  int d = blockIdx.x;
  int xcd = d & 7, slot = d >> 3;
  int w = (xcd < rr) ? xcd * (qq + 1) + slot
                     : rr * (qq + 1) + (xcd - rr) * qq + slot;
  const int bm = (w >> 2) * 128;
  const int bn = (w & 3) * 128;
  const int wv = tid >> 6, l = tid & 63;
  const int wr = wv >> 1, wc = wv & 1;
  const int fr = l & 15, fq = l >> 4;

  f32x4 acc[4][4] = {};

  for (int k0 = 0; k0 < K; k0 += BK) {
    __syncthreads();
#pragma unroll
    for (int i = 0; i < BK / 16; ++i) {
      int idx = i * 256 + tid;
      int row = idx / GPR, c8 = idx % GPR;
      size_t goA = (size_t)(bm + row) * K + k0 + c8 * 8;
      size_t goB = (size_t)(bn + row) * K + k0 + c8 * 8;
      __builtin_amdgcn_global_load_lds(
          (const __attribute__((address_space(1))) void*)(Ah + goA),
          (__attribute__((address_space(3))) void*)(AsH + idx * 8), 16, 0, 0);
      if (APL == 2)
        __builtin_amdgcn_global_load_lds(
            (const __attribute__((address_space(1))) void*)(Al + goA),
            (__attribute__((address_space(3))) void*)(AsL + idx * 8), 16, 0, 0);
      __builtin_amdgcn_global_load_lds(
          (const __attribute__((address_space(1))) void*)(Bh + goB),
          (__attribute__((address_space(3))) void*)(BsH + idx * 8), 16, 0, 0);
      __builtin_amdgcn_global_load_lds(
          (const __attribute__((address_space(1))) void*)(Bl + goB),
          (__attribute__((address_space(3))) void*)(BsL + idx * 8), 16, 0, 0);
    }
    __syncthreads();
    {
      bf16x8 ah[4], al4[4], bh[4], bl4[4];
#pragma unroll
      for (int mi = 0; mi < 4; ++mi) {
        int off = (wr * 64 + mi * 16 + fr) * BK + fq * 8;
        ah[mi] = *reinterpret_cast<const bf16x8*>(AsH + off);
        if (APL == 2) al4[mi] = *reinterpret_cast<const bf16x8*>(AsL + off);
      }
#pragma unroll
      for (int ni = 0; ni < 4; ++ni) {
        int off = (wc * 64 + ni * 16 + fr) * BK + fq * 8;
        bh[ni]  = *reinterpret_cast<const bf16x8*>(BsH + off);
        bl4[ni] = *reinterpret_cast<const bf16x8*>(BsL + off);
      }
#pragma unroll
      for (int mi = 0; mi < 4; ++mi)
#pragma unroll
        for (int ni = 0; ni < 4; ++ni) {
          acc[mi][ni] = __builtin_amdgcn_mfma_f32_16x16x32_bf16(
              ah[mi], bh[ni], acc[mi][ni], 0, 0, 0);
          acc[mi][ni] = __builtin_amdgcn_mfma_f32_16x16x32_bf16(
              ah[mi], bl4[ni], acc[mi][ni], 0, 0, 0);
          if (APL == 2)
            acc[mi][ni] = __builtin_amdgcn_mfma_f32_16x16x32_bf16(
                al4[mi], bh[ni], acc[mi][ni], 0, 0, 0);
        }
    }
  }
  // ---- C store (bf16 plane) ----
#pragma unroll
  for (int mi = 0; mi < 4; ++mi)
#pragma unroll
    for (int ni = 0; ni < 4; ++ni) {
      int r0 = bm + wr * 64 + mi * 16 + fq * 4;
      int c0 = bn + wc * 64 + ni * 16 + fr;
#pragma unroll
      for (int j = 0; j < 4; ++j)
        if (r0 + j < M) Cb[(size_t)(r0 + j) * FHC + c0] = f2bf(acc[mi][ni][j]);
    }
  // ---- fused attention logits: this wave's 64 cols == head hd ----
  {
    int hd = (bn >> 6) + wc;
    int cb = bn + wc * 64 + fr;
    float as_v[4], ad_v[4];
#pragma unroll
    for (int ni = 0; ni < 4; ++ni) {
      as_v[ni] = As_g[cb + ni * 16];
      ad_v[ni] = Ad_g[cb + ni * 16];
    }
#pragma unroll
    for (int mi = 0; mi < 4; ++mi)
#pragma unroll
      for (int j = 0; j < 4; ++j) {
        float ps = 0.f, pd = 0.f;
#pragma unroll
        for (int ni = 0; ni < 4; ++ni) {
          float v = acc[mi][ni][j];
          ps += v * as_v[ni];
          pd += v * ad_v[ni];
        }
#pragma unroll
        for (int off = 1; off < 16; off <<= 1) {
          ps += __shfl_xor(ps, off);
          pd += __shfl_xor(pd, off);
        }
        int row = bm + wr * 64 + mi * 16 + fq * 4 + j;
        if (fr == 0 && row < M) {
          asrc[row * FH + hd] = ps;
          adst[row * FH + hd] = pd;
        }
      }
  }
}

// ---- CSR build: histogram of dst ----
__global__ __launch_bounds__(256) void hist_k(const int* __restrict__ ei,
                                              int* __restrict__ deg) {
  int e = blockIdx.x * 256 + threadIdx.x;
  if (e >= NET) return;
  int d = (e < NE) ? ei[NE + e] : e - NE;
  atomicAdd(&deg[d], 1);
}

// ---- hierarchical scan pass 1: per-block exclusive prefix + block sums ----
__global__ __launch_bounds__(256) void scan1_k(const int* __restrict__ deg,
                                               int* __restrict__ row_ptr,
                                               int* __restrict__ bsum) {
  int tid = threadIdx.x;
  int i = blockIdx.x * 256 + tid;
  int lane = tid & 63, w = tid >> 6;
  int val = (i < NN) ? deg[i] : 0;
  int s = val;
#pragma unroll
  for (int off = 1; off < 64; off <<= 1) {
    int t = __shfl_up(s, off);
    if (lane >= off) s += t;
  }
  __shared__ int wt[4], wo[4];
  if (lane == 63) wt[w] = s;
  __syncthreads();
  if (tid == 0) {
    int r = 0;
#pragma unroll
    for (int k = 0; k < 4; ++k) { wo[k] = r; r += wt[k]; }
    bsum[blockIdx.x] = r;
  }
  __syncthreads();
  if (i < NN) row_ptr[i] = s - val + wo[w];
}

// ---- scan pass 2: scan the NB block sums (single tiny block) ----
__global__ __launch_bounds__(256) void scan2_k(int* __restrict__ bsum,
                                               int* __restrict__ row_ptr) {
  int tid = threadIdx.x;
  int lane = tid & 63, w = tid >> 6;
  int val = (tid < NB) ? bsum[tid] : 0;
  int s = val;
#pragma unroll
  for (int off = 1; off < 64; off <<= 1) {
    int t = __shfl_up(s, off);
    if (lane >= off) s += t;
  }
  __shared__ int wt[4], wo[4];
  if (lane == 63) wt[w] = s;
  __syncthreads();
  if (tid == 0) {
    int r = 0;
#pragma unroll
    for (int k = 0; k < 4; ++k) { wo[k] = r; r += wt[k]; }
  }
  __syncthreads();
  int excl = s - val + wo[w];
  if (tid < NB) bsum[tid] = excl;
  if (tid == 255) row_ptr[NN] = excl;  // val=0 here -> excl == grand total
}

// ---- scan pass 3: add block offsets, init cursor ----
__global__ __launch_bounds__(256) void scan3_k(int* __restrict__ row_ptr,
                                               const int* __restrict__ bsum,
                                               int* __restrict__ cursor) {
  int i = blockIdx.x * 256 + threadIdx.x;
  if (i >= NN) return;
  int v = row_ptr[i] + bsum[blockIdx.x];
  row_ptr[i] = v;
  cursor[i] = v;
}

// ---- CSR build: fill src ids per dst bucket ----
__global__ __launch_bounds__(256) void fill_k(const int* __restrict__ ei,
                                              int* __restrict__ cursor,
                                              int* __restrict__ col_src) {
  int e = blockIdx.x * 256 + threadIdx.x;
  if (e >= NET) return;
  int s, d;
  if (e < NE) { s = ei[e]; d = ei[NE + e]; } else { s = d = e - NE; }
  int pos = atomicAdd(&cursor[d], 1);
  col_src[pos] = s;
}

// ---- graph boundary detection (batch is sorted) ----
__global__ __launch_bounds__(256) void bnd_k(const int* __restrict__ batch,
                                             int* __restrict__ gstart,
                                             int* __restrict__ gend) {
  int n = blockIdx.x * 256 + threadIdx.x;
  if (n >= NN) return;
  int b = batch[n];
  if (n == 0 || batch[n - 1] != b) gstart[b] = n;
  if (n == NN - 1 || batch[n + 1] != b) gend[b] = n + 1;
}

// ---- gather-aggregate: one wave per dst node, 8 bf16/lane, 4-edge chunks ----
template <int LAYER>
__global__ __launch_bounds__(256) void gather_k(const int* __restrict__ row_ptr,
                                                const int* __restrict__ col_src,
                                                const float* __restrict__ asrc,
                                                const float* __restrict__ adst,
                                                const u16* __restrict__ hb,
                                                const float* __restrict__ bias,
                                                u16* __restrict__ outb,
                                                float* __restrict__ nodeval) {
  int n = blockIdx.x * 4 + (threadIdx.x >> 6);
  if (n >= NN) return;
  int lane = threadIdx.x & 63;
  int hh = lane & 7;
  int hsel = lane >> 3;
  int start = row_ptr[n], end = row_ptr[n + 1];
  float adn = adst[n * FH + hh];
  float den = 0.f;
  float v[8] = {};
  for (int j0 = start; j0 < end; j0 += 4) {
    int sidx[4];
#pragma unroll
    for (int u = 0; u < 4; ++u) {
      int jj = (j0 + u < end) ? j0 + u : end - 1;
      sidx[u] = col_src[jj];
    }
    float ex[4];
#pragma unroll
    for (int u = 0; u < 4; ++u) {
      float el = asrc[sidx[u] * FH + hh] + adn;
      el = el > 0.f ? el : 0.2f * el;
      ex[u] = (j0 + u < end) ? __expf(el) : 0.f;
      den += ex[u];
    }
    u16x8 hv[4];
#pragma unroll
    for (int u = 0; u < 4; ++u)
      hv[u] = *reinterpret_cast<const u16x8*>(hb + (size_t)sidx[u] * FHC + lane * 8);
#pragma unroll
    for (int u = 0; u < 4; ++u) {
      float exv = __shfl(ex[u], hsel);
#pragma unroll
      for (int j = 0; j < 8; ++j) v[j] += exv * bf2f(hv[u][j]);
    }
  }
  float dh = __shfl(den, hsel);
  float inv = 1.f / (dh + 1e-16f);
#pragma unroll
  for (int j = 0; j < 8; ++j) v[j] *= inv;
  if (LAYER == 1) {
    const float4* bp = reinterpret_cast<const float4*>(bias + lane * 8);
    float4 b0 = bp[0], b1 = bp[1];
    float bb[8] = {b0.x, b0.y, b0.z, b0.w, b1.x, b1.y, b1.z, b1.w};
    u16x8 ov;
#pragma unroll
    for (int j = 0; j < 8; ++j) {
      float val = v[j] + bb[j];
      val = val > 0.f ? val : expm1f(val);
      ov[j] = f2bf(val);
    }
    *reinterpret_cast<u16x8*>(outb + (size_t)n * FHC + lane * 8) = ov;
  } else {
#pragma unroll
    for (int off = 8; off < 64; off <<= 1)
#pragma unroll
      for (int j = 0; j < 8; ++j) v[j] += __shfl_xor(v[j], off);
    if (lane < 8) {
      const float4* bp = reinterpret_cast<const float4*>(bias + lane * 8);
      float4 b0 = bp[0], b1 = bp[1];
      float bb[8] = {b0.x, b0.y, b0.z, b0.w, b1.x, b1.y, b1.z, b1.w};
      float o[8];
#pragma unroll
      for (int j = 0; j < 8; ++j) {
        float val = v[j] * (1.f / FH) + bb[j];
        o[j] = val > 0.f ? val : expm1f(val);
      }
      float4* np = reinterpret_cast<float4*>(nodeval + (size_t)n * FC + lane * 8);
      np[0] = make_float4(o[0], o[1], o[2], o[3]);
      np[1] = make_float4(o[4], o[5], o[6], o[7]);
    }
  }
}

// ---- pool: one block per graph over its contiguous node range ----
__global__ __launch_bounds__(256) void pool_k(const float* __restrict__ nodeval,
                                              const int* __restrict__ gstart,
                                              const int* __restrict__ gend,
                                              float* __restrict__ out) {
  __shared__ float red[4][FC];
  int g = blockIdx.x;
  int c = threadIdx.x & 63, w = threadIdx.x >> 6;
  int s = gstart[g], e = gend[g];
  float acc = 0.f;
  for (int n = s + w; n < e; n += 4) acc += nodeval[(size_t)n * FC + c];
  red[w][c] = acc;
  __syncthreads();
  if (w == 0) {
    float v = red[0][c] + red[1][c] + red[2][c] + red[3][c];
    out[g * FC + c] = v / fmaxf((float)(e - s), 1.f);
  }
}

extern "C" void kernel_launch(void* const* d_in, const int* in_sizes, int n_in,
                              void* d_out, int out_size, void* d_ws, size_t ws_size,
                              hipStream_t stream) {
  const float* x    = (const float*)d_in[0];
  const int*   ei   = (const int*)d_in[1];
  const int*   batch= (const int*)d_in[2];
  const float* W1   = (const float*)d_in[3];
  const float* as1  = (const float*)d_in[4];
  const float* ad1  = (const float*)d_in[5];
  const float* b1   = (const float*)d_in[6];
  const float* W2   = (const float*)d_in[7];
  const float* as2  = (const float*)d_in[8];
  const float* ad2  = (const float*)d_in[9];
  const float* b2   = (const float*)d_in[10];
  float* out = (float*)d_out;

  char* p = (char*)d_ws;
  u16* Cb  = (u16*)p; p += (size_t)NN * FHC * 2;     // 51.2 MB (GEMM out, bf16)
  u16* xh  = (u16*)p; p += (size_t)MPAD * FIN * 2;
  u16* xl  = (u16*)p; p += (size_t)MPAD * FIN * 2;
  u16* h1b = (u16*)p; p += (size_t)MPAD * FHC * 2;   // layer-1 out / GEMM2 A
  u16* w1h = (u16*)p; p += (size_t)FHC * FIN * 2;
  u16* w1l = (u16*)p; p += (size_t)FHC * FIN * 2;
  u16* w2h = (u16*)p; p += (size_t)FHC * FHC * 2;
  u16* w2l = (u16*)p; p += (size_t)FHC * FHC * 2;
  float* asrc = (float*)p;            p += (size_t)NN * FH * 4;
  float* adst = (float*)p;            p += (size_t)NN * FH * 4;
  int* deg    = (int*)p;              p += (size_t)NN * 4;
  int* rowp   = (int*)p;              p += (size_t)(NN + 1) * 4;
  int* cursor = (int*)p;              p += (size_t)NN * 4;
  int* col    = (int*)p;              p += (size_t)NET * 4;
  int* gstart = (int*)p;              p += (size_t)NG * 4;
  int* gend   = (int*)p;              p += (size_t)NG * 4;
  int* bsum   = (int*)p;              p += (size_t)NB * 4;
  // nodeval reuses xh's region (dead by the time gather_k<2> runs)
  float* nodeval = (float*)xh;

  const int NWG = (MPAD / 128) * (FHC / 128);   // 1564, 1D XCD-chunked grid
  const int egrid = (NET + 255) / 256;
  const int ngrid = (NN + 3) / 4;

  // ---- zero-init: deg, boundaries, pad rows of A planes ----
  hipMemsetAsync(deg, 0, (size_t)NN * 4, stream);
  hipMemsetAsync(gstart, 0, (size_t)NG * 2 * 4, stream);
  hipMemsetAsync(xh + (size_t)NN * FIN, 0, (size_t)(MPAD - NN) * FIN * 2, stream);
  hipMemsetAsync(xl + (size_t)NN * FIN, 0, (size_t)(MPAD - NN) * FIN * 2, stream);
  hipMemsetAsync(h1b + (size_t)NN * FHC, 0, (size_t)(MPAD - NN) * FHC * 2, stream);

  // ---- conversions ----
  conv_split_k<<<(NN * FIN / 4 + 255) / 256, 256, 0, stream>>>(x, xh, xl, NN * FIN / 4);
  conv_wt_k<<<(FIN * FHC + 255) / 256, 256, 0, stream>>>(W1, w1h, w1l, FIN);
  conv_wt_k<<<(FHC * FHC + 255) / 256, 256, 0, stream>>>(W2, w2h, w2l, FHC);

  // ---- CSR build (3-pass parallel scan) + graph boundaries ----
  hist_k<<<egrid, 256, 0, stream>>>(ei, deg);
  scan1_k<<<NB, 256, 0, stream>>>(deg, rowp, bsum);
  scan2_k<<<1, 256, 0, stream>>>(bsum, rowp);
  scan3_k<<<NB, 256, 0, stream>>>(rowp, bsum, cursor);
  fill_k<<<egrid, 256, 0, stream>>>(ei, cursor, col);
  bnd_k<<<(NN + 255) / 256, 256, 0, stream>>>(batch, gstart, gend);

  // ---- layer 1 (alphas fused into GEMM epilogue) ----
  gemm_mfma<2><<<NWG, 256, 0, stream>>>(xh, xl, w1h, w1l, Cb,
                                        as1, ad1, asrc, adst, NN, FIN);
  gather_k<1><<<ngrid, 256, 0, stream>>>(rowp, col, asrc, adst, Cb, b1,
                                         h1b, nullptr);

  // ---- layer 2 (A single bf16 plane, 2 MFMA products) ----
  gemm_mfma<1><<<NWG, 256, 0, stream>>>(h1b, nullptr, w2h, w2l, Cb,
                                        as2, ad2, asrc, adst, NN, FHC);
  gather_k<2><<<ngrid, 256, 0, stream>>>(rowp, col, asrc, adst, Cb, b2,
                                         nullptr, nodeval);

  pool_k<<<NG, 256, 0, stream>>>(nodeval, gstart, gend, out);
}

// Round 11
// 383.045 us; speedup vs baseline: 6.7143x; 1.0771x over previous
//
#include <hip/hip_runtime.h>
#include <hip/hip_bf16.h>
#include <hip/hip_fp16.h>
#include <math.h>

// Problem constants (from reference setup_inputs)
#define NN   50000      // nodes
#define NE   400000     // edges (without self loops)
#define NET  450000     // edges + self loops
#define FH   8          // heads
#define FC   64         // channels per head
#define FHC  512        // H*C
#define FIN  128        // input features
#define NG   64         // graphs
#define MPAD 50048      // NN padded to tile multiple (391*128)
#define NB   196        // scan blocks = ceil(NN/256)

typedef unsigned short u16;
typedef _Float16 f16x8 __attribute__((ext_vector_type(8)));
typedef float f32x4 __attribute__((ext_vector_type(4)));
typedef unsigned short u16x8 __attribute__((ext_vector_type(8)));

// ---- f32 <-> fp16 helpers (RNE) ----
static __device__ __forceinline__ u16 f2h(float f) {
  return __half_as_ushort(__float2half(f));
}
static __device__ __forceinline__ float h2f(u16 u) {
  return __half2float(__ushort_as_half(u));
}

// ---- convert x -> fp16 plane, 4 elems/thread ----
__global__ __launch_bounds__(256) void conv_h_k(const float* __restrict__ in,
                                                u16* __restrict__ outp,
                                                int n4) {
  int t = blockIdx.x * 256 + threadIdx.x;
  if (t >= n4) return;
  float4 f = reinterpret_cast<const float4*>(in)[t];
  ushort4 h;
  h.x = f2h(f.x); h.y = f2h(f.y); h.z = f2h(f.z); h.w = f2h(f.w);
  reinterpret_cast<ushort4*>(outp)[t] = h;
}

// ---- W [K,512] -> transposed fp16 plane Wt [512,K] ----
__global__ __launch_bounds__(256) void conv_wt_k(const float* __restrict__ W,
                                                 u16* __restrict__ hT,
                                                 int K) {
  int t = blockIdx.x * 256 + threadIdx.x;
  if (t >= K * FHC) return;
  int k = t >> 9, n = t & 511;
  hT[n * K + k] = f2h(W[t]);
}

// ---- fp16 MFMA GEMM + fused attention-logit epilogue.
// C[M,512] = A[M,K] @ Wt^T, all fp16 inputs, f32 accumulate.
// 128x128 tile, 4 waves, BK=64, 32 KB LDS. Bijective XCD-chunked 1D grid.
__global__ __launch_bounds__(256) void gemm_mfma(const u16* __restrict__ Af,
                                                 const u16* __restrict__ Bf,
                                                 u16* __restrict__ Cb,
                                                 const float* __restrict__ As_g,
                                                 const float* __restrict__ Ad_g,
                                                 float* __restrict__ asrc,
                                                 float* __restrict__ adst,
                                                 int M, int K) {
  constexpr int BK = 64;
  __shared__ u16 As[128 * BK];   // 16 KB
  __shared__ u16 Bs[128 * BK];   // 16 KB
  const int tid = threadIdx.x;
  // ---- bijective XCD-chunked block id -> (mt, nt) ----
  constexpr int NWG = (MPAD / 128) * (FHC / 128);  // 1564
  constexpr int qq = NWG >> 3, rr = NWG & 7;
  int d = blockIdx.x;
  int xcd = d & 7, slot = d >> 3;
  int w = (xcd < rr) ? xcd * (qq + 1) + slot
                     : rr * (qq + 1) + (xcd - rr) * qq + slot;
  const int bm = (w >> 2) * 128;
  const int bn = (w & 3) * 128;
  const int wv = tid >> 6, l = tid & 63;
  const int wr = wv >> 1, wc = wv & 1;
  const int fr = l & 15, fq = l >> 4;

  f32x4 acc[4][4] = {};

  for (int k0 = 0; k0 < K; k0 += BK) {
    __syncthreads();
#pragma unroll
    for (int i = 0; i < 4; ++i) {
      int idx = i * 256 + tid;          // 1024 granules of 8 fp16
      int row = idx >> 3, c8 = idx & 7;
      size_t goA = (size_t)(bm + row) * K + k0 + c8 * 8;
      size_t goB = (size_t)(bn + row) * K + k0 + c8 * 8;
      __builtin_amdgcn_global_load_lds(
          (const __attribute__((address_space(1))) void*)(Af + goA),
          (__attribute__((address_space(3))) void*)(As + idx * 8), 16, 0, 0);
      __builtin_amdgcn_global_load_lds(
          (const __attribute__((address_space(1))) void*)(Bf + goB),
          (__attribute__((address_space(3))) void*)(Bs + idx * 8), 16, 0, 0);
    }
    __syncthreads();
#pragma unroll
    for (int kk = 0; kk < 2; ++kk) {
      f16x8 av[4], bv[4];
#pragma unroll
      for (int mi = 0; mi < 4; ++mi)
        av[mi] = *reinterpret_cast<const f16x8*>(
            As + (wr * 64 + mi * 16 + fr) * BK + kk * 32 + fq * 8);
#pragma unroll
      for (int ni = 0; ni < 4; ++ni)
        bv[ni] = *reinterpret_cast<const f16x8*>(
            Bs + (wc * 64 + ni * 16 + fr) * BK + kk * 32 + fq * 8);
#pragma unroll
      for (int mi = 0; mi < 4; ++mi)
#pragma unroll
        for (int ni = 0; ni < 4; ++ni)
          acc[mi][ni] = __builtin_amdgcn_mfma_f32_16x16x32_f16(
              av[mi], bv[ni], acc[mi][ni], 0, 0, 0);
    }
  }
  // ---- C store (fp16 plane) ----
#pragma unroll
  for (int mi = 0; mi < 4; ++mi)
#pragma unroll
    for (int ni = 0; ni < 4; ++ni) {
      int r0 = bm + wr * 64 + mi * 16 + fq * 4;
      int c0 = bn + wc * 64 + ni * 16 + fr;
#pragma unroll
      for (int j = 0; j < 4; ++j)
        if (r0 + j < M) Cb[(size_t)(r0 + j) * FHC + c0] = f2h(acc[mi][ni][j]);
    }
  // ---- fused attention logits: this wave's 64 cols == head hd ----
  {
    int hd = (bn >> 6) + wc;
    int cb = bn + wc * 64 + fr;
    float as_v[4], ad_v[4];
#pragma unroll
    for (int ni = 0; ni < 4; ++ni) {
      as_v[ni] = As_g[cb + ni * 16];
      ad_v[ni] = Ad_g[cb + ni * 16];
    }
#pragma unroll
    for (int mi = 0; mi < 4; ++mi)
#pragma unroll
      for (int j = 0; j < 4; ++j) {
        float ps = 0.f, pd = 0.f;
#pragma unroll
        for (int ni = 0; ni < 4; ++ni) {
          float v = acc[mi][ni][j];
          ps += v * as_v[ni];
          pd += v * ad_v[ni];
        }
#pragma unroll
        for (int off = 1; off < 16; off <<= 1) {
          ps += __shfl_xor(ps, off);
          pd += __shfl_xor(pd, off);
        }
        int row = bm + wr * 64 + mi * 16 + fq * 4 + j;
        if (fr == 0 && row < M) {
          asrc[row * FH + hd] = ps;
          adst[row * FH + hd] = pd;
        }
      }
  }
}

// ---- CSR build: histogram of dst ----
__global__ __launch_bounds__(256) void hist_k(const int* __restrict__ ei,
                                              int* __restrict__ deg) {
  int e = blockIdx.x * 256 + threadIdx.x;
  if (e >= NET) return;
  int d = (e < NE) ? ei[NE + e] : e - NE;
  atomicAdd(&deg[d], 1);
}

// ---- hierarchical scan pass 1: per-block exclusive prefix + block sums ----
__global__ __launch_bounds__(256) void scan1_k(const int* __restrict__ deg,
                                               int* __restrict__ row_ptr,
                                               int* __restrict__ bsum) {
  int tid = threadIdx.x;
  int i = blockIdx.x * 256 + tid;
  int lane = tid & 63, w = tid >> 6;
  int val = (i < NN) ? deg[i] : 0;
  int s = val;
#pragma unroll
  for (int off = 1; off < 64; off <<= 1) {
    int t = __shfl_up(s, off);
    if (lane >= off) s += t;
  }
  __shared__ int wt[4], wo[4];
  if (lane == 63) wt[w] = s;
  __syncthreads();
  if (tid == 0) {
    int r = 0;
#pragma unroll
    for (int k = 0; k < 4; ++k) { wo[k] = r; r += wt[k]; }
    bsum[blockIdx.x] = r;
  }
  __syncthreads();
  if (i < NN) row_ptr[i] = s - val + wo[w];
}

// ---- scan pass 2: scan the NB block sums (single tiny block) ----
__global__ __launch_bounds__(256) void scan2_k(int* __restrict__ bsum,
                                               int* __restrict__ row_ptr) {
  int tid = threadIdx.x;
  int lane = tid & 63, w = tid >> 6;
  int val = (tid < NB) ? bsum[tid] : 0;
  int s = val;
#pragma unroll
  for (int off = 1; off < 64; off <<= 1) {
    int t = __shfl_up(s, off);
    if (lane >= off) s += t;
  }
  __shared__ int wt[4], wo[4];
  if (lane == 63) wt[w] = s;
  __syncthreads();
  if (tid == 0) {
    int r = 0;
#pragma unroll
    for (int k = 0; k < 4; ++k) { wo[k] = r; r += wt[k]; }
  }
  __syncthreads();
  int excl = s - val + wo[w];
  if (tid < NB) bsum[tid] = excl;
  if (tid == 255) row_ptr[NN] = excl;  // val=0 here -> excl == grand total
}

// ---- scan pass 3: add block offsets, init cursor ----
__global__ __launch_bounds__(256) void scan3_k(int* __restrict__ row_ptr,
                                               const int* __restrict__ bsum,
                                               int* __restrict__ cursor) {
  int i = blockIdx.x * 256 + threadIdx.x;
  if (i >= NN) return;
  int v = row_ptr[i] + bsum[blockIdx.x];
  row_ptr[i] = v;
  cursor[i] = v;
}

// ---- CSR build: fill src ids per dst bucket ----
__global__ __launch_bounds__(256) void fill_k(const int* __restrict__ ei,
                                              int* __restrict__ cursor,
                                              int* __restrict__ col_src) {
  int e = blockIdx.x * 256 + threadIdx.x;
  if (e >= NET) return;
  int s, d;
  if (e < NE) { s = ei[e]; d = ei[NE + e]; } else { s = d = e - NE; }
  int pos = atomicAdd(&cursor[d], 1);
  col_src[pos] = s;
}

// ---- graph boundary detection (batch is sorted) ----
__global__ __launch_bounds__(256) void bnd_k(const int* __restrict__ batch,
                                             int* __restrict__ gstart,
                                             int* __restrict__ gend) {
  int n = blockIdx.x * 256 + threadIdx.x;
  if (n >= NN) return;
  int b = batch[n];
  if (n == 0 || batch[n - 1] != b) gstart[b] = n;
  if (n == NN - 1 || batch[n + 1] != b) gend[b] = n + 1;
}

// ---- gather-aggregate: one wave per dst node, 8 fp16/lane, 4-edge chunks ----
template <int LAYER>
__global__ __launch_bounds__(256) void gather_k(const int* __restrict__ row_ptr,
                                                const int* __restrict__ col_src,
                                                const float* __restrict__ asrc,
                                                const float* __restrict__ adst,
                                                const u16* __restrict__ hb,
                                                const float* __restrict__ bias,
                                                u16* __restrict__ outb,
                                                float* __restrict__ nodeval) {
  int n = blockIdx.x * 4 + (threadIdx.x >> 6);
  if (n >= NN) return;
  int lane = threadIdx.x & 63;
  int hh = lane & 7;
  int hsel = lane >> 3;
  int start = row_ptr[n], end = row_ptr[n + 1];
  float adn = adst[n * FH + hh];
  float den = 0.f;
  float v[8] = {};
  for (int j0 = start; j0 < end; j0 += 4) {
    int sidx[4];
#pragma unroll
    for (int u = 0; u < 4; ++u) {
      int jj = (j0 + u < end) ? j0 + u : end - 1;
      sidx[u] = col_src[jj];
    }
    float ex[4];
#pragma unroll
    for (int u = 0; u < 4; ++u) {
      float el = asrc[sidx[u] * FH + hh] + adn;
      el = el > 0.f ? el : 0.2f * el;
      ex[u] = (j0 + u < end) ? __expf(el) : 0.f;
      den += ex[u];
    }
    u16x8 hv[4];
#pragma unroll
    for (int u = 0; u < 4; ++u)
      hv[u] = *reinterpret_cast<const u16x8*>(hb + (size_t)sidx[u] * FHC + lane * 8);
#pragma unroll
    for (int u = 0; u < 4; ++u) {
      float exv = __shfl(ex[u], hsel);
#pragma unroll
      for (int j = 0; j < 8; ++j) v[j] += exv * h2f(hv[u][j]);
    }
  }
  float dh = __shfl(den, hsel);
  float inv = 1.f / (dh + 1e-16f);
#pragma unroll
  for (int j = 0; j < 8; ++j) v[j] *= inv;
  if (LAYER == 1) {
    const float4* bp = reinterpret_cast<const float4*>(bias + lane * 8);
    float4 b0 = bp[0], b1 = bp[1];
    float bb[8] = {b0.x, b0.y, b0.z, b0.w, b1.x, b1.y, b1.z, b1.w};
    u16x8 ov;
#pragma unroll
    for (int j = 0; j < 8; ++j) {
      float val = v[j] + bb[j];
      val = val > 0.f ? val : expm1f(val);
      ov[j] = f2h(val);
    }
    *reinterpret_cast<u16x8*>(outb + (size_t)n * FHC + lane * 8) = ov;
  } else {
#pragma unroll
    for (int off = 8; off < 64; off <<= 1)
#pragma unroll
      for (int j = 0; j < 8; ++j) v[j] += __shfl_xor(v[j], off);
    if (lane < 8) {
      const float4* bp = reinterpret_cast<const float4*>(bias + lane * 8);
      float4 b0 = bp[0], b1 = bp[1];
      float bb[8] = {b0.x, b0.y, b0.z, b0.w, b1.x, b1.y, b1.z, b1.w};
      float o[8];
#pragma unroll
      for (int j = 0; j < 8; ++j) {
        float val = v[j] * (1.f / FH) + bb[j];
        o[j] = val > 0.f ? val : expm1f(val);
      }
      float4* np = reinterpret_cast<float4*>(nodeval + (size_t)n * FC + lane * 8);
      np[0] = make_float4(o[0], o[1], o[2], o[3]);
      np[1] = make_float4(o[4], o[5], o[6], o[7]);
    }
  }
}

// ---- pool: one block per graph over its contiguous node range ----
__global__ __launch_bounds__(256) void pool_k(const float* __restrict__ nodeval,
                                              const int* __restrict__ gstart,
                                              const int* __restrict__ gend,
                                              float* __restrict__ out) {
  __shared__ float red[4][FC];
  int g = blockIdx.x;
  int c = threadIdx.x & 63, w = threadIdx.x >> 6;
  int s = gstart[g], e = gend[g];
  float acc = 0.f;
  for (int n = s + w; n < e; n += 4) acc += nodeval[(size_t)n * FC + c];
  red[w][c] = acc;
  __syncthreads();
  if (w == 0) {
    float v = red[0][c] + red[1][c] + red[2][c] + red[3][c];
    out[g * FC + c] = v / fmaxf((float)(e - s), 1.f);
  }
}

extern "C" void kernel_launch(void* const* d_in, const int* in_sizes, int n_in,
                              void* d_out, int out_size, void* d_ws, size_t ws_size,
                              hipStream_t stream) {
  const float* x    = (const float*)d_in[0];
  const int*   ei   = (const int*)d_in[1];
  const int*   batch= (const int*)d_in[2];
  const float* W1   = (const float*)d_in[3];
  const float* as1  = (const float*)d_in[4];
  const float* ad1  = (const float*)d_in[5];
  const float* b1   = (const float*)d_in[6];
  const float* W2   = (const float*)d_in[7];
  const float* as2  = (const float*)d_in[8];
  const float* ad2  = (const float*)d_in[9];
  const float* b2   = (const float*)d_in[10];
  float* out = (float*)d_out;

  char* p = (char*)d_ws;
  u16* Cb  = (u16*)p; p += (size_t)NN * FHC * 2;     // 51.2 MB (GEMM out, fp16)
  u16* xf  = (u16*)p; p += (size_t)MPAD * FIN * 2;   // x fp16
  u16* h1f = (u16*)p; p += (size_t)MPAD * FHC * 2;   // layer-1 out / GEMM2 A
  u16* w1t = (u16*)p; p += (size_t)FHC * FIN * 2;
  u16* w2t = (u16*)p; p += (size_t)FHC * FHC * 2;
  float* asrc = (float*)p;            p += (size_t)NN * FH * 4;
  float* adst = (float*)p;            p += (size_t)NN * FH * 4;
  int* deg    = (int*)p;              p += (size_t)NN * 4;
  int* rowp   = (int*)p;              p += (size_t)(NN + 1) * 4;
  int* cursor = (int*)p;              p += (size_t)NN * 4;
  int* col    = (int*)p;              p += (size_t)NET * 4;
  int* gstart = (int*)p;              p += (size_t)NG * 4;
  int* gend   = (int*)p;              p += (size_t)NG * 4;
  int* bsum   = (int*)p;              p += (size_t)NB * 4;
  // nodeval reuses xf's region (dead by the time gather_k<2> runs):
  // NN*64*4 = 12.80 MB <= MPAD*FIN*2 = 12.81 MB
  float* nodeval = (float*)xf;

  const int NWG = (MPAD / 128) * (FHC / 128);   // 1564, 1D XCD-chunked grid
  const int egrid = (NET + 255) / 256;
  const int ngrid = (NN + 3) / 4;

  // ---- zero-init: deg, boundaries, pad rows of A planes ----
  hipMemsetAsync(deg, 0, (size_t)NN * 4, stream);
  hipMemsetAsync(gstart, 0, (size_t)NG * 2 * 4, stream);
  hipMemsetAsync(xf + (size_t)NN * FIN, 0, (size_t)(MPAD - NN) * FIN * 2, stream);
  hipMemsetAsync(h1f + (size_t)NN * FHC, 0, (size_t)(MPAD - NN) * FHC * 2, stream);

  // ---- conversions ----
  conv_h_k<<<(NN * FIN / 4 + 255) / 256, 256, 0, stream>>>(x, xf, NN * FIN / 4);
  conv_wt_k<<<(FIN * FHC + 255) / 256, 256, 0, stream>>>(W1, w1t, FIN);
  conv_wt_k<<<(FHC * FHC + 255) / 256, 256, 0, stream>>>(W2, w2t, FHC);

  // ---- CSR build (3-pass parallel scan) + graph boundaries ----
  hist_k<<<egrid, 256, 0, stream>>>(ei, deg);
  scan1_k<<<NB, 256, 0, stream>>>(deg, rowp, bsum);
  scan2_k<<<1, 256, 0, stream>>>(bsum, rowp);
  scan3_k<<<NB, 256, 0, stream>>>(rowp, bsum, cursor);
  fill_k<<<egrid, 256, 0, stream>>>(ei, cursor, col);
  bnd_k<<<(NN + 255) / 256, 256, 0, stream>>>(batch, gstart, gend);

  // ---- layer 1 (alphas fused into GEMM epilogue) ----
  gemm_mfma<<<NWG, 256, 0, stream>>>(xf, w1t, Cb, as1, ad1, asrc, adst, NN, FIN);
  gather_k<1><<<ngrid, 256, 0, stream>>>(rowp, col, asrc, adst, Cb, b1,
                                         h1f, nullptr);

  // ---- layer 2 ----
  gemm_mfma<<<NWG, 256, 0, stream>>>(h1f, w2t, Cb, as2, ad2, asrc, adst, NN, FHC);
  gather_k<2><<<ngrid, 256, 0, stream>>>(rowp, col, asrc, adst, Cb, b2,
                                         nullptr, nodeval);

  pool_k<<<NG, 256, 0, stream>>>(nodeval, gstart, gend, out);
}

// Round 12
// 348.579 us; speedup vs baseline: 7.3781x; 1.0989x over previous
//
#include <hip/hip_runtime.h>
#include <hip/hip_bf16.h>
#include <hip/hip_fp16.h>
#include <math.h>

// Problem constants (from reference setup_inputs)
#define NN   50000      // nodes
#define NE   400000     // edges (without self loops)
#define NET  450000     // edges + self loops
#define FH   8          // heads
#define FC   64         // channels per head
#define FHC  512        // H*C
#define FIN  128        // input features
#define NG   64         // graphs
#define MPAD 50048      // NN padded to tile multiple (391*128)
#define NB   196        // scan blocks = ceil(NN/256)

typedef unsigned short u16;
typedef _Float16 f16x8 __attribute__((ext_vector_type(8)));
typedef float f32x4 __attribute__((ext_vector_type(4)));
typedef unsigned short u16x8 __attribute__((ext_vector_type(8)));

// ---- f32 <-> fp16 helpers (RNE) ----
static __device__ __forceinline__ u16 f2h(float f) {
  return __half_as_ushort(__float2half(f));
}
static __device__ __forceinline__ float h2f(u16 u) {
  return __half2float(__ushort_as_half(u));
}

// ---- fused prep: x->fp16, W1/W2 transpose->fp16, zero pads/deg/bounds ----
// Range-partitioned single kernel (replaces 3 conv kernels + 4 memsets).
#define R0 (NN * FIN / 4)          // conv x (float4)        1,600,000
#define R1 (FIN * FHC)             // W1 transpose              65,536
#define R2 (FHC * FHC)             // W2 transpose             262,144
#define R3 ((MPAD - NN) * FIN / 8) // xf pad zero (u16x8)          768
#define R4 ((MPAD - NN) * FHC / 8) // h1f pad zero (u16x8)       3,072
#define R5 (NN / 4)                // deg zero (int4)           12,500
#define R6 (2 * NG)                // gstart/gend zero             128
#define PREP_T (R0 + R1 + R2 + R3 + R4 + R5 + R6)

__global__ __launch_bounds__(256) void prep_k(const float* __restrict__ x,
                                              const float* __restrict__ W1,
                                              const float* __restrict__ W2,
                                              u16* __restrict__ xf,
                                              u16* __restrict__ w1t,
                                              u16* __restrict__ w2t,
                                              u16* __restrict__ h1f,
                                              int* __restrict__ deg,
                                              int* __restrict__ gse) {
  int t = blockIdx.x * 256 + threadIdx.x;
  if (t < R0) {
    float4 f = reinterpret_cast<const float4*>(x)[t];
    ushort4 h;
    h.x = f2h(f.x); h.y = f2h(f.y); h.z = f2h(f.z); h.w = f2h(f.w);
    reinterpret_cast<ushort4*>(xf)[t] = h;
    return;
  }
  t -= R0;
  if (t < R1) {
    int k = t >> 9, n = t & 511;
    w1t[n * FIN + k] = f2h(W1[t]);
    return;
  }
  t -= R1;
  if (t < R2) {
    int k = t >> 9, n = t & 511;
    w2t[n * FHC + k] = f2h(W2[t]);
    return;
  }
  t -= R2;
  if (t < R3) {
    reinterpret_cast<u16x8*>(xf + (size_t)NN * FIN)[t] = (u16x8)0;
    return;
  }
  t -= R3;
  if (t < R4) {
    reinterpret_cast<u16x8*>(h1f + (size_t)NN * FHC)[t] = (u16x8)0;
    return;
  }
  t -= R4;
  if (t < R5) {
    reinterpret_cast<int4*>(deg)[t] = make_int4(0, 0, 0, 0);
    return;
  }
  t -= R5;
  if (t < R6) gse[t] = 0;
}

// ---- fp16 MFMA GEMM + fused attention-logit epilogue.
// C[M,512] = A[M,K] @ Wt^T, fp16 in, f32 accumulate. 128x128 tile, 4 waves,
// BK=32 -> 16 KB LDS (~6 blocks/CU). Bijective XCD-chunked 1D grid.
__global__ __launch_bounds__(256) void gemm_mfma(const u16* __restrict__ Af,
                                                 const u16* __restrict__ Bf,
                                                 u16* __restrict__ Cb,
                                                 const float* __restrict__ As_g,
                                                 const float* __restrict__ Ad_g,
                                                 float* __restrict__ asrc,
                                                 float* __restrict__ adst,
                                                 int M, int K) {
  constexpr int BK = 32;
  __shared__ u16 As[128 * BK];   // 8 KB
  __shared__ u16 Bs[128 * BK];   // 8 KB
  const int tid = threadIdx.x;
  // ---- bijective XCD-chunked block id -> (mt, nt) ----
  constexpr int NWG = (MPAD / 128) * (FHC / 128);  // 1564
  constexpr int qq = NWG >> 3, rr = NWG & 7;
  int d = blockIdx.x;
  int xcd = d & 7, slot = d >> 3;
  int w = (xcd < rr) ? xcd * (qq + 1) + slot
                     : rr * (qq + 1) + (xcd - rr) * qq + slot;
  const int bm = (w >> 2) * 128;
  const int bn = (w & 3) * 128;
  const int wv = tid >> 6, l = tid & 63;
  const int wr = wv >> 1, wc = wv & 1;
  const int fr = l & 15, fq = l >> 4;

  f32x4 acc[4][4] = {};

  for (int k0 = 0; k0 < K; k0 += BK) {
    __syncthreads();
#pragma unroll
    for (int i = 0; i < 2; ++i) {
      int idx = i * 256 + tid;          // 512 granules of 8 fp16 per matrix
      int row = idx >> 2, c8 = idx & 3;
      size_t goA = (size_t)(bm + row) * K + k0 + c8 * 8;
      size_t goB = (size_t)(bn + row) * K + k0 + c8 * 8;
      __builtin_amdgcn_global_load_lds(
          (const __attribute__((address_space(1))) void*)(Af + goA),
          (__attribute__((address_space(3))) void*)(As + idx * 8), 16, 0, 0);
      __builtin_amdgcn_global_load_lds(
          (const __attribute__((address_space(1))) void*)(Bf + goB),
          (__attribute__((address_space(3))) void*)(Bs + idx * 8), 16, 0, 0);
    }
    __syncthreads();
    {
      f16x8 av[4], bv[4];
#pragma unroll
      for (int mi = 0; mi < 4; ++mi)
        av[mi] = *reinterpret_cast<const f16x8*>(
            As + (wr * 64 + mi * 16 + fr) * BK + fq * 8);
#pragma unroll
      for (int ni = 0; ni < 4; ++ni)
        bv[ni] = *reinterpret_cast<const f16x8*>(
            Bs + (wc * 64 + ni * 16 + fr) * BK + fq * 8);
#pragma unroll
      for (int mi = 0; mi < 4; ++mi)
#pragma unroll
        for (int ni = 0; ni < 4; ++ni)
          acc[mi][ni] = __builtin_amdgcn_mfma_f32_16x16x32_f16(
              av[mi], bv[ni], acc[mi][ni], 0, 0, 0);
    }
  }
  // ---- C store (fp16 plane) ----
#pragma unroll
  for (int mi = 0; mi < 4; ++mi)
#pragma unroll
    for (int ni = 0; ni < 4; ++ni) {
      int r0 = bm + wr * 64 + mi * 16 + fq * 4;
      int c0 = bn + wc * 64 + ni * 16 + fr;
#pragma unroll
      for (int j = 0; j < 4; ++j)
        if (r0 + j < M) Cb[(size_t)(r0 + j) * FHC + c0] = f2h(acc[mi][ni][j]);
    }
  // ---- fused attention logits: this wave's 64 cols == head hd ----
  {
    int hd = (bn >> 6) + wc;
    int cb = bn + wc * 64 + fr;
    float as_v[4], ad_v[4];
#pragma unroll
    for (int ni = 0; ni < 4; ++ni) {
      as_v[ni] = As_g[cb + ni * 16];
      ad_v[ni] = Ad_g[cb + ni * 16];
    }
#pragma unroll
    for (int mi = 0; mi < 4; ++mi)
#pragma unroll
      for (int j = 0; j < 4; ++j) {
        float ps = 0.f, pd = 0.f;
#pragma unroll
        for (int ni = 0; ni < 4; ++ni) {
          float v = acc[mi][ni][j];
          ps += v * as_v[ni];
          pd += v * ad_v[ni];
        }
#pragma unroll
        for (int off = 1; off < 16; off <<= 1) {
          ps += __shfl_xor(ps, off);
          pd += __shfl_xor(pd, off);
        }
        int row = bm + wr * 64 + mi * 16 + fq * 4 + j;
        if (fr == 0 && row < M) {
          asrc[row * FH + hd] = ps;
          adst[row * FH + hd] = pd;
        }
      }
  }
}

// ---- CSR build: histogram of dst ----
__global__ __launch_bounds__(256) void hist_k(const int* __restrict__ ei,
                                              int* __restrict__ deg) {
  int e = blockIdx.x * 256 + threadIdx.x;
  if (e >= NET) return;
  int d = (e < NE) ? ei[NE + e] : e - NE;
  atomicAdd(&deg[d], 1);
}

// ---- hierarchical scan pass 1: per-block exclusive prefix + block sums ----
__global__ __launch_bounds__(256) void scan1_k(const int* __restrict__ deg,
                                               int* __restrict__ row_ptr,
                                               int* __restrict__ bsum) {
  int tid = threadIdx.x;
  int i = blockIdx.x * 256 + tid;
  int lane = tid & 63, w = tid >> 6;
  int val = (i < NN) ? deg[i] : 0;
  int s = val;
#pragma unroll
  for (int off = 1; off < 64; off <<= 1) {
    int t = __shfl_up(s, off);
    if (lane >= off) s += t;
  }
  __shared__ int wt[4], wo[4];
  if (lane == 63) wt[w] = s;
  __syncthreads();
  if (tid == 0) {
    int r = 0;
#pragma unroll
    for (int k = 0; k < 4; ++k) { wo[k] = r; r += wt[k]; }
    bsum[blockIdx.x] = r;
  }
  __syncthreads();
  if (i < NN) row_ptr[i] = s - val + wo[w];
}

// ---- scan pass 2: scan the NB block sums (single tiny block) ----
__global__ __launch_bounds__(256) void scan2_k(int* __restrict__ bsum,
                                               int* __restrict__ row_ptr) {
  int tid = threadIdx.x;
  int lane = tid & 63, w = tid >> 6;
  int val = (tid < NB) ? bsum[tid] : 0;
  int s = val;
#pragma unroll
  for (int off = 1; off < 64; off <<= 1) {
    int t = __shfl_up(s, off);
    if (lane >= off) s += t;
  }
  __shared__ int wt[4], wo[4];
  if (lane == 63) wt[w] = s;
  __syncthreads();
  if (tid == 0) {
    int r = 0;
#pragma unroll
    for (int k = 0; k < 4; ++k) { wo[k] = r; r += wt[k]; }
  }
  __syncthreads();
  int excl = s - val + wo[w];
  if (tid < NB) bsum[tid] = excl;
  if (tid == 255) row_ptr[NN] = excl;  // val=0 here -> excl == grand total
}

// ---- scan pass 3: add block offsets, init cursor ----
__global__ __launch_bounds__(256) void scan3_k(int* __restrict__ row_ptr,
                                               const int* __restrict__ bsum,
                                               int* __restrict__ cursor) {
  int i = blockIdx.x * 256 + threadIdx.x;
  if (i >= NN) return;
  int v = row_ptr[i] + bsum[blockIdx.x];
  row_ptr[i] = v;
  cursor[i] = v;
}

// ---- CSR fill + graph boundary detection (merged) ----
__global__ __launch_bounds__(256) void fillbnd_k(const int* __restrict__ ei,
                                                 int* __restrict__ cursor,
                                                 int* __restrict__ col_src,
                                                 const int* __restrict__ batch,
                                                 int* __restrict__ gstart,
                                                 int* __restrict__ gend) {
  int t = blockIdx.x * 256 + threadIdx.x;
  if (t < NET) {
    int s, d;
    if (t < NE) { s = ei[t]; d = ei[NE + t]; } else { s = d = t - NE; }
    int pos = atomicAdd(&cursor[d], 1);
    col_src[pos] = s;
    return;
  }
  int n = t - NET;
  if (n >= NN) return;
  int b = batch[n];
  if (n == 0 || batch[n - 1] != b) gstart[b] = n;
  if (n == NN - 1 || batch[n + 1] != b) gend[b] = n + 1;
}

// ---- gather-aggregate: one wave per dst node, 8 fp16/lane, 4-edge chunks ----
template <int LAYER>
__global__ __launch_bounds__(256) void gather_k(const int* __restrict__ row_ptr,
                                                const int* __restrict__ col_src,
                                                const float* __restrict__ asrc,
                                                const float* __restrict__ adst,
                                                const u16* __restrict__ hb,
                                                const float* __restrict__ bias,
                                                u16* __restrict__ outb,
                                                float* __restrict__ nodeval) {
  int n = blockIdx.x * 4 + (threadIdx.x >> 6);
  if (n >= NN) return;
  int lane = threadIdx.x & 63;
  int hh = lane & 7;
  int hsel = lane >> 3;
  int start = row_ptr[n], end = row_ptr[n + 1];
  float adn = adst[n * FH + hh];
  float den = 0.f;
  float v[8] = {};
  for (int j0 = start; j0 < end; j0 += 4) {
    int sidx[4];
#pragma unroll
    for (int u = 0; u < 4; ++u) {
      int jj = (j0 + u < end) ? j0 + u : end - 1;
      sidx[u] = col_src[jj];
    }
    float ex[4];
#pragma unroll
    for (int u = 0; u < 4; ++u) {
      float el = asrc[sidx[u] * FH + hh] + adn;
      el = el > 0.f ? el : 0.2f * el;
      ex[u] = (j0 + u < end) ? __expf(el) : 0.f;
      den += ex[u];
    }
    u16x8 hv[4];
#pragma unroll
    for (int u = 0; u < 4; ++u)
      hv[u] = *reinterpret_cast<const u16x8*>(hb + (size_t)sidx[u] * FHC + lane * 8);
#pragma unroll
    for (int u = 0; u < 4; ++u) {
      float exv = __shfl(ex[u], hsel);
#pragma unroll
      for (int j = 0; j < 8; ++j) v[j] += exv * h2f(hv[u][j]);
    }
  }
  float dh = __shfl(den, hsel);
  float inv = 1.f / (dh + 1e-16f);
#pragma unroll
  for (int j = 0; j < 8; ++j) v[j] *= inv;
  if (LAYER == 1) {
    const float4* bp = reinterpret_cast<const float4*>(bias + lane * 8);
    float4 b0 = bp[0], b1 = bp[1];
    float bb[8] = {b0.x, b0.y, b0.z, b0.w, b1.x, b1.y, b1.z, b1.w};
    u16x8 ov;
#pragma unroll
    for (int j = 0; j < 8; ++j) {
      float val = v[j] + bb[j];
      val = val > 0.f ? val : expm1f(val);
      ov[j] = f2h(val);
    }
    *reinterpret_cast<u16x8*>(outb + (size_t)n * FHC + lane * 8) = ov;
  } else {
#pragma unroll
    for (int off = 8; off < 64; off <<= 1)
#pragma unroll
      for (int j = 0; j < 8; ++j) v[j] += __shfl_xor(v[j], off);
    if (lane < 8) {
      const float4* bp = reinterpret_cast<const float4*>(bias + lane * 8);
      float4 b0 = bp[0], b1 = bp[1];
      float bb[8] = {b0.x, b0.y, b0.z, b0.w, b1.x, b1.y, b1.z, b1.w};
      float o[8];
#pragma unroll
      for (int j = 0; j < 8; ++j) {
        float val = v[j] * (1.f / FH) + bb[j];
        o[j] = val > 0.f ? val : expm1f(val);
      }
      float4* np = reinterpret_cast<float4*>(nodeval + (size_t)n * FC + lane * 8);
      np[0] = make_float4(o[0], o[1], o[2], o[3]);
      np[1] = make_float4(o[4], o[5], o[6], o[7]);
    }
  }
}

// ---- pool: one block per graph over its contiguous node range ----
__global__ __launch_bounds__(256) void pool_k(const float* __restrict__ nodeval,
                                              const int* __restrict__ gstart,
                                              const int* __restrict__ gend,
                                              float* __restrict__ out) {
  __shared__ float red[4][FC];
  int g = blockIdx.x;
  int c = threadIdx.x & 63, w = threadIdx.x >> 6;
  int s = gstart[g], e = gend[g];
  float acc = 0.f;
  for (int n = s + w; n < e; n += 4) acc += nodeval[(size_t)n * FC + c];
  red[w][c] = acc;
  __syncthreads();
  if (w == 0) {
    float v = red[0][c] + red[1][c] + red[2][c] + red[3][c];
    out[g * FC + c] = v / fmaxf((float)(e - s), 1.f);
  }
}

extern "C" void kernel_launch(void* const* d_in, const int* in_sizes, int n_in,
                              void* d_out, int out_size, void* d_ws, size_t ws_size,
                              hipStream_t stream) {
  const float* x    = (const float*)d_in[0];
  const int*   ei   = (const int*)d_in[1];
  const int*   batch= (const int*)d_in[2];
  const float* W1   = (const float*)d_in[3];
  const float* as1  = (const float*)d_in[4];
  const float* ad1  = (const float*)d_in[5];
  const float* b1   = (const float*)d_in[6];
  const float* W2   = (const float*)d_in[7];
  const float* as2  = (const float*)d_in[8];
  const float* ad2  = (const float*)d_in[9];
  const float* b2   = (const float*)d_in[10];
  float* out = (float*)d_out;

  char* p = (char*)d_ws;
  u16* Cb  = (u16*)p; p += (size_t)NN * FHC * 2;     // 51.2 MB (GEMM out, fp16)
  u16* xf  = (u16*)p; p += (size_t)MPAD * FIN * 2;   // x fp16
  u16* h1f = (u16*)p; p += (size_t)MPAD * FHC * 2;   // layer-1 out / GEMM2 A
  u16* w1t = (u16*)p; p += (size_t)FHC * FIN * 2;
  u16* w2t = (u16*)p; p += (size_t)FHC * FHC * 2;
  float* asrc = (float*)p;            p += (size_t)NN * FH * 4;
  float* adst = (float*)p;            p += (size_t)NN * FH * 4;
  int* deg    = (int*)p;              p += (size_t)NN * 4;
  int* rowp   = (int*)p;              p += (size_t)(NN + 1) * 4;
  int* cursor = (int*)p;              p += (size_t)NN * 4;
  int* col    = (int*)p;              p += (size_t)NET * 4;
  int* gse    = (int*)p;              p += (size_t)NG * 2 * 4;  // gstart|gend
  int* bsum   = (int*)p;              p += (size_t)NB * 4;
  int* gstart = gse;
  int* gend   = gse + NG;
  // nodeval reuses xf's region (dead by the time gather_k<2> runs):
  // NN*64*4 = 12.80 MB <= MPAD*FIN*2 = 12.81 MB
  float* nodeval = (float*)xf;

  const int NWG = (MPAD / 128) * (FHC / 128);   // 1564, 1D XCD-chunked grid
  const int ngrid = (NN + 3) / 4;

  // ---- prep: conversions + zero-inits (one kernel) ----
  prep_k<<<(PREP_T + 255) / 256, 256, 0, stream>>>(x, W1, W2, xf, w1t, w2t,
                                                   h1f, deg, gse);

  // ---- CSR build (3-pass parallel scan) + fill/boundaries ----
  hist_k<<<(NET + 255) / 256, 256, 0, stream>>>(ei, deg);
  scan1_k<<<NB, 256, 0, stream>>>(deg, rowp, bsum);
  scan2_k<<<1, 256, 0, stream>>>(bsum, rowp);
  scan3_k<<<NB, 256, 0, stream>>>(rowp, bsum, cursor);
  fillbnd_k<<<(NET + NN + 255) / 256, 256, 0, stream>>>(ei, cursor, col,
                                                        batch, gstart, gend);

  // ---- layer 1 (alphas fused into GEMM epilogue) ----
  gemm_mfma<<<NWG, 256, 0, stream>>>(xf, w1t, Cb, as1, ad1, asrc, adst, NN, FIN);
  gather_k<1><<<ngrid, 256, 0, stream>>>(rowp, col, asrc, adst, Cb, b1,
                                         h1f, nullptr);

  // ---- layer 2 ----
  gemm_mfma<<<NWG, 256, 0, stream>>>(h1f, w2t, Cb, as2, ad2, asrc, adst, NN, FHC);
  gather_k<2><<<ngrid, 256, 0, stream>>>(rowp, col, asrc, adst, Cb, b2,
                                         nullptr, nodeval);

  pool_k<<<NG, 256, 0, stream>>>(nodeval, gstart, gend, out);
}